// Round 1
// baseline (8400.810 us; speedup 1.0000x reference)
//
#include <hip/hip_runtime.h>
#include <math.h>

#define NP 16384
#define DD 192
#define NS 16
#define KSPN 16
#define MTOT (NP*NS)

// ws float offsets
#define WS_KNN   0                      // N*48  knn_xyz
#define WS_GEO9  (WS_KNN + NP*48)       // N*9
#define WS_GDIS  (WS_GEO9 + NP*9)       // N
#define WS_X1    (WS_GDIS + NP)         // N*192 post-propagate
#define WS_X2    (WS_X1 + NP*DD)        // N*192 post-fusion
#define WS_STATS (WS_X2 + NP*DD)        // [0]=dsum [1]=dmax(bits) [2..578) hsum [578..1154) hsq
#define WS_VOLV  (WS_STATS + 1154)      // 192
#define WS_W1P   (WS_VOLV + DD)         // 3*48*192 BN-folded pos_W1
#define WS_B1P   (WS_W1P + 3*48*DD)     // 576

__global__ __launch_bounds__(256) void k_init(float* __restrict__ ws) {
    int t = blockIdx.x * blockDim.x + threadIdx.x;
    if (t < 1154) ws[WS_STATS + t] = 0.f;
}

// ---- K1: geometry, propagate layer, BN layer-1 stat accumulation ----
__global__ __launch_bounds__(256) void k1_geom_prop(
    const float* __restrict__ p, const float* __restrict__ x,
    const int* __restrict__ knn,
    const float* __restrict__ propW, const float* __restrict__ propB,
    const float* __restrict__ posW1, const float* __restrict__ posB1,
    float* __restrict__ ws)
{
    __shared__ float A[NS][201];     // x_knn(0..191) | p_r(192..194); stride 201 -> conflict-free
    __shared__ float pos[NS][49];
    __shared__ float Xl[48];
    __shared__ int   idx[NS];
    __shared__ float pn[3];
    __shared__ float distl[NS];
    __shared__ float hsum_l[576];
    __shared__ float hsq_l[576];
    const int t = threadIdx.x;
    const int s = t & 15;        // row (consecutive lanes vary s -> width-16 shuffle reduce)
    const int u = t >> 4;
    const int c0 = u * 12;
    for (int e = t; e < 576; e += 256) { hsum_l[e] = 0.f; hsq_l[e] = 0.f; }
    float dsum_loc = 0.f, dmax_loc = 0.f;

    for (int it = 0; it < 16; ++it) {
        const int n = blockIdx.x * 16 + it;
        __syncthreads();                       // protect LDS reuse across iterations
        if (t < NS) idx[t] = knn[n*NS + t];
        if (t < 3)  pn[t] = p[n*3 + t];
        __syncthreads();
        if (t < 48) {
            float v = p[idx[t/3]*3 + (t % 3)];
            Xl[t] = v;
            ws[WS_KNN + n*48 + t] = v;
        }
        __syncthreads();
        if (t < NS) {
            float dx = Xl[t*3+0]-pn[0], dy = Xl[t*3+1]-pn[1], dz = Xl[t*3+2]-pn[2];
            A[t][192] = dx; A[t][193] = dy; A[t][194] = dz;
            distl[t] = sqrtf(dx*dx + dy*dy + dz*dz + 1e-12f);
        }
        for (int e = t; e < NS*DD; e += 256) {     // stage x_knn
            int r = e / DD, cc = e - r*DD;
            A[r][cc] = x[idx[r]*DD + cc];
        }
        for (int e = t; e < NS*48; e += 256) {     // pos[s][3j+c] = X[j][c]-X[s][c]
            int r = e / 48, k = e - r*48;
            pos[r][k] = Xl[k] - Xl[r*3 + (k % 3)];
        }
        __syncthreads();
        if (t == 0) {
            float dm = 0.f, dsm = 0.f;
            for (int j = 0; j < NS; ++j) { dm = fmaxf(dm, distl[j]); dsm += distl[j]; }
            ws[WS_GDIS + n] = dm;
            dsum_loc += dsm;
            dmax_loc = fmaxf(dmax_loc, dm);
        }
        if (t < 3) {
            float mx = 0.f;
            for (int j = 0; j < NS; ++j) mx += Xl[j*3 + t];
            mx *= (1.f/16.f);
            ws[WS_GEO9 + n*9 + t]     = mx - pn[t];   // mean p_r
            ws[WS_GEO9 + n*9 + 3 + t] = mx;           // mean knn_xyz
            ws[WS_GEO9 + n*9 + 6 + t] = pn[t];        // p
        }
        // propagate: row s, cols c0..c0+11
        float acc[12];
        #pragma unroll
        for (int m = 0; m < 12; ++m) acc[m] = 0.f;
        for (int k = 0; k < 195; ++k) {
            float a = A[s][k];
            const float* wr = propW + k*DD + c0;
            #pragma unroll
            for (int m = 0; m < 12; ++m) acc[m] += a * wr[m];
        }
        #pragma unroll
        for (int m = 0; m < 12; ++m) {
            float mv = fmaxf(acc[m] + propB[c0 + m], 0.f);
            #pragma unroll
            for (int off = 1; off < 16; off <<= 1) mv += __shfl_xor(mv, off, 16);
            if (s == 0) ws[WS_X1 + n*DD + c0 + m] = x[n*DD + c0 + m] + mv * (1.f/16.f);
        }
        // BN layer-1 stats (unfolded weights): h = pos@W1 + b1
        for (int i = 0; i < 3; ++i) {
            #pragma unroll
            for (int m = 0; m < 12; ++m) acc[m] = 0.f;
            for (int k = 0; k < 48; ++k) {
                float a = pos[s][k];
                const float* wr = posW1 + (i*48 + k)*DD + c0;
                #pragma unroll
                for (int m = 0; m < 12; ++m) acc[m] += a * wr[m];
            }
            #pragma unroll
            for (int m = 0; m < 12; ++m) {
                float hv = acc[m] + posB1[i*DD + c0 + m];
                float hs = hv, hq = hv * hv;
                #pragma unroll
                for (int off = 1; off < 16; off <<= 1) {
                    hs += __shfl_xor(hs, off, 16);
                    hq += __shfl_xor(hq, off, 16);
                }
                if (s == 0) { hsum_l[i*DD + c0 + m] += hs; hsq_l[i*DD + c0 + m] += hq; }
            }
        }
    }
    __syncthreads();
    for (int e = t; e < 576; e += 256) {
        atomicAdd(&ws[WS_STATS + 2 + e],       hsum_l[e]);
        atomicAdd(&ws[WS_STATS + 2 + 576 + e], hsq_l[e]);
    }
    if (t == 0) {
        atomicAdd(&ws[WS_STATS + 0], dsum_loc);
        atomicMax((int*)(ws + WS_STATS + 1), __float_as_int(dmax_loc));  // dist>=0: int cmp ok
    }
}

// ---- K2: vol scalar + BN fold into W1'/b1' ----
__global__ __launch_bounds__(576) void k2_stats(
    const float* __restrict__ gCW, const float* __restrict__ gCb,
    const float* __restrict__ posW1, const float* __restrict__ posB1,
    const float* __restrict__ gamma, const float* __restrict__ beta,
    float* __restrict__ ws)
{
    const int t = threadIdx.x;
    float dsum = ws[WS_STATS + 0];
    float dmax = __int_as_float(((const int*)ws)[WS_STATS + 1]);
    float vol = (dsum / (float)MTOT) / (dmax + 1e-8f);
    if (t < DD) ws[WS_VOLV + t] = vol * gCW[t] + gCb[t];
    float mu  = ws[WS_STATS + 2 + t] / (float)MTOT;
    float ex2 = ws[WS_STATS + 2 + 576 + t] / (float)MTOT;
    float var = fmaxf(ex2 - mu*mu, 0.f);
    float a = rsqrtf(var + 1e-5f) * gamma[t];
    ws[WS_B1P + t] = (posB1[t] - mu) * a + beta[t];
    int i = t / DD, c = t - i*DD;
    for (int k = 0; k < 48; ++k)
        ws[WS_W1P + (i*48 + k)*DD + c] = posW1[(i*48 + k)*DD + c] * a;
}

// ---- K3: keypoint attention + feature fusion -> x2 ----
__global__ __launch_bounds__(256) void k3_fuse(
    const float* __restrict__ p, const float* __restrict__ kn,
    const float* __restrict__ deW1, const float* __restrict__ deB1,
    const float* __restrict__ deW2, const float* __restrict__ deB2,
    const float* __restrict__ kpW, const float* __restrict__ kpB,
    const float* __restrict__ gAW, const float* __restrict__ gAb,
    const float* __restrict__ gBW, const float* __restrict__ gBb,
    const float* __restrict__ fusW, const float* __restrict__ fusB,
    float* __restrict__ ws)
{
    __shared__ float kd[KSPN];
    __shared__ float innr[KSPN][48];
    __shared__ float df[KSPN][DD];
    __shared__ float scl[KSPN];
    __shared__ float uv[DD];
    const int n = blockIdx.x;
    const int t = threadIdx.x;
    const int kap = t >> 4;    // row (same for 16 consecutive lanes -> broadcast reads)
    const int u = t & 15;
    const int c0 = u * 12;
    if (t < KSPN) {
        float dx = p[n*3+0]-kn[t*3+0], dy = p[n*3+1]-kn[t*3+1], dz = p[n*3+2]-kn[t*3+2];
        kd[t] = sqrtf(dx*dx + dy*dy + dz*dz + 1e-12f);
    }
    __syncthreads();
    for (int e = t; e < KSPN*48; e += 256) {
        int r = e / 48, j = e - r*48;
        innr[r][j] = fmaxf(kd[r]*deW1[j] + deB1[j], 0.f);
    }
    __syncthreads();
    float acc[12];
    #pragma unroll
    for (int m = 0; m < 12; ++m) acc[m] = deB2[c0 + m];
    for (int j = 0; j < 48; ++j) {
        float a = innr[kap][j];
        const float* wr = deW2 + j*DD + c0;
        #pragma unroll
        for (int m = 0; m < 12; ++m) acc[m] += a * wr[m];
    }
    float ks = 0.f;
    #pragma unroll
    for (int m = 0; m < 12; ++m) { df[kap][c0 + m] = acc[m]; ks += acc[m] * kpW[c0 + m]; }
    #pragma unroll
    for (int off = 1; off < 16; off <<= 1) ks += __shfl_xor(ks, off, 16);
    if (u == 0) scl[kap] = ks + kpB[0];
    __syncthreads();
    if (t < KSPN) {                              // softmax over 16 keypoints
        float v = scl[t];
        float mx = v;
        #pragma unroll
        for (int off = 1; off < 16; off <<= 1) mx = fmaxf(mx, __shfl_xor(mx, off, 16));
        float e = expf(v - mx);
        float sm = e;
        #pragma unroll
        for (int off = 1; off < 16; off <<= 1) sm += __shfl_xor(sm, off, 16);
        scl[t] = e / sm;
    }
    __syncthreads();
    if (t < DD) {
        float dfeat = 0.f;
        for (int k2 = 0; k2 < KSPN; ++k2) dfeat += scl[k2] * df[k2][t];
        float uval = ws[WS_X1 + n*DD + t] + gAb[t] + gBb[t] + ws[WS_VOLV + t] + dfeat;
        uval += ws[WS_GDIS + n] * gBW[t];
        for (int kk = 0; kk < 9; ++kk) uval += ws[WS_GEO9 + n*9 + kk] * gAW[kk*DD + t];
        uv[t] = uval;
    }
    __syncthreads();
    if (t < DD) {
        float o = fusB[t];
        for (int k2 = 0; k2 < DD; ++k2) o += uv[k2] * fusW[k2*DD + t];
        ws[WS_X2 + n*DD + t] = o;
    }
}

// ---- K4: positional MLPs + windowed attention (row 0 only) + proj ----
__global__ __launch_bounds__(256) void k4_attn(
    const int* __restrict__ knn,
    const float* __restrict__ Wqkv,
    const float* __restrict__ posW2, const float* __restrict__ posB2,
    const float* __restrict__ Wproj, const float* __restrict__ bproj,
    const float* __restrict__ ws, float* __restrict__ out)
{
    __shared__ float wxph[NS][193];   // wx, later reused as ph per i
    __shared__ float kb[NS][193];
    __shared__ float vb[NS][193];     // becomes v+pv
    __shared__ float pos[NS][49];
    __shared__ float q0l[DD];
    __shared__ float ctr[DD];
    __shared__ float Xl[48];
    __shared__ int   idx[NS];
    __shared__ float dq[6][16], dk[6][16], dqk[6][16], attn[6][16];
    const int n = blockIdx.x;
    const int t = threadIdx.x;
    const int sA = t & 15, uA = t >> 4, cA = uA * 12;   // decode A: lanes vary row
    const int jB = t >> 4, uB = t & 15;                 // decode B: lanes vary col-group
    if (t < NS) idx[t] = knn[n*NS + t];
    if (t < 48) Xl[t] = ws[WS_KNN + n*48 + t];
    __syncthreads();
    for (int e = t; e < NS*48; e += 256) {
        int r = e / 48, k = e - r*48;
        pos[r][k] = Xl[k] - Xl[r*3 + (k % 3)];
    }
    for (int e = t; e < NS*DD; e += 256) {
        int r = e / DD, cc = e - r*DD;
        wxph[r][cc] = ws[WS_X2 + idx[r]*DD + cc];
    }
    __syncthreads();
    if (t < DD) {                                    // q0 = wx[0] @ Wqkv[:,0:192]
        float a = 0.f;
        for (int k = 0; k < DD; ++k) a += wxph[0][k] * Wqkv[k*576 + t];
        q0l[t] = a;
    }
    {                                                // k,v full window
        float ak[12], av[12];
        #pragma unroll
        for (int m = 0; m < 12; ++m) { ak[m] = 0.f; av[m] = 0.f; }
        for (int k = 0; k < DD; ++k) {
            float a = wxph[sA][k];
            const float* wr = Wqkv + k*576 + DD + cA;
            #pragma unroll
            for (int m = 0; m < 12; ++m) { ak[m] += a*wr[m]; av[m] += a*wr[m + DD]; }
        }
        #pragma unroll
        for (int m = 0; m < 12; ++m) { kb[sA][cA+m] = ak[m]; vb[sA][cA+m] = av[m]; }
    }
    __syncthreads();
    for (int i = 0; i < 3; ++i) {
        // ph = relu(pos @ W1' + b1')  (BN folded)
        {
            float ac[12];
            #pragma unroll
            for (int m = 0; m < 12; ++m) ac[m] = 0.f;
            for (int k = 0; k < 48; ++k) {
                float a = pos[sA][k];
                const float* wr = ws + WS_W1P + (i*48 + k)*DD + cA;
                #pragma unroll
                for (int m = 0; m < 12; ++m) ac[m] += a * wr[m];
            }
            __syncthreads();   // prior readers of wxph done before overwrite
            #pragma unroll
            for (int m = 0; m < 12; ++m)
                wxph[sA][cA+m] = fmaxf(ac[m] + ws[WS_B1P + i*DD + cA + m], 0.f);
        }
        __syncthreads();
        // layer 2; i=0: q0.pq_j  i=1: k0.pk_j  i=2: v += pv
        {
            float ac[12];
            #pragma unroll
            for (int m = 0; m < 12; ++m) ac[m] = 0.f;
            for (int k = 0; k < DD; ++k) {
                float a = wxph[jB][k];
                const float* wr = posW2 + (i*DD + k)*DD;
                #pragma unroll
                for (int m = 0; m < 12; ++m) ac[m] += a * wr[uB + 16*m];
            }
            if (i == 2) {
                #pragma unroll
                for (int m = 0; m < 12; ++m) {
                    int c = uB + 16*m;
                    vb[jB][c] += ac[m] + posB2[2*DD + c];
                }
            } else {
                float hp[6];
                #pragma unroll
                for (int h = 0; h < 6; ++h) hp[h] = 0.f;
                #pragma unroll
                for (int m = 0; m < 12; ++m) {
                    int c = uB + 16*m;                 // head = m>>1 (static)
                    float pqv = ac[m] + posB2[i*DD + c];
                    float qv = (i == 0) ? q0l[c] : kb[0][c];
                    hp[m >> 1] += qv * pqv;
                }
                #pragma unroll
                for (int h = 0; h < 6; ++h) {
                    float v = hp[h];
                    #pragma unroll
                    for (int off = 1; off < 16; off <<= 1) v += __shfl_xor(v, off, 16);
                    if (uB == 0) { if (i == 0) dq[h][jB] = v; else dk[h][jB] = v; }
                }
            }
        }
    }
    {   // q0 . k_j per head
        float hp[6];
        #pragma unroll
        for (int h = 0; h < 6; ++h) hp[h] = 0.f;
        #pragma unroll
        for (int m = 0; m < 12; ++m) {
            int c = uB + 16*m;
            hp[m >> 1] += q0l[c] * kb[jB][c];
        }
        #pragma unroll
        for (int h = 0; h < 6; ++h) {
            float v = hp[h];
            #pragma unroll
            for (int off = 1; off < 16; off <<= 1) v += __shfl_xor(v, off, 16);
            if (uB == 0) dqk[h][jB] = v;
        }
    }
    __syncthreads();
    if (t < 6) {
        const float scale = 0.17677669529663687f;    // 32^-0.5
        float z[16], mx = -1e30f;
        #pragma unroll
        for (int j = 0; j < 16; ++j) {
            z[j] = (dqk[t][j] + dq[t][j] + dk[t][j]) * scale;
            mx = fmaxf(mx, z[j]);
        }
        float sm = 0.f;
        #pragma unroll
        for (int j = 0; j < 16; ++j) { z[j] = expf(z[j] - mx); sm += z[j]; }
        float inv = 1.f / sm;
        #pragma unroll
        for (int j = 0; j < 16; ++j) attn[t][j] = z[j] * inv;
    }
    __syncthreads();
    if (t < DD) {
        int h = t >> 5;
        float a = 0.f;
        #pragma unroll
        for (int j = 0; j < 16; ++j) a += attn[h][j] * vb[j][t];
        ctr[t] = a;
    }
    __syncthreads();
    if (t < DD) {
        float o = bproj[t];
        for (int k = 0; k < DD; ++k) o += ctr[k] * Wproj[k*DD + t];
        out[n*DD + t] = o;
    }
}

extern "C" void kernel_launch(void* const* d_in, const int* in_sizes, int n_in,
                              void* d_out, int out_size, void* d_ws, size_t ws_size,
                              hipStream_t stream)
{
    const float* p     = (const float*)d_in[0];
    const float* x     = (const float*)d_in[1];
    const int*   knn   = (const int*)  d_in[2];
    const float* Wqkv  = (const float*)d_in[3];
    const float* Wproj = (const float*)d_in[4];
    const float* bproj = (const float*)d_in[5];
    const float* propW = (const float*)d_in[6];
    const float* propB = (const float*)d_in[7];
    const float* gAW   = (const float*)d_in[8];
    const float* gAb   = (const float*)d_in[9];
    const float* gBW   = (const float*)d_in[10];
    const float* gBb   = (const float*)d_in[11];
    const float* gCW   = (const float*)d_in[12];
    const float* gCb   = (const float*)d_in[13];
    const float* posW1 = (const float*)d_in[14];
    const float* posB1 = (const float*)d_in[15];
    const float* gamma = (const float*)d_in[16];
    const float* beta  = (const float*)d_in[17];
    const float* posW2 = (const float*)d_in[18];
    const float* posB2 = (const float*)d_in[19];
    const float* kn    = (const float*)d_in[20];
    const float* deW1  = (const float*)d_in[21];
    const float* deB1  = (const float*)d_in[22];
    const float* deW2  = (const float*)d_in[23];
    const float* deB2  = (const float*)d_in[24];
    const float* kpW   = (const float*)d_in[25];
    const float* kpB   = (const float*)d_in[26];
    const float* fusW  = (const float*)d_in[27];
    const float* fusB  = (const float*)d_in[28];
    float* ws   = (float*)d_ws;
    float* outp = (float*)d_out;

    hipLaunchKernelGGL(k_init, dim3(5), dim3(256), 0, stream, ws);
    hipLaunchKernelGGL(k1_geom_prop, dim3(NP/16), dim3(256), 0, stream,
                       p, x, knn, propW, propB, posW1, posB1, ws);
    hipLaunchKernelGGL(k2_stats, dim3(1), dim3(576), 0, stream,
                       gCW, gCb, posW1, posB1, gamma, beta, ws);
    hipLaunchKernelGGL(k3_fuse, dim3(NP), dim3(256), 0, stream,
                       p, kn, deW1, deB1, deW2, deB2, kpW, kpB,
                       gAW, gAb, gBW, gBb, fusW, fusB, ws);
    hipLaunchKernelGGL(k4_attn, dim3(NP), dim3(256), 0, stream,
                       knn, Wqkv, posW2, posB2, Wproj, bproj, ws, outp);
}

// Round 2
// 4173.573 us; speedup vs baseline: 2.0129x; 2.0129x over previous
//
#include <hip/hip_runtime.h>
#include <math.h>

#define NP 16384
#define DD 192
#define NS 16
#define KSPN 16
#define MTOT (NP*NS)

// ws float offsets
#define WS_KNN   0                         // NP*48   knn_xyz
#define WS_PR    (WS_KNN + NP*48)          // MTOT*3  p_r per window row
#define WS_GEO9  (WS_PR + MTOT*3)          // NP*9
#define WS_GDIS  (WS_GEO9 + NP*9)          // NP
#define WS_STATS (WS_GDIS + NP)            // [0]=dsum [1]=dmax(bits) [2..50)=possum [50..2354)=M2
#define WS_VOLV  (WS_STATS + 2354)         // 192
#define WS_AB    (WS_VOLV + DD)            // a[3][192] | bb[3][192] = 1152
#define WS_X1    (WS_AB + 1152)            // NP*192 post-propagate; later reused as CTR
#define WS_U     (WS_X1 + NP*DD)           // NP*192 pre-fusion features
#define WS_X2    (WS_U + NP*DD)            // NP*192 post-fusion
#define WS_QKV   (WS_X2 + NP*DD)           // NP*576
// total ~20.6M floats ~82.5 MB

__global__ __launch_bounds__(256) void k_init(float* __restrict__ ws) {
    int t = blockIdx.x * 256 + threadIdx.x;
    if (t < 2354) ws[WS_STATS + t] = 0.f;
}

// ---- K1: geometry glue + stats (M2 second-moment, possum, dist stats) ----
__global__ __launch_bounds__(256) void k1_glue(
    const float* __restrict__ p, const int* __restrict__ knn,
    float* __restrict__ ws)
{
    __shared__ float Xl[48];
    __shared__ float pos[NS][49];
    __shared__ float distl[NS];
    __shared__ int idx[NS];
    __shared__ float pn[3];
    const int t = threadIdx.x;
    float m2acc[9];
    #pragma unroll
    for (int q = 0; q < 9; ++q) m2acc[q] = 0.f;
    float psacc = 0.f, dsum_loc = 0.f, dmax_loc = 0.f;

    for (int it = 0; it < 16; ++it) {
        const int n = blockIdx.x * 16 + it;
        __syncthreads();
        if (t < NS) idx[t] = knn[n*NS + t];
        if (t < 3)  pn[t] = p[n*3 + t];
        __syncthreads();
        if (t < 48) { float v = p[idx[t/3]*3 + (t % 3)]; Xl[t] = v; ws[WS_KNN + n*48 + t] = v; }
        __syncthreads();
        if (t < 48) {
            int j = t/3, c = t % 3;
            ws[WS_PR + (n*NS + j)*3 + c] = Xl[t] - pn[c];
        }
        if (t < NS) {
            float dx = Xl[t*3]-pn[0], dy = Xl[t*3+1]-pn[1], dz = Xl[t*3+2]-pn[2];
            distl[t] = sqrtf(dx*dx + dy*dy + dz*dz + 1e-12f);
        }
        for (int e = t; e < NS*48; e += 256) {
            int r = e/48, k = e - r*48;
            pos[r][k] = Xl[k] - Xl[r*3 + (k % 3)];
        }
        __syncthreads();
        if (t == 0) {
            float dm = 0.f, ds = 0.f;
            for (int j = 0; j < NS; ++j) { dm = fmaxf(dm, distl[j]); ds += distl[j]; }
            ws[WS_GDIS + n] = dm;
            dsum_loc += ds; dmax_loc = fmaxf(dmax_loc, dm);
        }
        if (t < 3) {
            float mx = 0.f;
            for (int j = 0; j < NS; ++j) mx += Xl[j*3 + t];
            mx *= (1.f/16.f);
            ws[WS_GEO9 + n*9 + t]     = mx - pn[t];
            ws[WS_GEO9 + n*9 + 3 + t] = mx;
            ws[WS_GEO9 + n*9 + 6 + t] = pn[t];
        }
        {
            int e = t;
            #pragma unroll
            for (int q = 0; q < 9; ++q) {
                int a = e / 48, b = e - a*48;
                float s = 0.f;
                for (int j = 0; j < NS; ++j) s += pos[j][a] * pos[j][b];
                m2acc[q] += s;
                e += 256;
            }
        }
        if (t < 48) { float s = 0.f; for (int j = 0; j < NS; ++j) s += pos[j][t]; psacc += s; }
    }
    {
        int e = t;
        #pragma unroll
        for (int q = 0; q < 9; ++q) { atomicAdd(&ws[WS_STATS + 50 + e], m2acc[q]); e += 256; }
    }
    if (t < 48) atomicAdd(&ws[WS_STATS + 2 + t], psacc);
    if (t == 0) {
        atomicAdd(&ws[WS_STATS + 0], dsum_loc);
        atomicMax((int*)(ws + WS_STATS + 1), __float_as_int(dmax_loc));  // dist>=0
    }
}

// ---- K2: vol vector + BN fold (var via M2) -> a/bb ----
__global__ __launch_bounds__(256) void k2_fold(
    const float* __restrict__ posW1, const float* __restrict__ posB1,
    const float* __restrict__ gamma, const float* __restrict__ beta,
    const float* __restrict__ gCW, const float* __restrict__ gCb,
    float* __restrict__ ws)
{
    __shared__ float M2n[48][48];
    __shared__ float pmean[48];
    __shared__ float Wc[48][193];
    const int t = threadIdx.x;
    const int i = blockIdx.x;
    for (int e = t; e < 2304; e += 256) ((float*)M2n)[e] = ws[WS_STATS + 50 + e] * (1.f/(float)MTOT);
    if (t < 48) pmean[t] = ws[WS_STATS + 2 + t] * (1.f/(float)MTOT);
    if (t < DD) {
        for (int k = 0; k < 48; ++k) Wc[k][t] = posW1[(size_t)(i*48 + k)*DD + t];
    }
    __syncthreads();
    if (i == 0 && t < DD) {
        float dsum = ws[WS_STATS + 0];
        float dmax = __int_as_float(((const int*)(ws + WS_STATS))[1]);
        float vol = (dsum * (1.f/(float)MTOT)) / (dmax + 1e-8f);
        ws[WS_VOLV + t] = vol * gCW[t] + gCb[t];
    }
    if (t < DD) {
        float mu0 = 0.f;
        #pragma unroll 8
        for (int k = 0; k < 48; ++k) mu0 += pmean[k] * Wc[k][t];
        float e2 = 0.f;
        for (int a2 = 0; a2 < 48; ++a2) {
            float inner = 0.f;
            #pragma unroll 8
            for (int b2 = 0; b2 < 48; ++b2) inner += M2n[a2][b2] * Wc[b2][t];
            e2 += Wc[a2][t] * inner;
        }
        float var = fmaxf(e2 - mu0*mu0, 0.f);
        float as = rsqrtf(var + 1e-5f) * gamma[i*DD + t];
        ws[WS_AB + i*DD + t]       = as;
        ws[WS_AB + 576 + i*DD + t] = beta[i*DD + t] - mu0 * as;   // h'=relu(acc*as+bb)
    }
}

// ---- K_prop: gathered GEMM [262144 x 195] @ propW -> relu -> window mean -> X1 ----
__global__ __launch_bounds__(256) void k_prop(
    const float* __restrict__ x, const int* __restrict__ knn,
    const float* __restrict__ propW, const float* __restrict__ propB,
    float* __restrict__ ws)
{
    __shared__ float At[16][68];
    __shared__ float Bt[16][196];
    __shared__ int idx64[64];
    const int t = threadIdx.x;
    const int ty = t >> 4, tx = t & 15;
    const int mbase = blockIdx.x * 64;
    if (t < 64) idx64[t] = knn[mbase + t];
    float acc[4][12];
    #pragma unroll
    for (int a = 0; a < 4; ++a)
        #pragma unroll
        for (int m = 0; m < 12; ++m) acc[a][m] = 0.f;
    __syncthreads();
    for (int kt = 0; kt < 13; ++kt) {
        {   // stage A (gather via knn), transposed
            const int r = t >> 2, kq = t & 3;
            const int k0 = kt*16 + kq*4;
            float4 v;
            if (k0 + 3 < DD) {
                v = *(const float4*)(x + (size_t)idx64[r]*DD + k0);
            } else {
                float tmp[4];
                #pragma unroll
                for (int e = 0; e < 4; ++e) {
                    int k = k0 + e;
                    tmp[e] = (k < DD) ? x[(size_t)idx64[r]*DD + k]
                           : ((k < 195) ? ws[WS_PR + (size_t)(mbase + r)*3 + (k - DD)] : 0.f);
                }
                v = make_float4(tmp[0], tmp[1], tmp[2], tmp[3]);
            }
            At[kq*4+0][r] = v.x; At[kq*4+1][r] = v.y; At[kq*4+2][r] = v.z; At[kq*4+3][r] = v.w;
        }
        for (int e = t; e < 16*48; e += 256) {   // stage B
            int kr = e / 48, cq = e - kr*48;
            int kg = kt*16 + kr;
            float4 v = (kg < 195) ? *(const float4*)(propW + (size_t)kg*DD + cq*4)
                                  : make_float4(0.f, 0.f, 0.f, 0.f);
            *(float4*)&Bt[kr][cq*4] = v;
        }
        __syncthreads();
        #pragma unroll
        for (int k = 0; k < 16; ++k) {
            float4 a4 = *(const float4*)&At[k][ty*4];
            const float* br = &Bt[k][tx*12];
            float b[12];
            #pragma unroll
            for (int m = 0; m < 12; ++m) b[m] = br[m];
            #pragma unroll
            for (int a = 0; a < 4; ++a) {
                float av = (&a4.x)[a];
                #pragma unroll
                for (int m = 0; m < 12; ++m) acc[a][m] += av * b[m];
            }
        }
        __syncthreads();
    }
    {   // relu(acc+bias), sum thread's 4 rows
        #pragma unroll
        for (int m = 0; m < 12; ++m) {
            float bias = propB[tx*12 + m];
            float s = 0.f;
            #pragma unroll
            for (int a = 0; a < 4; ++a) s += fmaxf(acc[a][m] + bias, 0.f);
            Bt[ty][tx*12 + m] = s;
        }
    }
    __syncthreads();
    for (int e = t; e < 4*DD; e += 256) {
        int w = e / DD, c = e - w*DD;
        int n = blockIdx.x*4 + w;
        float s = Bt[w*4+0][c] + Bt[w*4+1][c] + Bt[w*4+2][c] + Bt[w*4+3][c];
        ws[WS_X1 + (size_t)n*DD + c] = x[(size_t)n*DD + c] + s * (1.f/16.f);
    }
}

// ---- Generic tiled GEMM: C[M x N] = A[M x 192] @ B[192 x N] (+bias). BM=64,BN=64 ----
__global__ __launch_bounds__(256) void gemm_bias(
    const float* __restrict__ A, const float* __restrict__ B,
    const float* __restrict__ bias, float* __restrict__ C, int N)
{
    __shared__ float At[16][68];
    __shared__ float Bt[16][68];
    const int t = threadIdx.x;
    const int ty = t >> 4, tx = t & 15;
    const int rowBase = blockIdx.x * 64, colBase = blockIdx.y * 64;
    float acc[4][4];
    #pragma unroll
    for (int a = 0; a < 4; ++a)
        #pragma unroll
        for (int b = 0; b < 4; ++b) acc[a][b] = 0.f;
    for (int kt = 0; kt < 12; ++kt) {
        {
            const int r = t >> 2, kq = t & 3;
            float4 v = *(const float4*)(A + (size_t)(rowBase + r)*192 + kt*16 + kq*4);
            At[kq*4+0][r] = v.x; At[kq*4+1][r] = v.y; At[kq*4+2][r] = v.z; At[kq*4+3][r] = v.w;
        }
        {
            const int kr = t >> 4, cg = t & 15;
            float4 v = *(const float4*)(B + (size_t)(kt*16 + kr)*N + colBase + cg*4);
            *(float4*)&Bt[kr][cg*4] = v;
        }
        __syncthreads();
        #pragma unroll
        for (int k = 0; k < 16; ++k) {
            float4 a4 = *(const float4*)&At[k][ty*4];
            float4 b4 = *(const float4*)&Bt[k][tx*4];
            #pragma unroll
            for (int a = 0; a < 4; ++a) {
                float av = (&a4.x)[a];
                acc[a][0] += av * b4.x; acc[a][1] += av * b4.y;
                acc[a][2] += av * b4.z; acc[a][3] += av * b4.w;
            }
        }
        __syncthreads();
    }
    float bv[4];
    #pragma unroll
    for (int b = 0; b < 4; ++b) bv[b] = bias ? bias[colBase + tx*4 + b] : 0.f;
    #pragma unroll
    for (int a = 0; a < 4; ++a) {
        float4 o = make_float4(acc[a][0]+bv[0], acc[a][1]+bv[1], acc[a][2]+bv[2], acc[a][3]+bv[3]);
        *(float4*)(C + (size_t)(rowBase + ty*4 + a)*N + colBase + tx*4) = o;
    }
}

// ---- K3a: keypoint attention + U assembly (deW2 staged in LDS) ----
__global__ __launch_bounds__(256) void k3a(
    const float* __restrict__ p, const float* __restrict__ kn,
    const float* __restrict__ deW1, const float* __restrict__ deB1,
    const float* __restrict__ deW2, const float* __restrict__ deB2,
    const float* __restrict__ kpW, const float* __restrict__ kpB,
    const float* __restrict__ gAW, const float* __restrict__ gAb,
    const float* __restrict__ gBW, const float* __restrict__ gBb,
    float* __restrict__ ws)
{
    __shared__ float Wd[48][196];
    __shared__ float innr[KSPN][49];
    __shared__ float df[KSPN][193];
    __shared__ float kd[KSPN];
    __shared__ float scl[KSPN];
    const int t = threadIdx.x;
    for (int e = t; e < 48*48; e += 256) {
        int w = e / 48, cq = e - w*48;
        *(float4*)&Wd[w][cq*4] = *(const float4*)(deW2 + (size_t)w*DD + cq*4);
    }
    const int kap = t >> 4, u = t & 15, c0 = u*12;
    for (int it = 0; it < 16; ++it) {
        const int n = blockIdx.x*16 + it;
        __syncthreads();
        if (t < KSPN) {
            float dx = p[n*3]-kn[t*3], dy = p[n*3+1]-kn[t*3+1], dz = p[n*3+2]-kn[t*3+2];
            kd[t] = sqrtf(dx*dx + dy*dy + dz*dz + 1e-12f);
        }
        __syncthreads();
        for (int e = t; e < KSPN*48; e += 256) {
            int r = e / 48, j = e - r*48;
            innr[r][j] = fmaxf(kd[r]*deW1[j] + deB1[j], 0.f);
        }
        __syncthreads();
        float a12[12];
        #pragma unroll
        for (int m = 0; m < 12; ++m) a12[m] = deB2[c0 + m];
        for (int w = 0; w < 48; ++w) {
            float av = innr[kap][w];
            #pragma unroll
            for (int m = 0; m < 12; ++m) a12[m] += av * Wd[w][c0 + m];
        }
        float ksc = 0.f;
        #pragma unroll
        for (int m = 0; m < 12; ++m) { df[kap][c0 + m] = a12[m]; ksc += a12[m]*kpW[c0 + m]; }
        #pragma unroll
        for (int off = 1; off < 16; off <<= 1) ksc += __shfl_xor(ksc, off, 16);
        if (u == 0) scl[kap] = ksc + kpB[0];
        __syncthreads();
        if (t < KSPN) {
            float v = scl[t], mx = v;
            #pragma unroll
            for (int off = 1; off < 16; off <<= 1) mx = fmaxf(mx, __shfl_xor(mx, off, 16));
            float e = expf(v - mx);
            float sm = e;
            #pragma unroll
            for (int off = 1; off < 16; off <<= 1) sm += __shfl_xor(sm, off, 16);
            scl[t] = e / sm;
        }
        __syncthreads();
        if (t < DD) {
            float dfeat = 0.f;
            #pragma unroll
            for (int k2 = 0; k2 < KSPN; ++k2) dfeat += scl[k2]*df[k2][t];
            float uval = ws[WS_X1 + (size_t)n*DD + t] + gAb[t] + gBb[t] + ws[WS_VOLV + t] + dfeat;
            uval += ws[WS_GDIS + n] * gBW[t];
            #pragma unroll
            for (int kk = 0; kk < 9; ++kk) uval += ws[WS_GEO9 + n*9 + kk] * gAW[kk*DD + t];
            ws[WS_U + (size_t)n*DD + t] = uval;
        }
    }
}

// ---- K4c: per-window kernel: pos MLPs layer1 + factored layer2 + attention -> CTR ----
__global__ __launch_bounds__(256) void k4c(
    const int* __restrict__ knn,
    const float* __restrict__ posW1, const float* __restrict__ posW2,
    const float* __restrict__ posB2,
    float* __restrict__ ws)
{
    __shared__ float Hbuf[NS][200];     // K-window -> H'_i -> H'_2
    __shared__ float Wst[48][196];      // posW1_i staging
    __shared__ float pos[NS][49];
    __shared__ float q0s[DD];
    __shared__ float k0s[DD];
    __shared__ float rqk[2][6][DD];     // W2^T_slice @ q0 / k0, per head
    __shared__ float dqk[6][NS];
    __shared__ float dqi[2][6][NS];
    __shared__ float attn[6][NS];
    __shared__ float wsum[6][DD];
    __shared__ float Xl[48];
    __shared__ int idx[NS];
    const int t = threadIdx.x;
    const int n = blockIdx.x;
    const float* QKV = ws + WS_QKV;
    if (t < NS) idx[t] = knn[n*NS + t];
    if (t < 48) Xl[t] = ws[WS_KNN + n*48 + t];
    __syncthreads();
    for (int e = t; e < NS*48; e += 256) {
        int r = e / 48, k = e - r*48;
        pos[r][k] = Xl[k] - Xl[r*3 + (k % 3)];
    }
    const int m0 = idx[0];
    if (t < DD) {
        q0s[t] = QKV[(size_t)m0*576 + t];
        k0s[t] = QKV[(size_t)m0*576 + DD + t];
    }
    for (int e = t; e < NS*48; e += 256) {   // stage K window (16 x 192)
        int r = e / 48, cq = e - r*48;
        *(float4*)&Hbuf[r][cq*4] = *(const float4*)(QKV + (size_t)idx[r]*576 + DD + cq*4);
    }
    __syncthreads();
    {   // dqk[h][j] = q0 . k_j (per head)
        const int j = t >> 4, u = t & 15;
        #pragma unroll
        for (int h = 0; h < 6; ++h) {
            int c = h*32 + u*2;
            float v = q0s[c]*Hbuf[j][c] + q0s[c+1]*Hbuf[j][c+1];
            #pragma unroll
            for (int off = 1; off < 16; off <<= 1) v += __shfl_xor(v, off, 16);
            if (u == 0) dqk[h][j] = v;
        }
    }
    {   // rqk[i][h][kk] = sum_c W2_i[kk][32h+c] * (q0|k0)[32h+c]
        const int c32 = t & 31, kkr = t >> 5;
        #pragma unroll
        for (int i2 = 0; i2 < 2; ++i2) {
            const float* Wb = posW2 + (size_t)i2*DD*DD;
            const float* src = i2 ? k0s : q0s;
            for (int kb = 0; kb < 24; ++kb) {
                int kk = kb*8 + kkr;
                #pragma unroll
                for (int h = 0; h < 6; ++h) {
                    float v = Wb[(size_t)kk*DD + h*32 + c32] * src[h*32 + c32];
                    #pragma unroll
                    for (int off = 1; off < 32; off <<= 1) v += __shfl_xor(v, off, 32);
                    if (c32 == 0) rqk[i2][h][kk] = v;
                }
            }
        }
    }
    __syncthreads();
    for (int i = 0; i < 3; ++i) {
        for (int e = t; e < 48*48; e += 256) {   // stage posW1_i
            int kk = e / 48, cq = e - kk*48;
            *(float4*)&Wst[kk][cq*4] = *(const float4*)(posW1 + (size_t)(i*48 + kk)*DD + cq*4);
        }
        __syncthreads();
        {   // layer1: H'_i = relu((pos @ W1_i)*a + bb)
            const int s = t & 15, u = t >> 4, c0 = u*12;
            float a12[12];
            #pragma unroll
            for (int m = 0; m < 12; ++m) a12[m] = 0.f;
            for (int kk = 0; kk < 48; ++kk) {
                float av = pos[s][kk];
                #pragma unroll
                for (int m = 0; m < 12; ++m) a12[m] += av * Wst[kk][c0 + m];
            }
            #pragma unroll
            for (int m = 0; m < 12; ++m) {
                int c = c0 + m;
                float as = ws[WS_AB + i*DD + c], bb = ws[WS_AB + 576 + i*DD + c];
                Hbuf[s][c] = fmaxf(a12[m]*as + bb, 0.f);
            }
        }
        __syncthreads();
        if (i < 2) {   // dq/dk[h][j] = H'_i[j,:] . rqk[i][h,:]
            const int j = t >> 4, u = t & 15;
            #pragma unroll
            for (int h = 0; h < 6; ++h) {
                float v = 0.f;
                #pragma unroll
                for (int m = 0; m < 12; ++m) v += Hbuf[j][u*12 + m] * rqk[i][h][u*12 + m];
                #pragma unroll
                for (int off = 1; off < 16; off <<= 1) v += __shfl_xor(v, off, 16);
                if (u == 0) dqi[i][h][j] = v;
            }
            __syncthreads();
        }
    }
    if (t < 6) {   // softmax over j per head
        const float scale = 0.17677669529663687f;  // 32^-0.5
        float z[NS], mx = -1e30f;
        #pragma unroll
        for (int j = 0; j < NS; ++j) {
            z[j] = (dqk[t][j] + dqi[0][t][j] + dqi[1][t][j]) * scale;
            mx = fmaxf(mx, z[j]);
        }
        float sm = 0.f;
        #pragma unroll
        for (int j = 0; j < NS; ++j) { z[j] = expf(z[j] - mx); sm += z[j]; }
        float inv = 1.f / sm;
        #pragma unroll
        for (int j = 0; j < NS; ++j) attn[t][j] = z[j] * inv;
    }
    __syncthreads();
    if (t < DD) {   // wsum[h][kk] = sum_j attn[h][j] H'_2[j][kk]
        #pragma unroll
        for (int h = 0; h < 6; ++h) {
            float v = 0.f;
            #pragma unroll
            for (int j = 0; j < NS; ++j) v += attn[h][j] * Hbuf[j][t];
            wsum[h][t] = v;
        }
    }
    __syncthreads();
    if (t < DD) {   // CTR = attn@v + b2_2 + wsum @ W2_2
        const int h = t >> 5;
        float acc = posB2[2*DD + t];
        #pragma unroll
        for (int j = 0; j < NS; ++j) acc += attn[h][j] * QKV[(size_t)idx[j]*576 + 384 + t];
        const float* W2v = posW2 + (size_t)2*DD*DD;
        float pv = 0.f;
        #pragma unroll 4
        for (int kk = 0; kk < DD; ++kk) pv += wsum[h][kk] * W2v[(size_t)kk*DD + t];
        ws[WS_X1 + (size_t)n*DD + t] = acc + pv;   // CTR reuses X1 slot
    }
}

extern "C" void kernel_launch(void* const* d_in, const int* in_sizes, int n_in,
                              void* d_out, int out_size, void* d_ws, size_t ws_size,
                              hipStream_t stream)
{
    const float* p     = (const float*)d_in[0];
    const float* x     = (const float*)d_in[1];
    const int*   knn   = (const int*)  d_in[2];
    const float* Wqkv  = (const float*)d_in[3];
    const float* Wproj = (const float*)d_in[4];
    const float* bproj = (const float*)d_in[5];
    const float* propW = (const float*)d_in[6];
    const float* propB = (const float*)d_in[7];
    const float* gAW   = (const float*)d_in[8];
    const float* gAb   = (const float*)d_in[9];
    const float* gBW   = (const float*)d_in[10];
    const float* gBb   = (const float*)d_in[11];
    const float* gCW   = (const float*)d_in[12];
    const float* gCb   = (const float*)d_in[13];
    const float* posW1 = (const float*)d_in[14];
    const float* posB1 = (const float*)d_in[15];
    const float* gamma = (const float*)d_in[16];
    const float* beta  = (const float*)d_in[17];
    const float* posW2 = (const float*)d_in[18];
    const float* posB2 = (const float*)d_in[19];
    const float* kn    = (const float*)d_in[20];
    const float* deW1  = (const float*)d_in[21];
    const float* deB1  = (const float*)d_in[22];
    const float* deW2  = (const float*)d_in[23];
    const float* deB2  = (const float*)d_in[24];
    const float* kpW   = (const float*)d_in[25];
    const float* kpB   = (const float*)d_in[26];
    const float* fusW  = (const float*)d_in[27];
    const float* fusB  = (const float*)d_in[28];
    float* ws   = (float*)d_ws;
    float* outp = (float*)d_out;

    hipLaunchKernelGGL(k_init, dim3(10), dim3(256), 0, stream, ws);
    hipLaunchKernelGGL(k1_glue, dim3(NP/16), dim3(256), 0, stream, p, knn, ws);
    hipLaunchKernelGGL(k2_fold, dim3(3), dim3(256), 0, stream,
                       posW1, posB1, gamma, beta, gCW, gCb, ws);
    hipLaunchKernelGGL(k_prop, dim3(MTOT/64), dim3(256), 0, stream, x, knn, propW, propB, ws);
    hipLaunchKernelGGL(k3a, dim3(NP/16), dim3(256), 0, stream,
                       p, kn, deW1, deB1, deW2, deB2, kpW, kpB, gAW, gAb, gBW, gBb, ws);
    hipLaunchKernelGGL(gemm_bias, dim3(NP/64, 3), dim3(256), 0, stream,
                       ws + WS_U, fusW, fusB, ws + WS_X2, DD);        // X2 = U@fusW+fusB
    hipLaunchKernelGGL(gemm_bias, dim3(NP/64, 9), dim3(256), 0, stream,
                       ws + WS_X2, Wqkv, (const float*)nullptr, ws + WS_QKV, 576);  // QKV
    hipLaunchKernelGGL(k4c, dim3(NP), dim3(256), 0, stream, knn, posW1, posW2, posB2, ws);
    hipLaunchKernelGGL(gemm_bias, dim3(NP/64, 3), dim3(256), 0, stream,
                       ws + WS_X1, Wproj, bproj, outp, DD);           // OUT = CTR@Wproj+bproj
}

// Round 3
// 1720.983 us; speedup vs baseline: 4.8814x; 2.4251x over previous
//
#include <hip/hip_runtime.h>
#include <math.h>

#define NP 16384
#define DD 192
#define NS 16
#define KSPN 16
#define MTOT (NP*NS)

// ws float offsets
#define WS_KNN   0                         // NP*48   knn_xyz
#define WS_PR    (WS_KNN + NP*48)          // MTOT*3  p_r per window row
#define WS_GEO9  (WS_PR + MTOT*3)          // NP*9
#define WS_GDIS  (WS_GEO9 + NP*9)          // NP
#define WS_STATS (WS_GDIS + NP)            // [0]=dsum [1]=dmax(bits) [2..50)=possum [50..2354)=M2
#define WS_VOLV  (WS_STATS + 2354)         // 192
#define WS_AB    (WS_VOLV + DD)            // a[3][192] | bb[3][192] = 1152
#define WS_X1    (WS_AB + 1152)            // NP*192 post-propagate; later CTR1 (attn@v)
#define WS_U     (WS_X1 + NP*DD)           // NP*192 pre-fusion; later CTR final
#define WS_X2    (WS_U + NP*DD)            // NP*192 post-fusion
#define WS_QKV   (WS_X2 + NP*DD)           // NP*576
#define WS_SC    (WS_QKV + NP*576)         // NP*192  SC[n][i(2)][h(6)][j(16)]
#define WS_ATTN  (WS_SC + NP*DD)           // NP*96   attn[n][h][j]
// total ~25.3M floats ~101 MB

__global__ __launch_bounds__(256) void k_init(float* __restrict__ ws) {
    int t = blockIdx.x * 256 + threadIdx.x;
    if (t < 2354) ws[WS_STATS + t] = 0.f;
}

// ---- K1: geometry glue + stats (M2 second-moment, possum, dist stats) ----
__global__ __launch_bounds__(256) void k1_glue(
    const float* __restrict__ p, const int* __restrict__ knn,
    float* __restrict__ ws)
{
    __shared__ float Xl[48];
    __shared__ float pos[NS][49];
    __shared__ float distl[NS];
    __shared__ int idx[NS];
    __shared__ float pn[3];
    const int t = threadIdx.x;
    float m2acc[9];
    #pragma unroll
    for (int q = 0; q < 9; ++q) m2acc[q] = 0.f;
    float psacc = 0.f, dsum_loc = 0.f, dmax_loc = 0.f;

    for (int it = 0; it < 16; ++it) {
        const int n = blockIdx.x * 16 + it;
        __syncthreads();
        if (t < NS) idx[t] = knn[n*NS + t];
        if (t < 3)  pn[t] = p[n*3 + t];
        __syncthreads();
        if (t < 48) { float v = p[idx[t/3]*3 + (t % 3)]; Xl[t] = v; ws[WS_KNN + n*48 + t] = v; }
        __syncthreads();
        if (t < 48) {
            int j = t/3, c = t % 3;
            ws[WS_PR + (n*NS + j)*3 + c] = Xl[t] - pn[c];
        }
        if (t < NS) {
            float dx = Xl[t*3]-pn[0], dy = Xl[t*3+1]-pn[1], dz = Xl[t*3+2]-pn[2];
            distl[t] = sqrtf(dx*dx + dy*dy + dz*dz + 1e-12f);
        }
        for (int e = t; e < NS*48; e += 256) {
            int r = e/48, k = e - r*48;
            pos[r][k] = Xl[k] - Xl[r*3 + (k % 3)];
        }
        __syncthreads();
        if (t == 0) {
            float dm = 0.f, ds = 0.f;
            for (int j = 0; j < NS; ++j) { dm = fmaxf(dm, distl[j]); ds += distl[j]; }
            ws[WS_GDIS + n] = dm;
            dsum_loc += ds; dmax_loc = fmaxf(dmax_loc, dm);
        }
        if (t < 3) {
            float mx = 0.f;
            for (int j = 0; j < NS; ++j) mx += Xl[j*3 + t];
            mx *= (1.f/16.f);
            ws[WS_GEO9 + n*9 + t]     = mx - pn[t];
            ws[WS_GEO9 + n*9 + 3 + t] = mx;
            ws[WS_GEO9 + n*9 + 6 + t] = pn[t];
        }
        {
            int e = t;
            #pragma unroll
            for (int q = 0; q < 9; ++q) {
                int a = e / 48, b = e - a*48;
                float s = 0.f;
                for (int j = 0; j < NS; ++j) s += pos[j][a] * pos[j][b];
                m2acc[q] += s;
                e += 256;
            }
        }
        if (t < 48) { float s = 0.f; for (int j = 0; j < NS; ++j) s += pos[j][t]; psacc += s; }
    }
    {
        int e = t;
        #pragma unroll
        for (int q = 0; q < 9; ++q) { atomicAdd(&ws[WS_STATS + 50 + e], m2acc[q]); e += 256; }
    }
    if (t < 48) atomicAdd(&ws[WS_STATS + 2 + t], psacc);
    if (t == 0) {
        atomicAdd(&ws[WS_STATS + 0], dsum_loc);
        atomicMax((int*)(ws + WS_STATS + 1), __float_as_int(dmax_loc));  // dist>=0
    }
}

// ---- K2: vol vector + BN fold (var via M2) -> a/bb ----
__global__ __launch_bounds__(256) void k2_fold(
    const float* __restrict__ posW1, const float* __restrict__ posB1,
    const float* __restrict__ gamma, const float* __restrict__ beta,
    const float* __restrict__ gCW, const float* __restrict__ gCb,
    float* __restrict__ ws)
{
    __shared__ float M2n[48][48];
    __shared__ float pmean[48];
    __shared__ float Wc[48][193];
    const int t = threadIdx.x;
    const int i = blockIdx.x;
    for (int e = t; e < 2304; e += 256) ((float*)M2n)[e] = ws[WS_STATS + 50 + e] * (1.f/(float)MTOT);
    if (t < 48) pmean[t] = ws[WS_STATS + 2 + t] * (1.f/(float)MTOT);
    if (t < DD) {
        for (int k = 0; k < 48; ++k) Wc[k][t] = posW1[(size_t)(i*48 + k)*DD + t];
    }
    __syncthreads();
    if (i == 0 && t < DD) {
        float dsum = ws[WS_STATS + 0];
        float dmax = __int_as_float(((const int*)(ws + WS_STATS))[1]);
        float vol = (dsum * (1.f/(float)MTOT)) / (dmax + 1e-8f);
        ws[WS_VOLV + t] = vol * gCW[t] + gCb[t];
    }
    if (t < DD) {
        float mu0 = 0.f;
        #pragma unroll 8
        for (int k = 0; k < 48; ++k) mu0 += pmean[k] * Wc[k][t];
        float e2 = 0.f;
        for (int a2 = 0; a2 < 48; ++a2) {
            float inner = 0.f;
            #pragma unroll 8
            for (int b2 = 0; b2 < 48; ++b2) inner += M2n[a2][b2] * Wc[b2][t];
            e2 += Wc[a2][t] * inner;
        }
        float var = fmaxf(e2 - mu0*mu0, 0.f);
        float as = rsqrtf(var + 1e-5f) * gamma[i*DD + t];
        ws[WS_AB + i*DD + t]       = as;
        ws[WS_AB + 576 + i*DD + t] = beta[i*DD + t] - mu0 * as;   // h'=relu(acc*as+bb)
    }
}

// ---- K_prop: gathered GEMM [262144 x 195] @ propW -> relu -> window mean -> X1 ----
__global__ __launch_bounds__(256) void k_prop(
    const float* __restrict__ x, const int* __restrict__ knn,
    const float* __restrict__ propW, const float* __restrict__ propB,
    float* __restrict__ ws)
{
    __shared__ float At[16][68];
    __shared__ float Bt[16][196];
    __shared__ int idx64[64];
    const int t = threadIdx.x;
    const int ty = t >> 4, tx = t & 15;
    const int mbase = blockIdx.x * 64;
    if (t < 64) idx64[t] = knn[mbase + t];
    float acc[4][12];
    #pragma unroll
    for (int a = 0; a < 4; ++a)
        #pragma unroll
        for (int m = 0; m < 12; ++m) acc[a][m] = 0.f;
    __syncthreads();
    for (int kt = 0; kt < 13; ++kt) {
        {   // stage A (gather via knn), transposed
            const int r = t >> 2, kq = t & 3;
            const int k0 = kt*16 + kq*4;
            float4 v;
            if (k0 + 3 < DD) {
                v = *(const float4*)(x + (size_t)idx64[r]*DD + k0);
            } else {
                float tmp[4];
                #pragma unroll
                for (int e = 0; e < 4; ++e) {
                    int k = k0 + e;
                    tmp[e] = (k < DD) ? x[(size_t)idx64[r]*DD + k]
                           : ((k < 195) ? ws[WS_PR + (size_t)(mbase + r)*3 + (k - DD)] : 0.f);
                }
                v = make_float4(tmp[0], tmp[1], tmp[2], tmp[3]);
            }
            At[kq*4+0][r] = v.x; At[kq*4+1][r] = v.y; At[kq*4+2][r] = v.z; At[kq*4+3][r] = v.w;
        }
        for (int e = t; e < 16*48; e += 256) {   // stage B
            int kr = e / 48, cq = e - kr*48;
            int kg = kt*16 + kr;
            float4 v = (kg < 195) ? *(const float4*)(propW + (size_t)kg*DD + cq*4)
                                  : make_float4(0.f, 0.f, 0.f, 0.f);
            *(float4*)&Bt[kr][cq*4] = v;
        }
        __syncthreads();
        #pragma unroll
        for (int k = 0; k < 16; ++k) {
            float4 a4 = *(const float4*)&At[k][ty*4];
            const float* br = &Bt[k][tx*12];
            float b[12];
            #pragma unroll
            for (int m = 0; m < 12; ++m) b[m] = br[m];
            #pragma unroll
            for (int a = 0; a < 4; ++a) {
                float av = (&a4.x)[a];
                #pragma unroll
                for (int m = 0; m < 12; ++m) acc[a][m] += av * b[m];
            }
        }
        __syncthreads();
    }
    {   // relu(acc+bias), sum thread's 4 rows
        #pragma unroll
        for (int m = 0; m < 12; ++m) {
            float bias = propB[tx*12 + m];
            float s = 0.f;
            #pragma unroll
            for (int a = 0; a < 4; ++a) s += fmaxf(acc[a][m] + bias, 0.f);
            Bt[ty][tx*12 + m] = s;
        }
    }
    __syncthreads();
    for (int e = t; e < 4*DD; e += 256) {
        int w = e / DD, c = e - w*DD;
        int n = blockIdx.x*4 + w;
        float s = Bt[w*4+0][c] + Bt[w*4+1][c] + Bt[w*4+2][c] + Bt[w*4+3][c];
        ws[WS_X1 + (size_t)n*DD + c] = x[(size_t)n*DD + c] + s * (1.f/16.f);
    }
}

// ---- Generic tiled GEMM: C[M x N] = A[M x 192] @ B[192 x N] (+bias). BM=64,BN=64 ----
__global__ __launch_bounds__(256) void gemm_bias(
    const float* __restrict__ A, const float* __restrict__ B,
    const float* __restrict__ bias, float* __restrict__ C, int N)
{
    __shared__ float At[16][68];
    __shared__ float Bt[16][68];
    const int t = threadIdx.x;
    const int ty = t >> 4, tx = t & 15;
    const int rowBase = blockIdx.x * 64, colBase = blockIdx.y * 64;
    float acc[4][4];
    #pragma unroll
    for (int a = 0; a < 4; ++a)
        #pragma unroll
        for (int b = 0; b < 4; ++b) acc[a][b] = 0.f;
    for (int kt = 0; kt < 12; ++kt) {
        {
            const int r = t >> 2, kq = t & 3;
            float4 v = *(const float4*)(A + (size_t)(rowBase + r)*192 + kt*16 + kq*4);
            At[kq*4+0][r] = v.x; At[kq*4+1][r] = v.y; At[kq*4+2][r] = v.z; At[kq*4+3][r] = v.w;
        }
        {
            const int kr = t >> 4, cg = t & 15;
            float4 v = *(const float4*)(B + (size_t)(kt*16 + kr)*N + colBase + cg*4);
            *(float4*)&Bt[kr][cg*4] = v;
        }
        __syncthreads();
        #pragma unroll
        for (int k = 0; k < 16; ++k) {
            float4 a4 = *(const float4*)&At[k][ty*4];
            float4 b4 = *(const float4*)&Bt[k][tx*4];
            #pragma unroll
            for (int a = 0; a < 4; ++a) {
                float av = (&a4.x)[a];
                acc[a][0] += av * b4.x; acc[a][1] += av * b4.y;
                acc[a][2] += av * b4.z; acc[a][3] += av * b4.w;
            }
        }
        __syncthreads();
    }
    float bv[4];
    #pragma unroll
    for (int b = 0; b < 4; ++b) bv[b] = bias ? bias[colBase + tx*4 + b] : 0.f;
    #pragma unroll
    for (int a = 0; a < 4; ++a) {
        float4 o = make_float4(acc[a][0]+bv[0], acc[a][1]+bv[1], acc[a][2]+bv[2], acc[a][3]+bv[3]);
        *(float4*)(C + (size_t)(rowBase + ty*4 + a)*N + colBase + tx*4) = o;
    }
}

// ---- K3a: keypoint attention + U assembly (deW2 staged in LDS) ----
__global__ __launch_bounds__(256) void k3a(
    const float* __restrict__ p, const float* __restrict__ kn,
    const float* __restrict__ deW1, const float* __restrict__ deB1,
    const float* __restrict__ deW2, const float* __restrict__ deB2,
    const float* __restrict__ kpW, const float* __restrict__ kpB,
    const float* __restrict__ gAW, const float* __restrict__ gAb,
    const float* __restrict__ gBW, const float* __restrict__ gBb,
    float* __restrict__ ws)
{
    __shared__ float Wd[48][196];
    __shared__ float innr[KSPN][49];
    __shared__ float df[KSPN][193];
    __shared__ float kd[KSPN];
    __shared__ float scl[KSPN];
    const int t = threadIdx.x;
    for (int e = t; e < 48*48; e += 256) {
        int w = e / 48, cq = e - w*48;
        *(float4*)&Wd[w][cq*4] = *(const float4*)(deW2 + (size_t)w*DD + cq*4);
    }
    const int kap = t >> 4, u = t & 15, c0 = u*12;
    for (int it = 0; it < 16; ++it) {
        const int n = blockIdx.x*16 + it;
        __syncthreads();
        if (t < KSPN) {
            float dx = p[n*3]-kn[t*3], dy = p[n*3+1]-kn[t*3+1], dz = p[n*3+2]-kn[t*3+2];
            kd[t] = sqrtf(dx*dx + dy*dy + dz*dz + 1e-12f);
        }
        __syncthreads();
        for (int e = t; e < KSPN*48; e += 256) {
            int r = e / 48, j = e - r*48;
            innr[r][j] = fmaxf(kd[r]*deW1[j] + deB1[j], 0.f);
        }
        __syncthreads();
        float a12[12];
        #pragma unroll
        for (int m = 0; m < 12; ++m) a12[m] = deB2[c0 + m];
        for (int w = 0; w < 48; ++w) {
            float av = innr[kap][w];
            #pragma unroll
            for (int m = 0; m < 12; ++m) a12[m] += av * Wd[w][c0 + m];
        }
        float ksc = 0.f;
        #pragma unroll
        for (int m = 0; m < 12; ++m) { df[kap][c0 + m] = a12[m]; ksc += a12[m]*kpW[c0 + m]; }
        #pragma unroll
        for (int off = 1; off < 16; off <<= 1) ksc += __shfl_xor(ksc, off, 16);
        if (u == 0) scl[kap] = ksc + kpB[0];
        __syncthreads();
        if (t < KSPN) {
            float v = scl[t], mx = v;
            #pragma unroll
            for (int off = 1; off < 16; off <<= 1) mx = fmaxf(mx, __shfl_xor(mx, off, 16));
            float e = expf(v - mx);
            float sm = e;
            #pragma unroll
            for (int off = 1; off < 16; off <<= 1) sm += __shfl_xor(sm, off, 16);
            scl[t] = e / sm;
        }
        __syncthreads();
        if (t < DD) {
            float dfeat = 0.f;
            #pragma unroll
            for (int k2 = 0; k2 < KSPN; ++k2) dfeat += scl[k2]*df[k2][t];
            float uval = ws[WS_X1 + (size_t)n*DD + t] + gAb[t] + gBb[t] + ws[WS_VOLV + t] + dfeat;
            uval += ws[WS_GDIS + n] * gBW[t];
            #pragma unroll
            for (int kk = 0; kk < 9; ++kk) uval += ws[WS_GEO9 + n*9 + kk] * gAW[kk*DD + t];
            ws[WS_U + (size_t)n*DD + t] = uval;
        }
    }
}

// ---- K_dqdk: 2 windows/block. rq/rk via LDS-streamed W2 slices, then fused
//      H_i rows (BN-folded) + contraction -> SC[n][i][h][j] ----
__global__ __launch_bounds__(256) void k_dqdk(
    const int* __restrict__ knn,
    const float* __restrict__ posW1, const float* __restrict__ posW2,
    float* __restrict__ ws)
{
    __shared__ float Wbuf[48][196];     // W2 chunk [32][196] or W1 [48][196]
    __shared__ float rqs[2][6][196];
    __shared__ float q0s[2][192];
    __shared__ float k0s[2][192];
    __shared__ float Xl[2][48];
    __shared__ int idx0[2];
    const int t = threadIdx.x;
    const int nb = blockIdx.x*2;
    if (t < 96) { int w = t/48, k = t%48; Xl[w][k] = ws[WS_KNN + (size_t)(nb+w)*48 + k]; }
    if (t < 2) idx0[t] = knn[(nb+t)*NS];
    __syncthreads();
    for (int e = t; e < 384; e += 256) {
        int w = e/192, c = e%192;
        q0s[w][c] = ws[WS_QKV + (size_t)idx0[w]*576 + c];
        k0s[w][c] = ws[WS_QKV + (size_t)idx0[w]*576 + 192 + c];
    }
    const int j  = t >> 3;             // 0..31: window row (w=j>>4, jl=j&15)
    const int cg = t & 7;              // col group
    const int c0 = cg*24;
    const int w  = j >> 4, jl = j & 15;
    // hoist this row's 3 center coords (pos[jl][k] = Xl[k] - Xl[jl*3 + k%3])
    __syncthreads();
    const float px = Xl[w][jl*3], py = Xl[w][jl*3+1], pz = Xl[w][jl*3+2];
    for (int i = 0; i < 2; ++i) {
        const float* W2 = posW2 + (size_t)i*DD*DD;
        // rq[w][h][kk] = sum_c W2[kk][32h+c] * (q0|k0)[w][32h+c], streamed in 32-kk chunks
        for (int ch = 0; ch < 6; ++ch) {
            __syncthreads();
            for (int e = t; e < 32*48; e += 256) {
                int kkl = e/48, cq = e%48;
                *(float4*)&Wbuf[kkl][cq*4] = *(const float4*)(W2 + (size_t)(ch*32+kkl)*DD + cq*4);
            }
            __syncthreads();
            for (int e = t; e < 384; e += 256) {
                int ww = e/192, r = e%192, h = r>>5, kkl = r&31;
                const float* s0 = (i==0) ? q0s[ww] : k0s[ww];
                float acc = 0.f;
                #pragma unroll
                for (int c = 0; c < 32; ++c) acc += Wbuf[kkl][h*32+c] * s0[h*32+c];
                rqs[ww][h][ch*32+kkl] = acc;
            }
        }
        __syncthreads();
        for (int e = t; e < 48*48; e += 256) {     // stage W1_i
            int kk = e/48, cq = e%48;
            *(float4*)&Wbuf[kk][cq*4] = *(const float4*)(posW1 + (size_t)(i*48+kk)*DD + cq*4);
        }
        __syncthreads();
        // H row j, cols c0..c0+23, then contract with rqs
        float acc[24];
        #pragma unroll
        for (int m = 0; m < 24; ++m) acc[m] = 0.f;
        #pragma unroll
        for (int k = 0; k < 48; ++k) {
            float ctr = (k % 3 == 0) ? px : ((k % 3 == 1) ? py : pz);
            float av = Xl[w][k] - ctr;
            #pragma unroll
            for (int m = 0; m < 24; ++m) acc[m] += av * Wbuf[k][c0+m];
        }
        #pragma unroll
        for (int m = 0; m < 24; ++m) {
            int c = c0 + m;
            float as = ws[WS_AB + i*DD + c], bb = ws[WS_AB + 576 + i*DD + c];
            acc[m] = fmaxf(acc[m]*as + bb, 0.f);
        }
        #pragma unroll
        for (int h = 0; h < 6; ++h) {
            float s = 0.f;
            #pragma unroll
            for (int m = 0; m < 24; ++m) s += acc[m] * rqs[w][h][c0+m];
            s += __shfl_xor(s, 1, 8); s += __shfl_xor(s, 2, 8); s += __shfl_xor(s, 4, 8);
            if (cg == 0) ws[WS_SC + (size_t)(nb+w)*192 + i*96 + h*16 + jl] = s;
        }
    }
}

// ---- K_score: q0.k_j dots + softmax + CTR1 = attn@v; stores attn ----
__global__ __launch_bounds__(256) void k_score(
    const int* __restrict__ knn, float* __restrict__ ws)
{
    __shared__ float Kw[NS][196];
    __shared__ float Vw[NS][196];
    __shared__ float q0s[192];
    __shared__ float dqks[6][16];
    __shared__ float attns[6][16];
    __shared__ int idx[NS];
    const int n = blockIdx.x;
    const int t = threadIdx.x;
    if (t < NS) idx[t] = knn[n*NS + t];
    __syncthreads();
    for (int e = t; e < NS*48; e += 256) {
        int r = e/48, cq = e%48;
        *(float4*)&Kw[r][cq*4] = *(const float4*)(ws + WS_QKV + (size_t)idx[r]*576 + 192 + cq*4);
        *(float4*)&Vw[r][cq*4] = *(const float4*)(ws + WS_QKV + (size_t)idx[r]*576 + 384 + cq*4);
    }
    if (t < DD) q0s[t] = ws[WS_QKV + (size_t)idx[0]*576 + t];
    __syncthreads();
    {   // dqk[h][j] = q0 . k_j per head
        const int j = t >> 4, u = t & 15;
        #pragma unroll
        for (int h = 0; h < 6; ++h) {
            int c = h*32 + u*2;
            float v = q0s[c]*Kw[j][c] + q0s[c+1]*Kw[j][c+1];
            #pragma unroll
            for (int off = 1; off < 16; off <<= 1) v += __shfl_xor(v, off, 16);
            if (u == 0) dqks[h][j] = v;
        }
    }
    __syncthreads();
    if (t < 96) {   // softmax rows: h = t>>4, jj = t&15
        const float scale = 0.17677669529663687f;  // 32^-0.5
        const int h = t >> 4, jj = t & 15;
        float z = (dqks[h][jj]
                 + ws[WS_SC + (size_t)n*192 + h*16 + jj]
                 + ws[WS_SC + (size_t)n*192 + 96 + h*16 + jj]) * scale;
        float mx = z;
        #pragma unroll
        for (int off = 1; off < 16; off <<= 1) mx = fmaxf(mx, __shfl_xor(mx, off, 16));
        float e = expf(z - mx);
        float sm = e;
        #pragma unroll
        for (int off = 1; off < 16; off <<= 1) sm += __shfl_xor(sm, off, 16);
        float a = e / sm;
        attns[h][jj] = a;
        ws[WS_ATTN + (size_t)n*96 + h*16 + jj] = a;
    }
    __syncthreads();
    if (t < DD) {   // CTR1 = attn@v
        const int h = t >> 5;
        float s = 0.f;
        #pragma unroll
        for (int jj = 0; jj < NS; ++jj) s += attns[h][jj] * Vw[jj][t];
        ws[WS_X1 + (size_t)n*DD + t] = s;
    }
}

// ---- K_pv: 2 windows/block. H2 rows -> wsum = attn@H2 -> pv = wsum@W2_2
//      CTR = CTR1 + pv + b2_2 ----
__global__ __launch_bounds__(256) void k_pv(
    const float* __restrict__ posW1, const float* __restrict__ posW2,
    const float* __restrict__ posB2, float* __restrict__ ws)
{
    __shared__ float Wbuf[48][196];     // W1_2, then W2_2 chunks [32][196]
    __shared__ float H2[32][196];
    __shared__ float wsum[2][6][196];
    __shared__ float attns[2][96];
    __shared__ float Xl[2][48];
    const int t = threadIdx.x;
    const int nb = blockIdx.x*2;
    if (t < 96) { int w = t/48, k = t%48; Xl[w][k] = ws[WS_KNN + (size_t)(nb+w)*48 + k]; }
    if (t < 192) { int w = t/96, r = t%96; attns[w][r] = ws[WS_ATTN + (size_t)(nb+w)*96 + r]; }
    for (int e = t; e < 48*48; e += 256) {     // stage W1_2
        int kk = e/48, cq = e%48;
        *(float4*)&Wbuf[kk][cq*4] = *(const float4*)(posW1 + (size_t)(2*48+kk)*DD + cq*4);
    }
    __syncthreads();
    {   // H2 row j
        const int j = t >> 3, cg = t & 7, c0 = cg*24;
        const int w = j >> 4, jl = j & 15;
        const float px = Xl[w][jl*3], py = Xl[w][jl*3+1], pz = Xl[w][jl*3+2];
        float acc[24];
        #pragma unroll
        for (int m = 0; m < 24; ++m) acc[m] = 0.f;
        #pragma unroll
        for (int k = 0; k < 48; ++k) {
            float ctr = (k % 3 == 0) ? px : ((k % 3 == 1) ? py : pz);
            float av = Xl[w][k] - ctr;
            #pragma unroll
            for (int m = 0; m < 24; ++m) acc[m] += av * Wbuf[k][c0+m];
        }
        #pragma unroll
        for (int m = 0; m < 24; ++m) {
            int c = c0 + m;
            float as = ws[WS_AB + 2*DD + c], bb = ws[WS_AB + 576 + 2*DD + c];
            H2[j][c] = fmaxf(acc[m]*as + bb, 0.f);
        }
    }
    __syncthreads();
    for (int e = t; e < 2304; e += 256) {   // wsum[w][h][kk] = sum_j attn * H2
        int w = e/1152, r = e%1152, h = r/192, kk = r%192;
        float s = 0.f;
        #pragma unroll
        for (int jj = 0; jj < NS; ++jj) s += attns[w][h*16+jj] * H2[w*16+jj][kk];
        wsum[w][h][kk] = s;
    }
    float pvacc[2] = {0.f, 0.f};
    for (int ch = 0; ch < 6; ++ch) {        // pv += wsum_chunk @ W2_2_chunk
        __syncthreads();
        for (int e = t; e < 32*48; e += 256) {
            int kkl = e/48, cq = e%48;
            *(float4*)&Wbuf[kkl][cq*4] =
                *(const float4*)(posW2 + (size_t)(2*DD + ch*32 + kkl)*DD + cq*4);
        }
        __syncthreads();
        for (int e = t, q = 0; e < 384; e += 256, ++q) {
            int w = e/192, c = e%192, h = c>>5;
            float s = 0.f;
            #pragma unroll
            for (int kkl = 0; kkl < 32; ++kkl) s += wsum[w][h][ch*32+kkl] * Wbuf[kkl][c];
            pvacc[q] += s;
        }
    }
    __syncthreads();
    for (int e = t, q = 0; e < 384; e += 256, ++q) {
        int w = e/192, c = e%192;
        ws[WS_U + (size_t)(nb+w)*DD + c] =
            ws[WS_X1 + (size_t)(nb+w)*DD + c] + pvacc[q] + posB2[2*DD + c];
    }
}

extern "C" void kernel_launch(void* const* d_in, const int* in_sizes, int n_in,
                              void* d_out, int out_size, void* d_ws, size_t ws_size,
                              hipStream_t stream)
{
    const float* p     = (const float*)d_in[0];
    const float* x     = (const float*)d_in[1];
    const int*   knn   = (const int*)  d_in[2];
    const float* Wqkv  = (const float*)d_in[3];
    const float* Wproj = (const float*)d_in[4];
    const float* bproj = (const float*)d_in[5];
    const float* propW = (const float*)d_in[6];
    const float* propB = (const float*)d_in[7];
    const float* gAW   = (const float*)d_in[8];
    const float* gAb   = (const float*)d_in[9];
    const float* gBW   = (const float*)d_in[10];
    const float* gBb   = (const float*)d_in[11];
    const float* gCW   = (const float*)d_in[12];
    const float* gCb   = (const float*)d_in[13];
    const float* posW1 = (const float*)d_in[14];
    const float* posB1 = (const float*)d_in[15];
    const float* gamma = (const float*)d_in[16];
    const float* beta  = (const float*)d_in[17];
    const float* posW2 = (const float*)d_in[18];
    const float* posB2 = (const float*)d_in[19];
    const float* kn    = (const float*)d_in[20];
    const float* deW1  = (const float*)d_in[21];
    const float* deB1  = (const float*)d_in[22];
    const float* deW2  = (const float*)d_in[23];
    const float* deB2  = (const float*)d_in[24];
    const float* kpW   = (const float*)d_in[25];
    const float* kpB   = (const float*)d_in[26];
    const float* fusW  = (const float*)d_in[27];
    const float* fusB  = (const float*)d_in[28];
    float* ws   = (float*)d_ws;
    float* outp = (float*)d_out;

    hipLaunchKernelGGL(k_init, dim3(10), dim3(256), 0, stream, ws);
    hipLaunchKernelGGL(k1_glue, dim3(NP/16), dim3(256), 0, stream, p, knn, ws);
    hipLaunchKernelGGL(k2_fold, dim3(3), dim3(256), 0, stream,
                       posW1, posB1, gamma, beta, gCW, gCb, ws);
    hipLaunchKernelGGL(k_prop, dim3(MTOT/64), dim3(256), 0, stream, x, knn, propW, propB, ws);
    hipLaunchKernelGGL(k3a, dim3(NP/16), dim3(256), 0, stream,
                       p, kn, deW1, deB1, deW2, deB2, kpW, kpB, gAW, gAb, gBW, gBb, ws);
    hipLaunchKernelGGL(gemm_bias, dim3(NP/64, 3), dim3(256), 0, stream,
                       ws + WS_U, fusW, fusB, ws + WS_X2, DD);        // X2 = U@fusW+fusB
    hipLaunchKernelGGL(gemm_bias, dim3(NP/64, 9), dim3(256), 0, stream,
                       ws + WS_X2, Wqkv, (const float*)nullptr, ws + WS_QKV, 576);  // QKV
    hipLaunchKernelGGL(k_dqdk, dim3(NP/2), dim3(256), 0, stream, knn, posW1, posW2, ws);
    hipLaunchKernelGGL(k_score, dim3(NP), dim3(256), 0, stream, knn, ws);
    hipLaunchKernelGGL(k_pv, dim3(NP/2), dim3(256), 0, stream, posW1, posW2, posB2, ws);
    hipLaunchKernelGGL(gemm_bias, dim3(NP/64, 3), dim3(256), 0, stream,
                       ws + WS_U, Wproj, bproj, outp, DD);            // OUT = CTR@Wproj+bproj
}

// Round 4
// 1565.362 us; speedup vs baseline: 5.3667x; 1.0994x over previous
//
#include <hip/hip_runtime.h>
#include <math.h>

#define NP 16384
#define DD 192
#define NS 16
#define KSPN 16
#define MTOT (NP*NS)

// ws float offsets
#define WS_KNN   0                         // NP*48   knn_xyz
#define WS_PR    (WS_KNN + NP*48)          // MTOT*3  p_r per window row
#define WS_GEO9  (WS_PR + MTOT*3)          // NP*9
#define WS_GDIS  (WS_GEO9 + NP*9)          // NP
#define WS_STATS (WS_GDIS + NP)            // [0]=dsum [1]=dmax(bits) [2..50)=possum [50..2354)=M2
#define WS_VOLV  (WS_STATS + 2354)         // 192
#define WS_AB    (WS_VOLV + DD)            // a[3][192] | bb[3][192] = 1152
#define WS_X1    (WS_AB + 1152)            // NP*192 post-propagate; later CTR1 (attn@v)
#define WS_U     (WS_X1 + NP*DD)           // NP*192 pre-fusion; later CTR final
#define WS_X2    (WS_U + NP*DD)            // NP*192 post-fusion
#define WS_QKV   (WS_X2 + NP*DD)           // NP*576
#define WS_SC    (WS_QKV + NP*576)         // NP*192  SC[n][i(2)][h(6)][j(16)]
#define WS_ATTN  (WS_SC + NP*DD)           // NP*96   attn[n][h][j]
// total ~25.3M floats ~101 MB

__global__ __launch_bounds__(256) void k_init(float* __restrict__ ws) {
    int t = blockIdx.x * 256 + threadIdx.x;
    if (t < 2354) ws[WS_STATS + t] = 0.f;
}

// ---- K1: geometry glue + stats (M2 second-moment, possum, dist stats) ----
__global__ __launch_bounds__(256) void k1_glue(
    const float* __restrict__ p, const int* __restrict__ knn,
    float* __restrict__ ws)
{
    __shared__ float Xl[48];
    __shared__ float pos[NS][49];
    __shared__ float distl[NS];
    __shared__ int idx[NS];
    __shared__ float pn[3];
    const int t = threadIdx.x;
    float m2acc[9];
    #pragma unroll
    for (int q = 0; q < 9; ++q) m2acc[q] = 0.f;
    float psacc = 0.f, dsum_loc = 0.f, dmax_loc = 0.f;

    for (int it = 0; it < 16; ++it) {
        const int n = blockIdx.x * 16 + it;
        __syncthreads();
        if (t < NS) idx[t] = knn[n*NS + t];
        if (t < 3)  pn[t] = p[n*3 + t];
        __syncthreads();
        if (t < 48) { float v = p[idx[t/3]*3 + (t % 3)]; Xl[t] = v; ws[WS_KNN + n*48 + t] = v; }
        __syncthreads();
        if (t < 48) {
            int j = t/3, c = t % 3;
            ws[WS_PR + (n*NS + j)*3 + c] = Xl[t] - pn[c];
        }
        if (t < NS) {
            float dx = Xl[t*3]-pn[0], dy = Xl[t*3+1]-pn[1], dz = Xl[t*3+2]-pn[2];
            distl[t] = sqrtf(dx*dx + dy*dy + dz*dz + 1e-12f);
        }
        for (int e = t; e < NS*48; e += 256) {
            int r = e/48, k = e - r*48;
            pos[r][k] = Xl[k] - Xl[r*3 + (k % 3)];
        }
        __syncthreads();
        if (t == 0) {
            float dm = 0.f, ds = 0.f;
            for (int j = 0; j < NS; ++j) { dm = fmaxf(dm, distl[j]); ds += distl[j]; }
            ws[WS_GDIS + n] = dm;
            dsum_loc += ds; dmax_loc = fmaxf(dmax_loc, dm);
        }
        if (t < 3) {
            float mx = 0.f;
            for (int j = 0; j < NS; ++j) mx += Xl[j*3 + t];
            mx *= (1.f/16.f);
            ws[WS_GEO9 + n*9 + t]     = mx - pn[t];
            ws[WS_GEO9 + n*9 + 3 + t] = mx;
            ws[WS_GEO9 + n*9 + 6 + t] = pn[t];
        }
        {
            int e = t;
            #pragma unroll
            for (int q = 0; q < 9; ++q) {
                int a = e / 48, b = e - a*48;
                float s = 0.f;
                for (int j = 0; j < NS; ++j) s += pos[j][a] * pos[j][b];
                m2acc[q] += s;
                e += 256;
            }
        }
        if (t < 48) { float s = 0.f; for (int j = 0; j < NS; ++j) s += pos[j][t]; psacc += s; }
    }
    {
        int e = t;
        #pragma unroll
        for (int q = 0; q < 9; ++q) { atomicAdd(&ws[WS_STATS + 50 + e], m2acc[q]); e += 256; }
    }
    if (t < 48) atomicAdd(&ws[WS_STATS + 2 + t], psacc);
    if (t == 0) {
        atomicAdd(&ws[WS_STATS + 0], dsum_loc);
        atomicMax((int*)(ws + WS_STATS + 1), __float_as_int(dmax_loc));  // dist>=0
    }
}

// ---- K2: vol vector + BN fold (var via M2) -> a/bb ----
__global__ __launch_bounds__(256) void k2_fold(
    const float* __restrict__ posW1, const float* __restrict__ posB1,
    const float* __restrict__ gamma, const float* __restrict__ beta,
    const float* __restrict__ gCW, const float* __restrict__ gCb,
    float* __restrict__ ws)
{
    __shared__ float M2n[48][48];
    __shared__ float pmean[48];
    __shared__ float Wc[48][193];
    const int t = threadIdx.x;
    const int i = blockIdx.x;
    for (int e = t; e < 2304; e += 256) ((float*)M2n)[e] = ws[WS_STATS + 50 + e] * (1.f/(float)MTOT);
    if (t < 48) pmean[t] = ws[WS_STATS + 2 + t] * (1.f/(float)MTOT);
    if (t < DD) {
        for (int k = 0; k < 48; ++k) Wc[k][t] = posW1[(size_t)(i*48 + k)*DD + t];
    }
    __syncthreads();
    if (i == 0 && t < DD) {
        float dsum = ws[WS_STATS + 0];
        float dmax = __int_as_float(((const int*)(ws + WS_STATS))[1]);
        float vol = (dsum * (1.f/(float)MTOT)) / (dmax + 1e-8f);
        ws[WS_VOLV + t] = vol * gCW[t] + gCb[t];
    }
    if (t < DD) {
        float mu0 = 0.f;
        #pragma unroll 8
        for (int k = 0; k < 48; ++k) mu0 += pmean[k] * Wc[k][t];
        float e2 = 0.f;
        for (int a2 = 0; a2 < 48; ++a2) {
            float inner = 0.f;
            #pragma unroll 8
            for (int b2 = 0; b2 < 48; ++b2) inner += M2n[a2][b2] * Wc[b2][t];
            e2 += Wc[a2][t] * inner;
        }
        float var = fmaxf(e2 - mu0*mu0, 0.f);
        float as = rsqrtf(var + 1e-5f) * gamma[i*DD + t];
        ws[WS_AB + i*DD + t]       = as;
        ws[WS_AB + 576 + i*DD + t] = beta[i*DD + t] - mu0 * as;   // h'=relu(acc*as+bb)
    }
}

// ---- K_prop: gathered GEMM [262144 x 195] @ propW -> relu -> window mean -> X1 ----
__global__ __launch_bounds__(256) void k_prop(
    const float* __restrict__ x, const int* __restrict__ knn,
    const float* __restrict__ propW, const float* __restrict__ propB,
    float* __restrict__ ws)
{
    __shared__ float At[16][68];
    __shared__ float Bt[16][196];
    __shared__ int idx64[64];
    const int t = threadIdx.x;
    const int ty = t >> 4, tx = t & 15;
    const int mbase = blockIdx.x * 64;
    if (t < 64) idx64[t] = knn[mbase + t];
    float acc[4][12];
    #pragma unroll
    for (int a = 0; a < 4; ++a)
        #pragma unroll
        for (int m = 0; m < 12; ++m) acc[a][m] = 0.f;
    __syncthreads();
    for (int kt = 0; kt < 13; ++kt) {
        {   // stage A (gather via knn), transposed
            const int r = t >> 2, kq = t & 3;
            const int k0 = kt*16 + kq*4;
            float4 v;
            if (k0 + 3 < DD) {
                v = *(const float4*)(x + (size_t)idx64[r]*DD + k0);
            } else {
                float tmp[4];
                #pragma unroll
                for (int e = 0; e < 4; ++e) {
                    int k = k0 + e;
                    tmp[e] = (k < DD) ? x[(size_t)idx64[r]*DD + k]
                           : ((k < 195) ? ws[WS_PR + (size_t)(mbase + r)*3 + (k - DD)] : 0.f);
                }
                v = make_float4(tmp[0], tmp[1], tmp[2], tmp[3]);
            }
            At[kq*4+0][r] = v.x; At[kq*4+1][r] = v.y; At[kq*4+2][r] = v.z; At[kq*4+3][r] = v.w;
        }
        for (int e = t; e < 16*48; e += 256) {   // stage B
            int kr = e / 48, cq = e - kr*48;
            int kg = kt*16 + kr;
            float4 v = (kg < 195) ? *(const float4*)(propW + (size_t)kg*DD + cq*4)
                                  : make_float4(0.f, 0.f, 0.f, 0.f);
            *(float4*)&Bt[kr][cq*4] = v;
        }
        __syncthreads();
        #pragma unroll
        for (int k = 0; k < 16; ++k) {
            float4 a4 = *(const float4*)&At[k][ty*4];
            const float* br = &Bt[k][tx*12];
            float b[12];
            #pragma unroll
            for (int m = 0; m < 12; ++m) b[m] = br[m];
            #pragma unroll
            for (int a = 0; a < 4; ++a) {
                float av = (&a4.x)[a];
                #pragma unroll
                for (int m = 0; m < 12; ++m) acc[a][m] += av * b[m];
            }
        }
        __syncthreads();
    }
    {   // relu(acc+bias), sum thread's 4 rows
        #pragma unroll
        for (int m = 0; m < 12; ++m) {
            float bias = propB[tx*12 + m];
            float s = 0.f;
            #pragma unroll
            for (int a = 0; a < 4; ++a) s += fmaxf(acc[a][m] + bias, 0.f);
            Bt[ty][tx*12 + m] = s;
        }
    }
    __syncthreads();
    for (int e = t; e < 4*DD; e += 256) {
        int w = e / DD, c = e - w*DD;
        int n = blockIdx.x*4 + w;
        float s = Bt[w*4+0][c] + Bt[w*4+1][c] + Bt[w*4+2][c] + Bt[w*4+3][c];
        ws[WS_X1 + (size_t)n*DD + c] = x[(size_t)n*DD + c] + s * (1.f/16.f);
    }
}

// ---- Generic tiled GEMM: C[M x N] = A[M x 192] @ B[192 x N] (+bias). BM=64,BN=64 ----
__global__ __launch_bounds__(256) void gemm_bias(
    const float* __restrict__ A, const float* __restrict__ B,
    const float* __restrict__ bias, float* __restrict__ C, int N)
{
    __shared__ float At[16][68];
    __shared__ float Bt[16][68];
    const int t = threadIdx.x;
    const int ty = t >> 4, tx = t & 15;
    const int rowBase = blockIdx.x * 64, colBase = blockIdx.y * 64;
    float acc[4][4];
    #pragma unroll
    for (int a = 0; a < 4; ++a)
        #pragma unroll
        for (int b = 0; b < 4; ++b) acc[a][b] = 0.f;
    for (int kt = 0; kt < 12; ++kt) {
        {
            const int r = t >> 2, kq = t & 3;
            float4 v = *(const float4*)(A + (size_t)(rowBase + r)*192 + kt*16 + kq*4);
            At[kq*4+0][r] = v.x; At[kq*4+1][r] = v.y; At[kq*4+2][r] = v.z; At[kq*4+3][r] = v.w;
        }
        {
            const int kr = t >> 4, cg = t & 15;
            float4 v = *(const float4*)(B + (size_t)(kt*16 + kr)*N + colBase + cg*4);
            *(float4*)&Bt[kr][cg*4] = v;
        }
        __syncthreads();
        #pragma unroll
        for (int k = 0; k < 16; ++k) {
            float4 a4 = *(const float4*)&At[k][ty*4];
            float4 b4 = *(const float4*)&Bt[k][tx*4];
            #pragma unroll
            for (int a = 0; a < 4; ++a) {
                float av = (&a4.x)[a];
                acc[a][0] += av * b4.x; acc[a][1] += av * b4.y;
                acc[a][2] += av * b4.z; acc[a][3] += av * b4.w;
            }
        }
        __syncthreads();
    }
    float bv[4];
    #pragma unroll
    for (int b = 0; b < 4; ++b) bv[b] = bias ? bias[colBase + tx*4 + b] : 0.f;
    #pragma unroll
    for (int a = 0; a < 4; ++a) {
        float4 o = make_float4(acc[a][0]+bv[0], acc[a][1]+bv[1], acc[a][2]+bv[2], acc[a][3]+bv[3]);
        *(float4*)(C + (size_t)(rowBase + ty*4 + a)*N + colBase + tx*4) = o;
    }
}

// ---- K3a: keypoint attention + U assembly (deW2 staged in LDS) ----
__global__ __launch_bounds__(256) void k3a(
    const float* __restrict__ p, const float* __restrict__ kn,
    const float* __restrict__ deW1, const float* __restrict__ deB1,
    const float* __restrict__ deW2, const float* __restrict__ deB2,
    const float* __restrict__ kpW, const float* __restrict__ kpB,
    const float* __restrict__ gAW, const float* __restrict__ gAb,
    const float* __restrict__ gBW, const float* __restrict__ gBb,
    float* __restrict__ ws)
{
    __shared__ float Wd[48][196];
    __shared__ float innr[KSPN][49];
    __shared__ float df[KSPN][193];
    __shared__ float kd[KSPN];
    __shared__ float scl[KSPN];
    const int t = threadIdx.x;
    for (int e = t; e < 48*48; e += 256) {
        int w = e / 48, cq = e - w*48;
        *(float4*)&Wd[w][cq*4] = *(const float4*)(deW2 + (size_t)w*DD + cq*4);
    }
    const int kap = t >> 4, u = t & 15, c0 = u*12;
    for (int it = 0; it < 16; ++it) {
        const int n = blockIdx.x*16 + it;
        __syncthreads();
        if (t < KSPN) {
            float dx = p[n*3]-kn[t*3], dy = p[n*3+1]-kn[t*3+1], dz = p[n*3+2]-kn[t*3+2];
            kd[t] = sqrtf(dx*dx + dy*dy + dz*dz + 1e-12f);
        }
        __syncthreads();
        for (int e = t; e < KSPN*48; e += 256) {
            int r = e / 48, j = e - r*48;
            innr[r][j] = fmaxf(kd[r]*deW1[j] + deB1[j], 0.f);
        }
        __syncthreads();
        float a12[12];
        #pragma unroll
        for (int m = 0; m < 12; ++m) a12[m] = deB2[c0 + m];
        for (int w = 0; w < 48; ++w) {
            float av = innr[kap][w];
            #pragma unroll
            for (int m = 0; m < 12; ++m) a12[m] += av * Wd[w][c0 + m];
        }
        float ksc = 0.f;
        #pragma unroll
        for (int m = 0; m < 12; ++m) { df[kap][c0 + m] = a12[m]; ksc += a12[m]*kpW[c0 + m]; }
        #pragma unroll
        for (int off = 1; off < 16; off <<= 1) ksc += __shfl_xor(ksc, off, 16);
        if (u == 0) scl[kap] = ksc + kpB[0];
        __syncthreads();
        if (t < KSPN) {
            float v = scl[t], mx = v;
            #pragma unroll
            for (int off = 1; off < 16; off <<= 1) mx = fmaxf(mx, __shfl_xor(mx, off, 16));
            float e = expf(v - mx);
            float sm = e;
            #pragma unroll
            for (int off = 1; off < 16; off <<= 1) sm += __shfl_xor(sm, off, 16);
            scl[t] = e / sm;
        }
        __syncthreads();
        if (t < DD) {
            float dfeat = 0.f;
            #pragma unroll
            for (int k2 = 0; k2 < KSPN; ++k2) dfeat += scl[k2]*df[k2][t];
            float uval = ws[WS_X1 + (size_t)n*DD + t] + gAb[t] + gBb[t] + ws[WS_VOLV + t] + dfeat;
            uval += ws[WS_GDIS + n] * gBW[t];
            #pragma unroll
            for (int kk = 0; kk < 9; ++kk) uval += ws[WS_GEO9 + n*9 + kk] * gAW[kk*DD + t];
            ws[WS_U + (size_t)n*DD + t] = uval;
        }
    }
}

// ---- K_dqdk v3: 8 windows/block, i = blockIdx&1 (0: q0.pq, 1: k0.pk).
//      rq: W2 rows direct from global (regs) x q0 LDS-broadcast.
//      H: W1 staged, 4-row x 24-col register tiles, contraction vs rqs. ----
__global__ __launch_bounds__(256) void k_dqdk(
    const int* __restrict__ knn,
    const float* __restrict__ posW1, const float* __restrict__ posW2,
    float* __restrict__ ws)
{
    __shared__ float Wbuf[48*196];     // phase1: qk[8][192] (first 1536); phase2: W1[48][196]
    __shared__ float rqs[48*196];      // rqs[(w*6+h)*196 + kk]
    __shared__ float Xl[8][48];
    __shared__ int idx0[8];
    const int t = threadIdx.x;
    const int i = blockIdx.x & 1;
    const int nb = (blockIdx.x >> 1) * 8;
    if (t < 8) idx0[t] = knn[(nb + t)*NS];
    for (int e = t; e < 384; e += 256) {
        int w = e / 48, k = e % 48;
        Xl[w][k] = ws[WS_KNN + (size_t)(nb + w)*48 + k];
    }
    __syncthreads();
    // stage q0 (i=0) or k0 (i=1) for 8 windows into Wbuf[0..1536)
    for (int e = t; e < 384; e += 256) {
        int w = e / 48, cq = e % 48;
        *(float4*)&Wbuf[w*192 + cq*4] =
            *(const float4*)(ws + WS_QKV + (size_t)idx0[w]*576 + i*192 + cq*4);
    }
    __syncthreads();
    // rq[w][h][kk] = sum_c W2_i[kk][h*32+c] * qk[w][h*32+c]
    if (t < 192) {
        const float* Wrow = posW2 + (size_t)i*DD*DD + (size_t)t*DD;
        for (int h = 0; h < 6; ++h) {
            float4 wr[8];
            #pragma unroll
            for (int q = 0; q < 8; ++q) wr[q] = *(const float4*)(Wrow + h*32 + q*4);
            float a[8];
            #pragma unroll
            for (int w = 0; w < 8; ++w) a[w] = 0.f;
            #pragma unroll
            for (int q = 0; q < 8; ++q) {
                #pragma unroll
                for (int d = 0; d < 4; ++d) {
                    float wv = (&wr[q].x)[d];
                    int c = h*32 + q*4 + d;
                    #pragma unroll
                    for (int w = 0; w < 8; ++w) a[w] += wv * Wbuf[w*192 + c];  // broadcast read
                }
            }
            #pragma unroll
            for (int w = 0; w < 8; ++w) rqs[(w*6 + h)*196 + t] = a[w];
        }
    }
    __syncthreads();
    // stage W1_i [48][196]
    for (int e = t; e < 2304; e += 256) {
        int kk = e / 48, cq = e % 48;
        *(float4*)&Wbuf[kk*196 + cq*4] = *(const float4*)(posW1 + (size_t)(i*48 + kk)*DD + cq*4);
    }
    __syncthreads();
    // H rows (4 per thread) x 24 cols; then contraction vs rqs
    {
        const int cg = t & 7, rg = t >> 3;
        const int w = rg >> 2, j0 = (rg & 3)*4, c0 = cg*24;
        float cx0[3], cx1[3], cx2[3], cx3[3];
        #pragma unroll
        for (int d = 0; d < 3; ++d) {
            cx0[d] = Xl[w][(j0+0)*3 + d];
            cx1[d] = Xl[w][(j0+1)*3 + d];
            cx2[d] = Xl[w][(j0+2)*3 + d];
            cx3[d] = Xl[w][(j0+3)*3 + d];
        }
        float acc0[24], acc1[24], acc2[24], acc3[24];
        #pragma unroll
        for (int m = 0; m < 24; ++m) { acc0[m]=0.f; acc1[m]=0.f; acc2[m]=0.f; acc3[m]=0.f; }
        for (int k3 = 0; k3 < 16; ++k3) {
            #pragma unroll
            for (int d = 0; d < 3; ++d) {
                int k = k3*3 + d;
                float xk = Xl[w][k];
                float av0 = xk - cx0[d], av1 = xk - cx1[d];
                float av2 = xk - cx2[d], av3 = xk - cx3[d];
                #pragma unroll
                for (int m = 0; m < 24; ++m) {
                    float wv = Wbuf[k*196 + c0 + m];
                    acc0[m] += av0*wv; acc1[m] += av1*wv;
                    acc2[m] += av2*wv; acc3[m] += av3*wv;
                }
            }
        }
        #pragma unroll
        for (int m = 0; m < 24; ++m) {
            int c = c0 + m;
            float as = ws[WS_AB + i*DD + c];
            float bb = ws[WS_AB + 576 + i*DD + c];
            acc0[m] = fmaxf(acc0[m]*as + bb, 0.f);
            acc1[m] = fmaxf(acc1[m]*as + bb, 0.f);
            acc2[m] = fmaxf(acc2[m]*as + bb, 0.f);
            acc3[m] = fmaxf(acc3[m]*as + bb, 0.f);
        }
        #pragma unroll
        for (int h = 0; h < 6; ++h) {
            float s0 = 0.f, s1 = 0.f, s2 = 0.f, s3 = 0.f;
            #pragma unroll
            for (int m = 0; m < 24; ++m) {
                float rv = rqs[(w*6 + h)*196 + c0 + m];
                s0 += acc0[m]*rv; s1 += acc1[m]*rv; s2 += acc2[m]*rv; s3 += acc3[m]*rv;
            }
            #pragma unroll
            for (int off = 1; off < 8; off <<= 1) {
                s0 += __shfl_xor(s0, off, 8); s1 += __shfl_xor(s1, off, 8);
                s2 += __shfl_xor(s2, off, 8); s3 += __shfl_xor(s3, off, 8);
            }
            if (cg == 0) {
                float* dst = ws + WS_SC + (size_t)(nb + w)*192 + i*96 + h*16 + j0;
                dst[0] = s0; dst[1] = s1; dst[2] = s2; dst[3] = s3;
            }
        }
    }
}

// ---- K_score: q0.k_j dots + softmax + CTR1 = attn@v; stores attn ----
__global__ __launch_bounds__(256) void k_score(
    const int* __restrict__ knn, float* __restrict__ ws)
{
    __shared__ float Kw[NS][196];
    __shared__ float Vw[NS][196];
    __shared__ float q0s[192];
    __shared__ float dqks[6][16];
    __shared__ float attns[6][16];
    __shared__ int idx[NS];
    const int n = blockIdx.x;
    const int t = threadIdx.x;
    if (t < NS) idx[t] = knn[n*NS + t];
    __syncthreads();
    for (int e = t; e < NS*48; e += 256) {
        int r = e/48, cq = e%48;
        *(float4*)&Kw[r][cq*4] = *(const float4*)(ws + WS_QKV + (size_t)idx[r]*576 + 192 + cq*4);
        *(float4*)&Vw[r][cq*4] = *(const float4*)(ws + WS_QKV + (size_t)idx[r]*576 + 384 + cq*4);
    }
    if (t < DD) q0s[t] = ws[WS_QKV + (size_t)idx[0]*576 + t];
    __syncthreads();
    {   // dqk[h][j] = q0 . k_j per head
        const int j = t >> 4, u = t & 15;
        #pragma unroll
        for (int h = 0; h < 6; ++h) {
            int c = h*32 + u*2;
            float v = q0s[c]*Kw[j][c] + q0s[c+1]*Kw[j][c+1];
            #pragma unroll
            for (int off = 1; off < 16; off <<= 1) v += __shfl_xor(v, off, 16);
            if (u == 0) dqks[h][j] = v;
        }
    }
    __syncthreads();
    if (t < 96) {   // softmax rows: h = t>>4, jj = t&15
        const float scale = 0.17677669529663687f;  // 32^-0.5
        const int h = t >> 4, jj = t & 15;
        float z = (dqks[h][jj]
                 + ws[WS_SC + (size_t)n*192 + h*16 + jj]
                 + ws[WS_SC + (size_t)n*192 + 96 + h*16 + jj]) * scale;
        float mx = z;
        #pragma unroll
        for (int off = 1; off < 16; off <<= 1) mx = fmaxf(mx, __shfl_xor(mx, off, 16));
        float e = expf(z - mx);
        float sm = e;
        #pragma unroll
        for (int off = 1; off < 16; off <<= 1) sm += __shfl_xor(sm, off, 16);
        float a = e / sm;
        attns[h][jj] = a;
        ws[WS_ATTN + (size_t)n*96 + h*16 + jj] = a;
    }
    __syncthreads();
    if (t < DD) {   // CTR1 = attn@v
        const int h = t >> 5;
        float s = 0.f;
        #pragma unroll
        for (int jj = 0; jj < NS; ++jj) s += attns[h][jj] * Vw[jj][t];
        ws[WS_X1 + (size_t)n*DD + t] = s;
    }
}

// ---- K_pv: 2 windows/block. H2 rows -> wsum = attn@H2 -> pv = wsum@W2_2
//      CTR = CTR1 + pv + b2_2 ----
__global__ __launch_bounds__(256) void k_pv(
    const float* __restrict__ posW1, const float* __restrict__ posW2,
    const float* __restrict__ posB2, float* __restrict__ ws)
{
    __shared__ float Wbuf[48][196];     // W1_2, then W2_2 chunks [32][196]
    __shared__ float H2[32][196];
    __shared__ float wsum[2][6][196];
    __shared__ float attns[2][96];
    __shared__ float Xl[2][48];
    const int t = threadIdx.x;
    const int nb = blockIdx.x*2;
    if (t < 96) { int w = t/48, k = t%48; Xl[w][k] = ws[WS_KNN + (size_t)(nb+w)*48 + k]; }
    if (t < 192) { int w = t/96, r = t%96; attns[w][r] = ws[WS_ATTN + (size_t)(nb+w)*96 + r]; }
    for (int e = t; e < 48*48; e += 256) {     // stage W1_2
        int kk = e/48, cq = e%48;
        *(float4*)&Wbuf[kk][cq*4] = *(const float4*)(posW1 + (size_t)(2*48+kk)*DD + cq*4);
    }
    __syncthreads();
    {   // H2 row j
        const int j = t >> 3, cg = t & 7, c0 = cg*24;
        const int w = j >> 4, jl = j & 15;
        const float px = Xl[w][jl*3], py = Xl[w][jl*3+1], pz = Xl[w][jl*3+2];
        float acc[24];
        #pragma unroll
        for (int m = 0; m < 24; ++m) acc[m] = 0.f;
        #pragma unroll
        for (int k = 0; k < 48; ++k) {
            float ctr = (k % 3 == 0) ? px : ((k % 3 == 1) ? py : pz);
            float av = Xl[w][k] - ctr;
            #pragma unroll
            for (int m = 0; m < 24; ++m) acc[m] += av * Wbuf[k][c0+m];
        }
        #pragma unroll
        for (int m = 0; m < 24; ++m) {
            int c = c0 + m;
            float as = ws[WS_AB + 2*DD + c], bb = ws[WS_AB + 576 + 2*DD + c];
            H2[j][c] = fmaxf(acc[m]*as + bb, 0.f);
        }
    }
    __syncthreads();
    for (int e = t; e < 2304; e += 256) {   // wsum[w][h][kk] = sum_j attn * H2
        int w = e/1152, r = e%1152, h = r/192, kk = r%192;
        float s = 0.f;
        #pragma unroll
        for (int jj = 0; jj < NS; ++jj) s += attns[w][h*16+jj] * H2[w*16+jj][kk];
        wsum[w][h][kk] = s;
    }
    float pvacc[2] = {0.f, 0.f};
    for (int ch = 0; ch < 6; ++ch) {        // pv += wsum_chunk @ W2_2_chunk
        __syncthreads();
        for (int e = t; e < 32*48; e += 256) {
            int kkl = e/48, cq = e%48;
            *(float4*)&Wbuf[kkl][cq*4] =
                *(const float4*)(posW2 + (size_t)(2*DD + ch*32 + kkl)*DD + cq*4);
        }
        __syncthreads();
        for (int e = t, q = 0; e < 384; e += 256, ++q) {
            int w = e/192, c = e%192, h = c>>5;
            float s = 0.f;
            #pragma unroll
            for (int kkl = 0; kkl < 32; ++kkl) s += wsum[w][h][ch*32+kkl] * Wbuf[kkl][c];
            pvacc[q] += s;
        }
    }
    __syncthreads();
    for (int e = t, q = 0; e < 384; e += 256, ++q) {
        int w = e/192, c = e%192;
        ws[WS_U + (size_t)(nb+w)*DD + c] =
            ws[WS_X1 + (size_t)(nb+w)*DD + c] + pvacc[q] + posB2[2*DD + c];
    }
}

extern "C" void kernel_launch(void* const* d_in, const int* in_sizes, int n_in,
                              void* d_out, int out_size, void* d_ws, size_t ws_size,
                              hipStream_t stream)
{
    const float* p     = (const float*)d_in[0];
    const float* x     = (const float*)d_in[1];
    const int*   knn   = (const int*)  d_in[2];
    const float* Wqkv  = (const float*)d_in[3];
    const float* Wproj = (const float*)d_in[4];
    const float* bproj = (const float*)d_in[5];
    const float* propW = (const float*)d_in[6];
    const float* propB = (const float*)d_in[7];
    const float* gAW   = (const float*)d_in[8];
    const float* gAb   = (const float*)d_in[9];
    const float* gBW   = (const float*)d_in[10];
    const float* gBb   = (const float*)d_in[11];
    const float* gCW   = (const float*)d_in[12];
    const float* gCb   = (const float*)d_in[13];
    const float* posW1 = (const float*)d_in[14];
    const float* posB1 = (const float*)d_in[15];
    const float* gamma = (const float*)d_in[16];
    const float* beta  = (const float*)d_in[17];
    const float* posW2 = (const float*)d_in[18];
    const float* posB2 = (const float*)d_in[19];
    const float* kn    = (const float*)d_in[20];
    const float* deW1  = (const float*)d_in[21];
    const float* deB1  = (const float*)d_in[22];
    const float* deW2  = (const float*)d_in[23];
    const float* deB2  = (const float*)d_in[24];
    const float* kpW   = (const float*)d_in[25];
    const float* kpB   = (const float*)d_in[26];
    const float* fusW  = (const float*)d_in[27];
    const float* fusB  = (const float*)d_in[28];
    float* ws   = (float*)d_ws;
    float* outp = (float*)d_out;

    hipLaunchKernelGGL(k_init, dim3(10), dim3(256), 0, stream, ws);
    hipLaunchKernelGGL(k1_glue, dim3(NP/16), dim3(256), 0, stream, p, knn, ws);
    hipLaunchKernelGGL(k2_fold, dim3(3), dim3(256), 0, stream,
                       posW1, posB1, gamma, beta, gCW, gCb, ws);
    hipLaunchKernelGGL(k_prop, dim3(MTOT/64), dim3(256), 0, stream, x, knn, propW, propB, ws);
    hipLaunchKernelGGL(k3a, dim3(NP/16), dim3(256), 0, stream,
                       p, kn, deW1, deB1, deW2, deB2, kpW, kpB, gAW, gAb, gBW, gBb, ws);
    hipLaunchKernelGGL(gemm_bias, dim3(NP/64, 3), dim3(256), 0, stream,
                       ws + WS_U, fusW, fusB, ws + WS_X2, DD);        // X2 = U@fusW+fusB
    hipLaunchKernelGGL(gemm_bias, dim3(NP/64, 9), dim3(256), 0, stream,
                       ws + WS_X2, Wqkv, (const float*)nullptr, ws + WS_QKV, 576);  // QKV
    hipLaunchKernelGGL(k_dqdk, dim3(NP/4), dim3(256), 0, stream, knn, posW1, posW2, ws);
    hipLaunchKernelGGL(k_score, dim3(NP), dim3(256), 0, stream, knn, ws);
    hipLaunchKernelGGL(k_pv, dim3(NP/2), dim3(256), 0, stream, posW1, posW2, posB2, ws);
    hipLaunchKernelGGL(gemm_bias, dim3(NP/64, 3), dim3(256), 0, stream,
                       ws + WS_U, Wproj, bproj, outp, DD);            // OUT = CTR@Wproj+bproj
}

// Round 5
// 1353.055 us; speedup vs baseline: 6.2088x; 1.1569x over previous
//
#include <hip/hip_runtime.h>
#include <math.h>

#define NP 16384
#define DD 192
#define NS 16
#define KSPN 16
#define MTOT (NP*NS)

// ws float offsets
#define WS_KNN   0                         // NP*48   knn_xyz
#define WS_PR    (WS_KNN + NP*48)          // MTOT*3  p_r per window row
#define WS_GEO9  (WS_PR + MTOT*3)          // NP*9
#define WS_GDIS  (WS_GEO9 + NP*9)          // NP
#define WS_STATS (WS_GDIS + NP)            // [0]=dsum [1]=dmax(bits) [2..50)=possum [50..2354)=M2
#define WS_VOLV  (WS_STATS + 2354)         // 192
#define WS_AB    (WS_VOLV + DD)            // a[3][192] | bb[3][192] = 1152
#define WS_X1    (WS_AB + 1152)            // NP*192 post-propagate; later CTR1 (attn@v)
#define WS_U     (WS_X1 + NP*DD)           // NP*192 pre-fusion; later CTR final
#define WS_X2    (WS_U + NP*DD)            // NP*192 post-fusion
#define WS_QKV   (WS_X2 + NP*DD)           // NP*576
#define WS_SC    (WS_QKV + NP*576)         // NP*192  SC[n][i(2)][h(6)][j(16)]
#define WS_ATTN  (WS_SC + NP*DD)           // NP*96   attn[n][h][j]
#define WS_W2T   (WS_ATTN + NP*96)         // 192*192 transposed posW2[2]
// total ~25.4M floats ~102 MB

__global__ __launch_bounds__(256) void k_init(float* __restrict__ ws) {
    int t = blockIdx.x * 256 + threadIdx.x;
    if (t < 2354) ws[WS_STATS + t] = 0.f;
}

// ---- tiny: W2T[c][kk] = posW2[2][kk][c] ----
__global__ __launch_bounds__(256) void k_w2t(const float* __restrict__ posW2,
                                             float* __restrict__ ws) {
    int e = blockIdx.x*256 + threadIdx.x;      // e = c*192 + kk
    int c = e / DD, kk = e - c*DD;
    ws[WS_W2T + e] = posW2[(size_t)(2*DD + kk)*DD + c];
}

// ---- K1: geometry glue + stats (M2 second-moment, possum, dist stats) ----
__global__ __launch_bounds__(256) void k1_glue(
    const float* __restrict__ p, const int* __restrict__ knn,
    float* __restrict__ ws)
{
    __shared__ float Xl[48];
    __shared__ float pos[NS][49];
    __shared__ float distl[NS];
    __shared__ int idx[NS];
    __shared__ float pn[3];
    const int t = threadIdx.x;
    float m2acc[9];
    #pragma unroll
    for (int q = 0; q < 9; ++q) m2acc[q] = 0.f;
    float psacc = 0.f, dsum_loc = 0.f, dmax_loc = 0.f;

    for (int it = 0; it < 16; ++it) {
        const int n = blockIdx.x * 16 + it;
        __syncthreads();
        if (t < NS) idx[t] = knn[n*NS + t];
        if (t < 3)  pn[t] = p[n*3 + t];
        __syncthreads();
        if (t < 48) { float v = p[idx[t/3]*3 + (t % 3)]; Xl[t] = v; ws[WS_KNN + n*48 + t] = v; }
        __syncthreads();
        if (t < 48) {
            int j = t/3, c = t % 3;
            ws[WS_PR + (n*NS + j)*3 + c] = Xl[t] - pn[c];
        }
        if (t < NS) {
            float dx = Xl[t*3]-pn[0], dy = Xl[t*3+1]-pn[1], dz = Xl[t*3+2]-pn[2];
            distl[t] = sqrtf(dx*dx + dy*dy + dz*dz + 1e-12f);
        }
        for (int e = t; e < NS*48; e += 256) {
            int r = e/48, k = e - r*48;
            pos[r][k] = Xl[k] - Xl[r*3 + (k % 3)];
        }
        __syncthreads();
        if (t == 0) {
            float dm = 0.f, ds = 0.f;
            for (int j = 0; j < NS; ++j) { dm = fmaxf(dm, distl[j]); ds += distl[j]; }
            ws[WS_GDIS + n] = dm;
            dsum_loc += ds; dmax_loc = fmaxf(dmax_loc, dm);
        }
        if (t < 3) {
            float mx = 0.f;
            for (int j = 0; j < NS; ++j) mx += Xl[j*3 + t];
            mx *= (1.f/16.f);
            ws[WS_GEO9 + n*9 + t]     = mx - pn[t];
            ws[WS_GEO9 + n*9 + 3 + t] = mx;
            ws[WS_GEO9 + n*9 + 6 + t] = pn[t];
        }
        {
            int e = t;
            #pragma unroll
            for (int q = 0; q < 9; ++q) {
                int a = e / 48, b = e - a*48;
                float s = 0.f;
                for (int j = 0; j < NS; ++j) s += pos[j][a] * pos[j][b];
                m2acc[q] += s;
                e += 256;
            }
        }
        if (t < 48) { float s = 0.f; for (int j = 0; j < NS; ++j) s += pos[j][t]; psacc += s; }
    }
    {
        int e = t;
        #pragma unroll
        for (int q = 0; q < 9; ++q) { atomicAdd(&ws[WS_STATS + 50 + e], m2acc[q]); e += 256; }
    }
    if (t < 48) atomicAdd(&ws[WS_STATS + 2 + t], psacc);
    if (t == 0) {
        atomicAdd(&ws[WS_STATS + 0], dsum_loc);
        atomicMax((int*)(ws + WS_STATS + 1), __float_as_int(dmax_loc));  // dist>=0
    }
}

// ---- K2: vol vector + BN fold (var via M2) -> a/bb ----
__global__ __launch_bounds__(256) void k2_fold(
    const float* __restrict__ posW1, const float* __restrict__ posB1,
    const float* __restrict__ gamma, const float* __restrict__ beta,
    const float* __restrict__ gCW, const float* __restrict__ gCb,
    float* __restrict__ ws)
{
    __shared__ float M2n[48][48];
    __shared__ float pmean[48];
    __shared__ float Wc[48][193];
    const int t = threadIdx.x;
    const int i = blockIdx.x;
    for (int e = t; e < 2304; e += 256) ((float*)M2n)[e] = ws[WS_STATS + 50 + e] * (1.f/(float)MTOT);
    if (t < 48) pmean[t] = ws[WS_STATS + 2 + t] * (1.f/(float)MTOT);
    if (t < DD) {
        for (int k = 0; k < 48; ++k) Wc[k][t] = posW1[(size_t)(i*48 + k)*DD + t];
    }
    __syncthreads();
    if (i == 0 && t < DD) {
        float dsum = ws[WS_STATS + 0];
        float dmax = __int_as_float(((const int*)(ws + WS_STATS))[1]);
        float vol = (dsum * (1.f/(float)MTOT)) / (dmax + 1e-8f);
        ws[WS_VOLV + t] = vol * gCW[t] + gCb[t];
    }
    if (t < DD) {
        float mu0 = 0.f;
        #pragma unroll 8
        for (int k = 0; k < 48; ++k) mu0 += pmean[k] * Wc[k][t];
        float e2 = 0.f;
        for (int a2 = 0; a2 < 48; ++a2) {
            float inner = 0.f;
            #pragma unroll 8
            for (int b2 = 0; b2 < 48; ++b2) inner += M2n[a2][b2] * Wc[b2][t];
            e2 += Wc[a2][t] * inner;
        }
        float var = fmaxf(e2 - mu0*mu0, 0.f);
        float as = rsqrtf(var + 1e-5f) * gamma[i*DD + t];
        ws[WS_AB + i*DD + t]       = as;
        ws[WS_AB + 576 + i*DD + t] = beta[i*DD + t] - mu0 * as;   // h'=relu(acc*as+bb)
    }
}

// ---- K_prop: gathered GEMM [262144 x 195] @ propW -> relu -> window mean -> X1 ----
__global__ __launch_bounds__(256) void k_prop(
    const float* __restrict__ x, const int* __restrict__ knn,
    const float* __restrict__ propW, const float* __restrict__ propB,
    float* __restrict__ ws)
{
    __shared__ float At[16][68];
    __shared__ float Bt[16][196];
    __shared__ int idx64[64];
    const int t = threadIdx.x;
    const int ty = t >> 4, tx = t & 15;
    const int mbase = blockIdx.x * 64;
    if (t < 64) idx64[t] = knn[mbase + t];
    float acc[4][12];
    #pragma unroll
    for (int a = 0; a < 4; ++a)
        #pragma unroll
        for (int m = 0; m < 12; ++m) acc[a][m] = 0.f;
    __syncthreads();
    for (int kt = 0; kt < 13; ++kt) {
        {   // stage A (gather via knn), transposed
            const int r = t >> 2, kq = t & 3;
            const int k0 = kt*16 + kq*4;
            float4 v;
            if (k0 + 3 < DD) {
                v = *(const float4*)(x + (size_t)idx64[r]*DD + k0);
            } else {
                float tmp[4];
                #pragma unroll
                for (int e = 0; e < 4; ++e) {
                    int k = k0 + e;
                    tmp[e] = (k < DD) ? x[(size_t)idx64[r]*DD + k]
                           : ((k < 195) ? ws[WS_PR + (size_t)(mbase + r)*3 + (k - DD)] : 0.f);
                }
                v = make_float4(tmp[0], tmp[1], tmp[2], tmp[3]);
            }
            At[kq*4+0][r] = v.x; At[kq*4+1][r] = v.y; At[kq*4+2][r] = v.z; At[kq*4+3][r] = v.w;
        }
        for (int e = t; e < 16*48; e += 256) {   // stage B
            int kr = e / 48, cq = e - kr*48;
            int kg = kt*16 + kr;
            float4 v = (kg < 195) ? *(const float4*)(propW + (size_t)kg*DD + cq*4)
                                  : make_float4(0.f, 0.f, 0.f, 0.f);
            *(float4*)&Bt[kr][cq*4] = v;
        }
        __syncthreads();
        #pragma unroll
        for (int k = 0; k < 16; ++k) {
            float4 a4 = *(const float4*)&At[k][ty*4];
            const float* br = &Bt[k][tx*12];
            float b[12];
            #pragma unroll
            for (int m = 0; m < 12; ++m) b[m] = br[m];
            #pragma unroll
            for (int a = 0; a < 4; ++a) {
                float av = (&a4.x)[a];
                #pragma unroll
                for (int m = 0; m < 12; ++m) acc[a][m] += av * b[m];
            }
        }
        __syncthreads();
    }
    {   // relu(acc+bias), sum thread's 4 rows
        #pragma unroll
        for (int m = 0; m < 12; ++m) {
            float bias = propB[tx*12 + m];
            float s = 0.f;
            #pragma unroll
            for (int a = 0; a < 4; ++a) s += fmaxf(acc[a][m] + bias, 0.f);
            Bt[ty][tx*12 + m] = s;
        }
    }
    __syncthreads();
    for (int e = t; e < 4*DD; e += 256) {
        int w = e / DD, c = e - w*DD;
        int n = blockIdx.x*4 + w;
        float s = Bt[w*4+0][c] + Bt[w*4+1][c] + Bt[w*4+2][c] + Bt[w*4+3][c];
        ws[WS_X1 + (size_t)n*DD + c] = x[(size_t)n*DD + c] + s * (1.f/16.f);
    }
}

// ---- Generic tiled GEMM: C[M x N] = A[M x 192] @ B[192 x N] (+bias). BM=64,BN=64 ----
__global__ __launch_bounds__(256) void gemm_bias(
    const float* __restrict__ A, const float* __restrict__ B,
    const float* __restrict__ bias, float* __restrict__ C, int N)
{
    __shared__ float At[16][68];
    __shared__ float Bt[16][68];
    const int t = threadIdx.x;
    const int ty = t >> 4, tx = t & 15;
    const int rowBase = blockIdx.x * 64, colBase = blockIdx.y * 64;
    float acc[4][4];
    #pragma unroll
    for (int a = 0; a < 4; ++a)
        #pragma unroll
        for (int b = 0; b < 4; ++b) acc[a][b] = 0.f;
    for (int kt = 0; kt < 12; ++kt) {
        {
            const int r = t >> 2, kq = t & 3;
            float4 v = *(const float4*)(A + (size_t)(rowBase + r)*192 + kt*16 + kq*4);
            At[kq*4+0][r] = v.x; At[kq*4+1][r] = v.y; At[kq*4+2][r] = v.z; At[kq*4+3][r] = v.w;
        }
        {
            const int kr = t >> 4, cg = t & 15;
            float4 v = *(const float4*)(B + (size_t)(kt*16 + kr)*N + colBase + cg*4);
            *(float4*)&Bt[kr][cg*4] = v;
        }
        __syncthreads();
        #pragma unroll
        for (int k = 0; k < 16; ++k) {
            float4 a4 = *(const float4*)&At[k][ty*4];
            float4 b4 = *(const float4*)&Bt[k][tx*4];
            #pragma unroll
            for (int a = 0; a < 4; ++a) {
                float av = (&a4.x)[a];
                acc[a][0] += av * b4.x; acc[a][1] += av * b4.y;
                acc[a][2] += av * b4.z; acc[a][3] += av * b4.w;
            }
        }
        __syncthreads();
    }
    float bv[4];
    #pragma unroll
    for (int b = 0; b < 4; ++b) bv[b] = bias ? bias[colBase + tx*4 + b] : 0.f;
    #pragma unroll
    for (int a = 0; a < 4; ++a) {
        float4 o = make_float4(acc[a][0]+bv[0], acc[a][1]+bv[1], acc[a][2]+bv[2], acc[a][3]+bv[3]);
        *(float4*)(C + (size_t)(rowBase + ty*4 + a)*N + colBase + tx*4) = o;
    }
}

// ---- K3a: keypoint attention + U assembly (deW2 staged in LDS) ----
__global__ __launch_bounds__(256) void k3a(
    const float* __restrict__ p, const float* __restrict__ kn,
    const float* __restrict__ deW1, const float* __restrict__ deB1,
    const float* __restrict__ deW2, const float* __restrict__ deB2,
    const float* __restrict__ kpW, const float* __restrict__ kpB,
    const float* __restrict__ gAW, const float* __restrict__ gAb,
    const float* __restrict__ gBW, const float* __restrict__ gBb,
    float* __restrict__ ws)
{
    __shared__ float Wd[48][196];
    __shared__ float innr[KSPN][49];
    __shared__ float df[KSPN][193];
    __shared__ float kd[KSPN];
    __shared__ float scl[KSPN];
    const int t = threadIdx.x;
    for (int e = t; e < 48*48; e += 256) {
        int w = e / 48, cq = e - w*48;
        *(float4*)&Wd[w][cq*4] = *(const float4*)(deW2 + (size_t)w*DD + cq*4);
    }
    const int kap = t >> 4, u = t & 15, c0 = u*12;
    for (int it = 0; it < 16; ++it) {
        const int n = blockIdx.x*16 + it;
        __syncthreads();
        if (t < KSPN) {
            float dx = p[n*3]-kn[t*3], dy = p[n*3+1]-kn[t*3+1], dz = p[n*3+2]-kn[t*3+2];
            kd[t] = sqrtf(dx*dx + dy*dy + dz*dz + 1e-12f);
        }
        __syncthreads();
        for (int e = t; e < KSPN*48; e += 256) {
            int r = e / 48, j = e - r*48;
            innr[r][j] = fmaxf(kd[r]*deW1[j] + deB1[j], 0.f);
        }
        __syncthreads();
        float a12[12];
        #pragma unroll
        for (int m = 0; m < 12; ++m) a12[m] = deB2[c0 + m];
        for (int w = 0; w < 48; ++w) {
            float av = innr[kap][w];
            #pragma unroll
            for (int m = 0; m < 12; ++m) a12[m] += av * Wd[w][c0 + m];
        }
        float ksc = 0.f;
        #pragma unroll
        for (int m = 0; m < 12; ++m) { df[kap][c0 + m] = a12[m]; ksc += a12[m]*kpW[c0 + m]; }
        #pragma unroll
        for (int off = 1; off < 16; off <<= 1) ksc += __shfl_xor(ksc, off, 16);
        if (u == 0) scl[kap] = ksc + kpB[0];
        __syncthreads();
        if (t < KSPN) {
            float v = scl[t], mx = v;
            #pragma unroll
            for (int off = 1; off < 16; off <<= 1) mx = fmaxf(mx, __shfl_xor(mx, off, 16));
            float e = expf(v - mx);
            float sm = e;
            #pragma unroll
            for (int off = 1; off < 16; off <<= 1) sm += __shfl_xor(sm, off, 16);
            scl[t] = e / sm;
        }
        __syncthreads();
        if (t < DD) {
            float dfeat = 0.f;
            #pragma unroll
            for (int k2 = 0; k2 < KSPN; ++k2) dfeat += scl[k2]*df[k2][t];
            float uval = ws[WS_X1 + (size_t)n*DD + t] + gAb[t] + gBb[t] + ws[WS_VOLV + t] + dfeat;
            uval += ws[WS_GDIS + n] * gBW[t];
            #pragma unroll
            for (int kk = 0; kk < 9; ++kk) uval += ws[WS_GEO9 + n*9 + kk] * gAW[kk*DD + t];
            ws[WS_U + (size_t)n*DD + t] = uval;
        }
    }
}

// ---- K_dqdk v3: 8 windows/block, i = blockIdx&1 (0: q0.pq, 1: k0.pk).
//      rq: W2 rows direct from global (regs) x q0 LDS-broadcast.
//      H: W1 staged, 4-row x 24-col register tiles, contraction vs rqs. ----
__global__ __launch_bounds__(256) void k_dqdk(
    const int* __restrict__ knn,
    const float* __restrict__ posW1, const float* __restrict__ posW2,
    float* __restrict__ ws)
{
    __shared__ float Wbuf[48*196];     // phase1: qk[8][192] (first 1536); phase2: W1[48][196]
    __shared__ float rqs[48*196];      // rqs[(w*6+h)*196 + kk]
    __shared__ float Xl[8][48];
    __shared__ int idx0[8];
    const int t = threadIdx.x;
    const int i = blockIdx.x & 1;
    const int nb = (blockIdx.x >> 1) * 8;
    if (t < 8) idx0[t] = knn[(nb + t)*NS];
    for (int e = t; e < 384; e += 256) {
        int w = e / 48, k = e % 48;
        Xl[w][k] = ws[WS_KNN + (size_t)(nb + w)*48 + k];
    }
    __syncthreads();
    // stage q0 (i=0) or k0 (i=1) for 8 windows into Wbuf[0..1536)
    for (int e = t; e < 384; e += 256) {
        int w = e / 48, cq = e % 48;
        *(float4*)&Wbuf[w*192 + cq*4] =
            *(const float4*)(ws + WS_QKV + (size_t)idx0[w]*576 + i*192 + cq*4);
    }
    __syncthreads();
    // rq[w][h][kk] = sum_c W2_i[kk][h*32+c] * qk[w][h*32+c]
    if (t < 192) {
        const float* Wrow = posW2 + (size_t)i*DD*DD + (size_t)t*DD;
        for (int h = 0; h < 6; ++h) {
            float4 wr[8];
            #pragma unroll
            for (int q = 0; q < 8; ++q) wr[q] = *(const float4*)(Wrow + h*32 + q*4);
            float a[8];
            #pragma unroll
            for (int w = 0; w < 8; ++w) a[w] = 0.f;
            #pragma unroll
            for (int q = 0; q < 8; ++q) {
                #pragma unroll
                for (int d = 0; d < 4; ++d) {
                    float wv = (&wr[q].x)[d];
                    int c = h*32 + q*4 + d;
                    #pragma unroll
                    for (int w = 0; w < 8; ++w) a[w] += wv * Wbuf[w*192 + c];  // broadcast read
                }
            }
            #pragma unroll
            for (int w = 0; w < 8; ++w) rqs[(w*6 + h)*196 + t] = a[w];
        }
    }
    __syncthreads();
    // stage W1_i [48][196]
    for (int e = t; e < 2304; e += 256) {
        int kk = e / 48, cq = e % 48;
        *(float4*)&Wbuf[kk*196 + cq*4] = *(const float4*)(posW1 + (size_t)(i*48 + kk)*DD + cq*4);
    }
    __syncthreads();
    // H rows (4 per thread) x 24 cols; then contraction vs rqs
    {
        const int cg = t & 7, rg = t >> 3;
        const int w = rg >> 2, j0 = (rg & 3)*4, c0 = cg*24;
        float cx0[3], cx1[3], cx2[3], cx3[3];
        #pragma unroll
        for (int d = 0; d < 3; ++d) {
            cx0[d] = Xl[w][(j0+0)*3 + d];
            cx1[d] = Xl[w][(j0+1)*3 + d];
            cx2[d] = Xl[w][(j0+2)*3 + d];
            cx3[d] = Xl[w][(j0+3)*3 + d];
        }
        float acc0[24], acc1[24], acc2[24], acc3[24];
        #pragma unroll
        for (int m = 0; m < 24; ++m) { acc0[m]=0.f; acc1[m]=0.f; acc2[m]=0.f; acc3[m]=0.f; }
        for (int k3 = 0; k3 < 16; ++k3) {
            #pragma unroll
            for (int d = 0; d < 3; ++d) {
                int k = k3*3 + d;
                float xk = Xl[w][k];
                float av0 = xk - cx0[d], av1 = xk - cx1[d];
                float av2 = xk - cx2[d], av3 = xk - cx3[d];
                #pragma unroll
                for (int m = 0; m < 24; ++m) {
                    float wv = Wbuf[k*196 + c0 + m];
                    acc0[m] += av0*wv; acc1[m] += av1*wv;
                    acc2[m] += av2*wv; acc3[m] += av3*wv;
                }
            }
        }
        #pragma unroll
        for (int m = 0; m < 24; ++m) {
            int c = c0 + m;
            float as = ws[WS_AB + i*DD + c];
            float bb = ws[WS_AB + 576 + i*DD + c];
            acc0[m] = fmaxf(acc0[m]*as + bb, 0.f);
            acc1[m] = fmaxf(acc1[m]*as + bb, 0.f);
            acc2[m] = fmaxf(acc2[m]*as + bb, 0.f);
            acc3[m] = fmaxf(acc3[m]*as + bb, 0.f);
        }
        #pragma unroll
        for (int h = 0; h < 6; ++h) {
            float s0 = 0.f, s1 = 0.f, s2 = 0.f, s3 = 0.f;
            #pragma unroll
            for (int m = 0; m < 24; ++m) {
                float rv = rqs[(w*6 + h)*196 + c0 + m];
                s0 += acc0[m]*rv; s1 += acc1[m]*rv; s2 += acc2[m]*rv; s3 += acc3[m]*rv;
            }
            #pragma unroll
            for (int off = 1; off < 8; off <<= 1) {
                s0 += __shfl_xor(s0, off, 8); s1 += __shfl_xor(s1, off, 8);
                s2 += __shfl_xor(s2, off, 8); s3 += __shfl_xor(s3, off, 8);
            }
            if (cg == 0) {
                float* dst = ws + WS_SC + (size_t)(nb + w)*192 + i*96 + h*16 + j0;
                dst[0] = s0; dst[1] = s1; dst[2] = s2; dst[3] = s3;
            }
        }
    }
}

// ---- K_score: q0.k_j dots + softmax + CTR1 = attn@v; stores attn ----
__global__ __launch_bounds__(256) void k_score(
    const int* __restrict__ knn, float* __restrict__ ws)
{
    __shared__ float Kw[NS][196];
    __shared__ float Vw[NS][196];
    __shared__ float q0s[192];
    __shared__ float dqks[6][16];
    __shared__ float attns[6][16];
    __shared__ int idx[NS];
    const int n = blockIdx.x;
    const int t = threadIdx.x;
    if (t < NS) idx[t] = knn[n*NS + t];
    __syncthreads();
    for (int e = t; e < NS*48; e += 256) {
        int r = e/48, cq = e%48;
        *(float4*)&Kw[r][cq*4] = *(const float4*)(ws + WS_QKV + (size_t)idx[r]*576 + 192 + cq*4);
        *(float4*)&Vw[r][cq*4] = *(const float4*)(ws + WS_QKV + (size_t)idx[r]*576 + 384 + cq*4);
    }
    if (t < DD) q0s[t] = ws[WS_QKV + (size_t)idx[0]*576 + t];
    __syncthreads();
    {   // dqk[h][j] = q0 . k_j per head
        const int j = t >> 4, u = t & 15;
        #pragma unroll
        for (int h = 0; h < 6; ++h) {
            int c = h*32 + u*2;
            float v = q0s[c]*Kw[j][c] + q0s[c+1]*Kw[j][c+1];
            #pragma unroll
            for (int off = 1; off < 16; off <<= 1) v += __shfl_xor(v, off, 16);
            if (u == 0) dqks[h][j] = v;
        }
    }
    __syncthreads();
    if (t < 96) {   // softmax rows: h = t>>4, jj = t&15
        const float scale = 0.17677669529663687f;  // 32^-0.5
        const int h = t >> 4, jj = t & 15;
        float z = (dqks[h][jj]
                 + ws[WS_SC + (size_t)n*192 + h*16 + jj]
                 + ws[WS_SC + (size_t)n*192 + 96 + h*16 + jj]) * scale;
        float mx = z;
        #pragma unroll
        for (int off = 1; off < 16; off <<= 1) mx = fmaxf(mx, __shfl_xor(mx, off, 16));
        float e = expf(z - mx);
        float sm = e;
        #pragma unroll
        for (int off = 1; off < 16; off <<= 1) sm += __shfl_xor(sm, off, 16);
        float a = e / sm;
        attns[h][jj] = a;
        ws[WS_ATTN + (size_t)n*96 + h*16 + jj] = a;
    }
    __syncthreads();
    if (t < DD) {   // CTR1 = attn@v
        const int h = t >> 5;
        float s = 0.f;
        #pragma unroll
        for (int jj = 0; jj < NS; ++jj) s += attns[h][jj] * Vw[jj][t];
        ws[WS_X1 + (size_t)n*DD + t] = s;
    }
}

// ---- K_pv v2: 8 windows/block. Fused H2+wsum (register tiles + shuffle reduce),
//      then pv = wsum @ W2_2 via pre-transposed W2T rows from global. ----
__global__ __launch_bounds__(256) void k_pv(
    const float* __restrict__ posW1, const float* __restrict__ posB2,
    float* __restrict__ ws)
{
    __shared__ float Wbuf[48*196];      // W1_2
    __shared__ float wsum[8*6*196];     // [w][h][kk], stride 196
    __shared__ float attns[8][96];
    __shared__ float Xl[8][48];
    const int t = threadIdx.x;
    const int nb = blockIdx.x * 8;
    for (int e = t; e < 384; e += 256) {
        int w = e/48, k = e%48;
        Xl[w][k] = ws[WS_KNN + (size_t)(nb+w)*48 + k];
    }
    for (int e = t; e < 768; e += 256) {
        int w = e/96, r = e%96;
        attns[w][r] = ws[WS_ATTN + (size_t)(nb+w)*96 + r];
    }
    for (int e = t; e < 2304; e += 256) {     // stage W1_2
        int kk = e/48, cq = e%48;
        *(float4*)&Wbuf[kk*196 + cq*4] = *(const float4*)(posW1 + (size_t)(96+kk)*DD + cq*4);
    }
    __syncthreads();
    // H2 (4 rows x 24 cols register tiles) fused with attn-weighted reduce -> wsum
    {
        const int cg = t & 7, rg5 = (t >> 3) & 3, w = t >> 5;
        const int j0 = rg5*4, c0 = cg*24;
        float cx0[3], cx1[3], cx2[3], cx3[3];
        #pragma unroll
        for (int d = 0; d < 3; ++d) {
            cx0[d] = Xl[w][(j0+0)*3 + d];
            cx1[d] = Xl[w][(j0+1)*3 + d];
            cx2[d] = Xl[w][(j0+2)*3 + d];
            cx3[d] = Xl[w][(j0+3)*3 + d];
        }
        float acc0[24], acc1[24], acc2[24], acc3[24];
        #pragma unroll
        for (int m = 0; m < 24; ++m) { acc0[m]=0.f; acc1[m]=0.f; acc2[m]=0.f; acc3[m]=0.f; }
        for (int k3 = 0; k3 < 16; ++k3) {
            #pragma unroll
            for (int d = 0; d < 3; ++d) {
                int k = k3*3 + d;
                float xk = Xl[w][k];
                float av0 = xk - cx0[d], av1 = xk - cx1[d];
                float av2 = xk - cx2[d], av3 = xk - cx3[d];
                #pragma unroll
                for (int m = 0; m < 24; ++m) {
                    float wv = Wbuf[k*196 + c0 + m];
                    acc0[m] += av0*wv; acc1[m] += av1*wv;
                    acc2[m] += av2*wv; acc3[m] += av3*wv;
                }
            }
        }
        #pragma unroll
        for (int m = 0; m < 24; ++m) {
            int c = c0 + m;
            float as = ws[WS_AB + 2*DD + c];
            float bb = ws[WS_AB + 576 + 2*DD + c];
            acc0[m] = fmaxf(acc0[m]*as + bb, 0.f);
            acc1[m] = fmaxf(acc1[m]*as + bb, 0.f);
            acc2[m] = fmaxf(acc2[m]*as + bb, 0.f);
            acc3[m] = fmaxf(acc3[m]*as + bb, 0.f);
        }
        #pragma unroll
        for (int h = 0; h < 6; ++h) {
            float a0 = attns[w][h*16 + j0 + 0];
            float a1 = attns[w][h*16 + j0 + 1];
            float a2 = attns[w][h*16 + j0 + 2];
            float a3 = attns[w][h*16 + j0 + 3];
            #pragma unroll
            for (int m = 0; m < 24; ++m) {
                float pm = a0*acc0[m] + a1*acc1[m] + a2*acc2[m] + a3*acc3[m];
                pm += __shfl_xor(pm, 8, 32);    // reduce over rg5 bit 0 (t bit 3)
                pm += __shfl_xor(pm, 16, 32);   // reduce over rg5 bit 1 (t bit 4)
                if (rg5 == 0) wsum[(w*6 + h)*196 + c0 + m] = pm;
            }
        }
    }
    __syncthreads();
    // pv: thread t<192 owns col c=t; 8 windows in registers; W2T rows from global
    if (t < DD) {
        const int h = t >> 5;
        float pvacc[8];
        #pragma unroll
        for (int w = 0; w < 8; ++w) pvacc[w] = 0.f;
        const float* wrow = ws + WS_W2T + (size_t)t*DD;
        for (int k4 = 0; k4 < 48; ++k4) {
            float4 wv = *(const float4*)(wrow + k4*4);
            #pragma unroll
            for (int w = 0; w < 8; ++w) {
                float4 av = *(const float4*)&wsum[(w*6 + h)*196 + k4*4];  // 2-addr broadcast
                pvacc[w] += av.x*wv.x + av.y*wv.y + av.z*wv.z + av.w*wv.w;
            }
        }
        float b2 = posB2[2*DD + t];
        #pragma unroll
        for (int w = 0; w < 8; ++w) {
            ws[WS_U + (size_t)(nb+w)*DD + t] =
                ws[WS_X1 + (size_t)(nb+w)*DD + t] + pvacc[w] + b2;
        }
    }
}

extern "C" void kernel_launch(void* const* d_in, const int* in_sizes, int n_in,
                              void* d_out, int out_size, void* d_ws, size_t ws_size,
                              hipStream_t stream)
{
    const float* p     = (const float*)d_in[0];
    const float* x     = (const float*)d_in[1];
    const int*   knn   = (const int*)  d_in[2];
    const float* Wqkv  = (const float*)d_in[3];
    const float* Wproj = (const float*)d_in[4];
    const float* bproj = (const float*)d_in[5];
    const float* propW = (const float*)d_in[6];
    const float* propB = (const float*)d_in[7];
    const float* gAW   = (const float*)d_in[8];
    const float* gAb   = (const float*)d_in[9];
    const float* gBW   = (const float*)d_in[10];
    const float* gBb   = (const float*)d_in[11];
    const float* gCW   = (const float*)d_in[12];
    const float* gCb   = (const float*)d_in[13];
    const float* posW1 = (const float*)d_in[14];
    const float* posB1 = (const float*)d_in[15];
    const float* gamma = (const float*)d_in[16];
    const float* beta  = (const float*)d_in[17];
    const float* posW2 = (const float*)d_in[18];
    const float* posB2 = (const float*)d_in[19];
    const float* kn    = (const float*)d_in[20];
    const float* deW1  = (const float*)d_in[21];
    const float* deB1  = (const float*)d_in[22];
    const float* deW2  = (const float*)d_in[23];
    const float* deB2  = (const float*)d_in[24];
    const float* kpW   = (const float*)d_in[25];
    const float* kpB   = (const float*)d_in[26];
    const float* fusW  = (const float*)d_in[27];
    const float* fusB  = (const float*)d_in[28];
    float* ws   = (float*)d_ws;
    float* outp = (float*)d_out;

    hipLaunchKernelGGL(k_init, dim3(10), dim3(256), 0, stream, ws);
    hipLaunchKernelGGL(k_w2t, dim3(144), dim3(256), 0, stream, posW2, ws);
    hipLaunchKernelGGL(k1_glue, dim3(NP/16), dim3(256), 0, stream, p, knn, ws);
    hipLaunchKernelGGL(k2_fold, dim3(3), dim3(256), 0, stream,
                       posW1, posB1, gamma, beta, gCW, gCb, ws);
    hipLaunchKernelGGL(k_prop, dim3(MTOT/64), dim3(256), 0, stream, x, knn, propW, propB, ws);
    hipLaunchKernelGGL(k3a, dim3(NP/16), dim3(256), 0, stream,
                       p, kn, deW1, deB1, deW2, deB2, kpW, kpB, gAW, gAb, gBW, gBb, ws);
    hipLaunchKernelGGL(gemm_bias, dim3(NP/64, 3), dim3(256), 0, stream,
                       ws + WS_U, fusW, fusB, ws + WS_X2, DD);        // X2 = U@fusW+fusB
    hipLaunchKernelGGL(gemm_bias, dim3(NP/64, 9), dim3(256), 0, stream,
                       ws + WS_X2, Wqkv, (const float*)nullptr, ws + WS_QKV, 576);  // QKV
    hipLaunchKernelGGL(k_dqdk, dim3(NP/4), dim3(256), 0, stream, knn, posW1, posW2, ws);
    hipLaunchKernelGGL(k_score, dim3(NP), dim3(256), 0, stream, knn, ws);
    hipLaunchKernelGGL(k_pv, dim3(NP/8), dim3(256), 0, stream, posW1, posB2, ws);
    hipLaunchKernelGGL(gemm_bias, dim3(NP/64, 3), dim3(256), 0, stream,
                       ws + WS_U, Wproj, bproj, outp, DD);            // OUT = CTR@Wproj+bproj
}

// Round 6
// 1117.930 us; speedup vs baseline: 7.5146x; 1.2103x over previous
//
#include <hip/hip_runtime.h>
#include <math.h>

#define NP 16384
#define DD 192
#define NS 16
#define KSPN 16
#define MTOT (NP*NS)

typedef unsigned short ushort_t;
typedef __attribute__((ext_vector_type(8))) short short8;
typedef __attribute__((ext_vector_type(4))) float f32x4;

__device__ __forceinline__ ushort_t f2bf(float f) {
    union { float f; unsigned int u; } v; v.f = f;
    return (ushort_t)((v.u + 0x7FFFu + ((v.u >> 16) & 1u)) >> 16);
}

// ws float offsets
#define WS_KNN   0                         // NP*48   knn_xyz
#define WS_PR    (WS_KNN + NP*48)          // MTOT*3  p_r per window row
#define WS_GEO9  (WS_PR + MTOT*3)          // NP*9
#define WS_GDIS  (WS_GEO9 + NP*9)          // NP
#define WS_STATS (WS_GDIS + NP)            // [0]=dsum [1]=dmax(bits) [2..50)=possum [50..2354)=M2
#define WS_VOLV  (WS_STATS + 2354)         // 192
#define WS_AB    (WS_VOLV + DD)            // a[3][192] | bb[3][192] = 1152
#define WS_X1    (WS_AB + 1152)            // NP*192 post-propagate; later CTR1 (attn@v)
#define WS_U     (WS_X1 + NP*DD)           // NP*192: CTRB (bf16) after k_pv
#define WS_X2    (WS_U + NP*DD)            // NP*192: X2B (bf16, written by fus gemm)
#define WS_QKV   (WS_X2 + NP*DD)           // NP*576
#define WS_SC    (WS_QKV + NP*576)         // NP*192  SC[n][i(2)][h(6)][j(16)]; early: XB overlay
#define WS_ATTN  (WS_SC + NP*DD)           // NP*96   attn; early: UB (bf16) overlay
#define WS_W2T   (WS_ATTN + NP*96)         // 192*192 transposed posW2[2] fp32
#define WS_PROPWT (WS_W2T + 36864)         // 192*192 bf16 = 18432 floats (transposed propW[:192])
#define WS_QKVT  (WS_PROPWT + 18432)       // 576*192 bf16 = 55296 floats
#define WS_FUSWT (WS_QKVT + 55296)         // 18432
#define WS_PROJWT (WS_FUSWT + 18432)       // 18432
// overlays (bf16 arrays in dead-interval regions):
#define WS_XB    WS_SC                     // NP*192 bf16 (dead before k_dqdk writes SC)
#define WS_UB    WS_ATTN                   // NP*192 bf16 (dead before k_score writes ATTN)
#define WS_X2B   WS_X2
#define WS_CTRB  WS_U
// total ~25.5M floats ~102 MB

__global__ __launch_bounds__(256) void k_init(float* __restrict__ ws) {
    int t = blockIdx.x * 256 + threadIdx.x;
    if (t < 2354) ws[WS_STATS + t] = 0.f;
}

// ---- tiny: W2T[c][kk] = posW2[2][kk][c] (fp32, for k_pv) ----
__global__ __launch_bounds__(256) void k_w2t(const float* __restrict__ posW2,
                                             float* __restrict__ ws) {
    int e = blockIdx.x*256 + threadIdx.x;      // e = c*192 + kk
    int c = e / DD, kk = e - c*DD;
    ws[WS_W2T + e] = posW2[(size_t)(2*DD + kk)*DD + c];
}

// ---- prep: bf16 transposed weight copies (n-major, k-contiguous) ----
__global__ __launch_bounds__(256) void k_prep(
    const float* __restrict__ propW, const float* __restrict__ Wqkv,
    const float* __restrict__ fusW, const float* __restrict__ Wproj,
    float* __restrict__ ws)
{
    int e = blockIdx.x*256 + threadIdx.x;
    ushort_t* pwt = (ushort_t*)(ws + WS_PROPWT);
    ushort_t* qkt = (ushort_t*)(ws + WS_QKVT);
    ushort_t* fwt = (ushort_t*)(ws + WS_FUSWT);
    ushort_t* pjt = (ushort_t*)(ws + WS_PROJWT);
    if (e < 36864) {
        int n = e/192, k = e - n*192;
        pwt[e] = f2bf(propW[(size_t)k*192 + n]);
    } else if (e < 147456) {
        int r = e - 36864; int n = r/192, k = r - n*192;
        qkt[r] = f2bf(Wqkv[(size_t)k*576 + n]);
    } else if (e < 184320) {
        int r = e - 147456; int n = r/192, k = r - n*192;
        fwt[r] = f2bf(fusW[(size_t)k*192 + n]);
    } else if (e < 221184) {
        int r = e - 184320; int n = r/192, k = r - n*192;
        pjt[r] = f2bf(Wproj[(size_t)k*192 + n]);
    }
}

// ---- cast x -> bf16 ----
__global__ __launch_bounds__(256) void k_castx(const float* __restrict__ x,
                                               float* __restrict__ ws) {
    int e = blockIdx.x*256 + threadIdx.x;
    ((ushort_t*)(ws + WS_XB))[e] = f2bf(x[e]);
}

// ---- K1: geometry glue + stats ----
__global__ __launch_bounds__(256) void k1_glue(
    const float* __restrict__ p, const int* __restrict__ knn,
    float* __restrict__ ws)
{
    __shared__ float Xl[48];
    __shared__ float pos[NS][49];
    __shared__ float distl[NS];
    __shared__ int idx[NS];
    __shared__ float pn[3];
    const int t = threadIdx.x;
    float m2acc[9];
    #pragma unroll
    for (int q = 0; q < 9; ++q) m2acc[q] = 0.f;
    float psacc = 0.f, dsum_loc = 0.f, dmax_loc = 0.f;

    for (int it = 0; it < 16; ++it) {
        const int n = blockIdx.x * 16 + it;
        __syncthreads();
        if (t < NS) idx[t] = knn[n*NS + t];
        if (t < 3)  pn[t] = p[n*3 + t];
        __syncthreads();
        if (t < 48) { float v = p[idx[t/3]*3 + (t % 3)]; Xl[t] = v; ws[WS_KNN + n*48 + t] = v; }
        __syncthreads();
        if (t < 48) {
            int j = t/3, c = t % 3;
            ws[WS_PR + (n*NS + j)*3 + c] = Xl[t] - pn[c];
        }
        if (t < NS) {
            float dx = Xl[t*3]-pn[0], dy = Xl[t*3+1]-pn[1], dz = Xl[t*3+2]-pn[2];
            distl[t] = sqrtf(dx*dx + dy*dy + dz*dz + 1e-12f);
        }
        for (int e = t; e < NS*48; e += 256) {
            int r = e/48, k = e - r*48;
            pos[r][k] = Xl[k] - Xl[r*3 + (k % 3)];
        }
        __syncthreads();
        if (t == 0) {
            float dm = 0.f, ds = 0.f;
            for (int j = 0; j < NS; ++j) { dm = fmaxf(dm, distl[j]); ds += distl[j]; }
            ws[WS_GDIS + n] = dm;
            dsum_loc += ds; dmax_loc = fmaxf(dmax_loc, dm);
        }
        if (t < 3) {
            float mx = 0.f;
            for (int j = 0; j < NS; ++j) mx += Xl[j*3 + t];
            mx *= (1.f/16.f);
            ws[WS_GEO9 + n*9 + t]     = mx - pn[t];
            ws[WS_GEO9 + n*9 + 3 + t] = mx;
            ws[WS_GEO9 + n*9 + 6 + t] = pn[t];
        }
        {
            int e = t;
            #pragma unroll
            for (int q = 0; q < 9; ++q) {
                int a = e / 48, b = e - a*48;
                float s = 0.f;
                for (int j = 0; j < NS; ++j) s += pos[j][a] * pos[j][b];
                m2acc[q] += s;
                e += 256;
            }
        }
        if (t < 48) { float s = 0.f; for (int j = 0; j < NS; ++j) s += pos[j][t]; psacc += s; }
    }
    {
        int e = t;
        #pragma unroll
        for (int q = 0; q < 9; ++q) { atomicAdd(&ws[WS_STATS + 50 + e], m2acc[q]); e += 256; }
    }
    if (t < 48) atomicAdd(&ws[WS_STATS + 2 + t], psacc);
    if (t == 0) {
        atomicAdd(&ws[WS_STATS + 0], dsum_loc);
        atomicMax((int*)(ws + WS_STATS + 1), __float_as_int(dmax_loc));  // dist>=0
    }
}

// ---- K2: vol vector + BN fold (var via M2) -> a/bb ----
__global__ __launch_bounds__(256) void k2_fold(
    const float* __restrict__ posW1, const float* __restrict__ posB1,
    const float* __restrict__ gamma, const float* __restrict__ beta,
    const float* __restrict__ gCW, const float* __restrict__ gCb,
    float* __restrict__ ws)
{
    __shared__ float M2n[48][48];
    __shared__ float pmean[48];
    __shared__ float Wc[48][193];
    const int t = threadIdx.x;
    const int i = blockIdx.x;
    for (int e = t; e < 2304; e += 256) ((float*)M2n)[e] = ws[WS_STATS + 50 + e] * (1.f/(float)MTOT);
    if (t < 48) pmean[t] = ws[WS_STATS + 2 + t] * (1.f/(float)MTOT);
    if (t < DD) {
        for (int k = 0; k < 48; ++k) Wc[k][t] = posW1[(size_t)(i*48 + k)*DD + t];
    }
    __syncthreads();
    if (i == 0 && t < DD) {
        float dsum = ws[WS_STATS + 0];
        float dmax = __int_as_float(((const int*)(ws + WS_STATS))[1]);
        float vol = (dsum * (1.f/(float)MTOT)) / (dmax + 1e-8f);
        ws[WS_VOLV + t] = vol * gCW[t] + gCb[t];
    }
    if (t < DD) {
        float mu0 = 0.f;
        #pragma unroll 8
        for (int k = 0; k < 48; ++k) mu0 += pmean[k] * Wc[k][t];
        float e2 = 0.f;
        for (int a2 = 0; a2 < 48; ++a2) {
            float inner = 0.f;
            #pragma unroll 8
            for (int b2 = 0; b2 < 48; ++b2) inner += M2n[a2][b2] * Wc[b2][t];
            e2 += Wc[a2][t] * inner;
        }
        float var = fmaxf(e2 - mu0*mu0, 0.f);
        float as = rsqrtf(var + 1e-5f) * gamma[i*DD + t];
        ws[WS_AB + i*DD + t]       = as;
        ws[WS_AB + 576 + i*DD + t] = beta[i*DD + t] - mu0 * as;   // h'=relu(acc*as+bb)
    }
}

// ---- K_prop MFMA: gathered bf16 GEMM + fp32 p_r tail + relu + window mean ----
__global__ __launch_bounds__(256) void k_prop_mfma(
    const float* __restrict__ x, const int* __restrict__ knn,
    const float* __restrict__ propW, const float* __restrict__ propB,
    float* __restrict__ ws)
{
    __shared__ ushort_t As[64*40];     // A tile, stride 40 bf16 (80 B)
    __shared__ ushort_t Bs[192*40];    // Bt tile
    __shared__ float prs[64*3];
    __shared__ float W3[3*192];
    __shared__ int idx64[64];
    const int t = threadIdx.x;
    const int mbase = blockIdx.x * 64;
    const ushort_t* xb = (const ushort_t*)(ws + WS_XB);
    const ushort_t* pwt = (const ushort_t*)(ws + WS_PROPWT);
    if (t < 64) idx64[t] = knn[mbase + t];
    for (int e = t; e < 576; e += 256) W3[e] = propW[(size_t)(192 + e/192)*DD + (e % 192)];
    for (int e = t; e < 192; e += 256) prs[e] = ws[WS_PR + (size_t)mbase*3 + e];
    const int wave = t >> 6, lane = t & 63, m = lane & 15, quad = lane >> 4;
    f32x4 acc[12];
    #pragma unroll
    for (int nt = 0; nt < 12; ++nt) acc[nt] = (f32x4){0.f,0.f,0.f,0.f};
    for (int ks = 0; ks < 6; ++ks) {
        const int k0 = ks*32;
        __syncthreads();
        {   int r = t >> 2, seg = t & 3;
            *(uint4*)&As[r*40 + seg*8] = *(const uint4*)(xb + (size_t)idx64[r]*192 + k0 + seg*8);
        }
        for (int e = t; e < 768; e += 256) {
            int n = e >> 2, seg = e & 3;
            *(uint4*)&Bs[n*40 + seg*8] = *(const uint4*)(pwt + (size_t)n*192 + k0 + seg*8);
        }
        __syncthreads();
        short8 a = *(const short8*)&As[(wave*16 + m)*40 + quad*8];
        #pragma unroll
        for (int nt = 0; nt < 12; ++nt) {
            short8 b = *(const short8*)&Bs[(nt*16 + m)*40 + quad*8];
            acc[nt] = __builtin_amdgcn_mfma_f32_16x16x32_bf16(a, b, acc[nt], 0, 0, 0);
        }
    }
    const int n = blockIdx.x*4 + wave;   // global point
    #pragma unroll
    for (int nt = 0; nt < 12; ++nt) {
        int col = nt*16 + m;
        float bv = propB[col];
        float w0 = W3[col], w1 = W3[192 + col], w2 = W3[384 + col];
        float s = 0.f;
        #pragma unroll
        for (int reg = 0; reg < 4; ++reg) {
            int j = wave*16 + quad*4 + reg;
            float v = acc[nt][reg] + prs[j*3+0]*w0 + prs[j*3+1]*w1 + prs[j*3+2]*w2 + bv;
            s += fmaxf(v, 0.f);
        }
        s += __shfl_xor(s, 16);
        s += __shfl_xor(s, 32);
        if (quad == 0)
            ws[WS_X1 + (size_t)n*DD + col] = x[(size_t)n*DD + col] + s * (1.f/16.f);
    }
}

// ---- generic bf16 MFMA GEMM: C[M x N] = A[M x 192] @ Bt^T (+bias) ----
__global__ __launch_bounds__(256) void gemm_mfma(
    const ushort_t* __restrict__ A, const ushort_t* __restrict__ Bt,
    const float* __restrict__ bias, float* __restrict__ Cf,
    ushort_t* __restrict__ Cb, int N)
{
    __shared__ ushort_t As[64*40];
    __shared__ ushort_t Bs[64*40];
    const int t = threadIdx.x;
    const int wave = t >> 6, lane = t & 63, m = lane & 15, quad = lane >> 4;
    const int rowBase = blockIdx.x * 64, colBase = blockIdx.y * 64;
    f32x4 acc[4];
    #pragma unroll
    for (int nt = 0; nt < 4; ++nt) acc[nt] = (f32x4){0.f,0.f,0.f,0.f};
    for (int ks = 0; ks < 6; ++ks) {
        __syncthreads();
        {   int r = t >> 2, seg = t & 3;
            *(uint4*)&As[r*40 + seg*8] = *(const uint4*)(A + (size_t)(rowBase + r)*192 + ks*32 + seg*8);
            *(uint4*)&Bs[r*40 + seg*8] = *(const uint4*)(Bt + (size_t)(colBase + r)*192 + ks*32 + seg*8);
        }
        __syncthreads();
        short8 a = *(const short8*)&As[(wave*16 + m)*40 + quad*8];
        #pragma unroll
        for (int nt = 0; nt < 4; ++nt) {
            short8 b = *(const short8*)&Bs[(nt*16 + m)*40 + quad*8];
            acc[nt] = __builtin_amdgcn_mfma_f32_16x16x32_bf16(a, b, acc[nt], 0, 0, 0);
        }
    }
    #pragma unroll
    for (int nt = 0; nt < 4; ++nt) {
        int col = colBase + nt*16 + m;
        float bv = bias ? bias[col] : 0.f;
        #pragma unroll
        for (int reg = 0; reg < 4; ++reg) {
            int row = rowBase + wave*16 + quad*4 + reg;
            float v = acc[nt][reg] + bv;
            if (Cf) Cf[(size_t)row*N + col] = v;
            else    Cb[(size_t)row*N + col] = f2bf(v);
        }
    }
}

// ---- K3a: keypoint attention + U assembly (writes bf16 UB) ----
__global__ __launch_bounds__(256) void k3a(
    const float* __restrict__ p, const float* __restrict__ kn,
    const float* __restrict__ deW1, const float* __restrict__ deB1,
    const float* __restrict__ deW2, const float* __restrict__ deB2,
    const float* __restrict__ kpW, const float* __restrict__ kpB,
    const float* __restrict__ gAW, const float* __restrict__ gAb,
    const float* __restrict__ gBW, const float* __restrict__ gBb,
    float* __restrict__ ws)
{
    __shared__ float Wd[48][196];
    __shared__ float innr[KSPN][49];
    __shared__ float df[KSPN][193];
    __shared__ float kd[KSPN];
    __shared__ float scl[KSPN];
    ushort_t* ub = (ushort_t*)(ws + WS_UB);
    const int t = threadIdx.x;
    for (int e = t; e < 48*48; e += 256) {
        int w = e / 48, cq = e - w*48;
        *(float4*)&Wd[w][cq*4] = *(const float4*)(deW2 + (size_t)w*DD + cq*4);
    }
    const int kap = t >> 4, u = t & 15, c0 = u*12;
    for (int it = 0; it < 16; ++it) {
        const int n = blockIdx.x*16 + it;
        __syncthreads();
        if (t < KSPN) {
            float dx = p[n*3]-kn[t*3], dy = p[n*3+1]-kn[t*3+1], dz = p[n*3+2]-kn[t*3+2];
            kd[t] = sqrtf(dx*dx + dy*dy + dz*dz + 1e-12f);
        }
        __syncthreads();
        for (int e = t; e < KSPN*48; e += 256) {
            int r = e / 48, j = e - r*48;
            innr[r][j] = fmaxf(kd[r]*deW1[j] + deB1[j], 0.f);
        }
        __syncthreads();
        float a12[12];
        #pragma unroll
        for (int m = 0; m < 12; ++m) a12[m] = deB2[c0 + m];
        for (int w = 0; w < 48; ++w) {
            float av = innr[kap][w];
            #pragma unroll
            for (int m = 0; m < 12; ++m) a12[m] += av * Wd[w][c0 + m];
        }
        float ksc = 0.f;
        #pragma unroll
        for (int m = 0; m < 12; ++m) { df[kap][c0 + m] = a12[m]; ksc += a12[m]*kpW[c0 + m]; }
        #pragma unroll
        for (int off = 1; off < 16; off <<= 1) ksc += __shfl_xor(ksc, off, 16);
        if (u == 0) scl[kap] = ksc + kpB[0];
        __syncthreads();
        if (t < KSPN) {
            float v = scl[t], mx = v;
            #pragma unroll
            for (int off = 1; off < 16; off <<= 1) mx = fmaxf(mx, __shfl_xor(mx, off, 16));
            float e = expf(v - mx);
            float sm = e;
            #pragma unroll
            for (int off = 1; off < 16; off <<= 1) sm += __shfl_xor(sm, off, 16);
            scl[t] = e / sm;
        }
        __syncthreads();
        if (t < DD) {
            float dfeat = 0.f;
            #pragma unroll
            for (int k2 = 0; k2 < KSPN; ++k2) dfeat += scl[k2]*df[k2][t];
            float uval = ws[WS_X1 + (size_t)n*DD + t] + gAb[t] + gBb[t] + ws[WS_VOLV + t] + dfeat;
            uval += ws[WS_GDIS + n] * gBW[t];
            #pragma unroll
            for (int kk = 0; kk < 9; ++kk) uval += ws[WS_GEO9 + n*9 + kk] * gAW[kk*DD + t];
            ub[(size_t)n*DD + t] = f2bf(uval);
        }
    }
}

// ---- K_dqdk v3 (unchanged) ----
__global__ __launch_bounds__(256) void k_dqdk(
    const int* __restrict__ knn,
    const float* __restrict__ posW1, const float* __restrict__ posW2,
    float* __restrict__ ws)
{
    __shared__ float Wbuf[48*196];
    __shared__ float rqs[48*196];
    __shared__ float Xl[8][48];
    __shared__ int idx0[8];
    const int t = threadIdx.x;
    const int i = blockIdx.x & 1;
    const int nb = (blockIdx.x >> 1) * 8;
    if (t < 8) idx0[t] = knn[(nb + t)*NS];
    for (int e = t; e < 384; e += 256) {
        int w = e / 48, k = e % 48;
        Xl[w][k] = ws[WS_KNN + (size_t)(nb + w)*48 + k];
    }
    __syncthreads();
    for (int e = t; e < 384; e += 256) {
        int w = e / 48, cq = e % 48;
        *(float4*)&Wbuf[w*192 + cq*4] =
            *(const float4*)(ws + WS_QKV + (size_t)idx0[w]*576 + i*192 + cq*4);
    }
    __syncthreads();
    if (t < 192) {
        const float* Wrow = posW2 + (size_t)i*DD*DD + (size_t)t*DD;
        for (int h = 0; h < 6; ++h) {
            float4 wr[8];
            #pragma unroll
            for (int q = 0; q < 8; ++q) wr[q] = *(const float4*)(Wrow + h*32 + q*4);
            float a[8];
            #pragma unroll
            for (int w = 0; w < 8; ++w) a[w] = 0.f;
            #pragma unroll
            for (int q = 0; q < 8; ++q) {
                #pragma unroll
                for (int d = 0; d < 4; ++d) {
                    float wv = (&wr[q].x)[d];
                    int c = h*32 + q*4 + d;
                    #pragma unroll
                    for (int w = 0; w < 8; ++w) a[w] += wv * Wbuf[w*192 + c];
                }
            }
            #pragma unroll
            for (int w = 0; w < 8; ++w) rqs[(w*6 + h)*196 + t] = a[w];
        }
    }
    __syncthreads();
    for (int e = t; e < 2304; e += 256) {
        int kk = e / 48, cq = e % 48;
        *(float4*)&Wbuf[kk*196 + cq*4] = *(const float4*)(posW1 + (size_t)(i*48 + kk)*DD + cq*4);
    }
    __syncthreads();
    {
        const int cg = t & 7, rg = t >> 3;
        const int w = rg >> 2, j0 = (rg & 3)*4, c0 = cg*24;
        float cx0[3], cx1[3], cx2[3], cx3[3];
        #pragma unroll
        for (int d = 0; d < 3; ++d) {
            cx0[d] = Xl[w][(j0+0)*3 + d];
            cx1[d] = Xl[w][(j0+1)*3 + d];
            cx2[d] = Xl[w][(j0+2)*3 + d];
            cx3[d] = Xl[w][(j0+3)*3 + d];
        }
        float acc0[24], acc1[24], acc2[24], acc3[24];
        #pragma unroll
        for (int m = 0; m < 24; ++m) { acc0[m]=0.f; acc1[m]=0.f; acc2[m]=0.f; acc3[m]=0.f; }
        for (int k3 = 0; k3 < 16; ++k3) {
            #pragma unroll
            for (int d = 0; d < 3; ++d) {
                int k = k3*3 + d;
                float xk = Xl[w][k];
                float av0 = xk - cx0[d], av1 = xk - cx1[d];
                float av2 = xk - cx2[d], av3 = xk - cx3[d];
                #pragma unroll
                for (int m = 0; m < 24; ++m) {
                    float wv = Wbuf[k*196 + c0 + m];
                    acc0[m] += av0*wv; acc1[m] += av1*wv;
                    acc2[m] += av2*wv; acc3[m] += av3*wv;
                }
            }
        }
        #pragma unroll
        for (int m = 0; m < 24; ++m) {
            int c = c0 + m;
            float as = ws[WS_AB + i*DD + c];
            float bb = ws[WS_AB + 576 + i*DD + c];
            acc0[m] = fmaxf(acc0[m]*as + bb, 0.f);
            acc1[m] = fmaxf(acc1[m]*as + bb, 0.f);
            acc2[m] = fmaxf(acc2[m]*as + bb, 0.f);
            acc3[m] = fmaxf(acc3[m]*as + bb, 0.f);
        }
        #pragma unroll
        for (int h = 0; h < 6; ++h) {
            float s0 = 0.f, s1 = 0.f, s2 = 0.f, s3 = 0.f;
            #pragma unroll
            for (int m = 0; m < 24; ++m) {
                float rv = rqs[(w*6 + h)*196 + c0 + m];
                s0 += acc0[m]*rv; s1 += acc1[m]*rv; s2 += acc2[m]*rv; s3 += acc3[m]*rv;
            }
            #pragma unroll
            for (int off = 1; off < 8; off <<= 1) {
                s0 += __shfl_xor(s0, off, 8); s1 += __shfl_xor(s1, off, 8);
                s2 += __shfl_xor(s2, off, 8); s3 += __shfl_xor(s3, off, 8);
            }
            if (cg == 0) {
                float* dst = ws + WS_SC + (size_t)(nb + w)*192 + i*96 + h*16 + j0;
                dst[0] = s0; dst[1] = s1; dst[2] = s2; dst[3] = s3;
            }
        }
    }
}

// ---- K_score (unchanged) ----
__global__ __launch_bounds__(256) void k_score(
    const int* __restrict__ knn, float* __restrict__ ws)
{
    __shared__ float Kw[NS][196];
    __shared__ float Vw[NS][196];
    __shared__ float q0s[192];
    __shared__ float dqks[6][16];
    __shared__ float attns[6][16];
    __shared__ int idx[NS];
    const int n = blockIdx.x;
    const int t = threadIdx.x;
    if (t < NS) idx[t] = knn[n*NS + t];
    __syncthreads();
    for (int e = t; e < NS*48; e += 256) {
        int r = e/48, cq = e%48;
        *(float4*)&Kw[r][cq*4] = *(const float4*)(ws + WS_QKV + (size_t)idx[r]*576 + 192 + cq*4);
        *(float4*)&Vw[r][cq*4] = *(const float4*)(ws + WS_QKV + (size_t)idx[r]*576 + 384 + cq*4);
    }
    if (t < DD) q0s[t] = ws[WS_QKV + (size_t)idx[0]*576 + t];
    __syncthreads();
    {
        const int j = t >> 4, u = t & 15;
        #pragma unroll
        for (int h = 0; h < 6; ++h) {
            int c = h*32 + u*2;
            float v = q0s[c]*Kw[j][c] + q0s[c+1]*Kw[j][c+1];
            #pragma unroll
            for (int off = 1; off < 16; off <<= 1) v += __shfl_xor(v, off, 16);
            if (u == 0) dqks[h][j] = v;
        }
    }
    __syncthreads();
    if (t < 96) {
        const float scale = 0.17677669529663687f;  // 32^-0.5
        const int h = t >> 4, jj = t & 15;
        float z = (dqks[h][jj]
                 + ws[WS_SC + (size_t)n*192 + h*16 + jj]
                 + ws[WS_SC + (size_t)n*192 + 96 + h*16 + jj]) * scale;
        float mx = z;
        #pragma unroll
        for (int off = 1; off < 16; off <<= 1) mx = fmaxf(mx, __shfl_xor(mx, off, 16));
        float e = expf(z - mx);
        float sm = e;
        #pragma unroll
        for (int off = 1; off < 16; off <<= 1) sm += __shfl_xor(sm, off, 16);
        float a = e / sm;
        attns[h][jj] = a;
        ws[WS_ATTN + (size_t)n*96 + h*16 + jj] = a;
    }
    __syncthreads();
    if (t < DD) {
        const int h = t >> 5;
        float s = 0.f;
        #pragma unroll
        for (int jj = 0; jj < NS; ++jj) s += attns[h][jj] * Vw[jj][t];
        ws[WS_X1 + (size_t)n*DD + t] = s;
    }
}

// ---- K_pv v2 (writes bf16 CTRB) ----
__global__ __launch_bounds__(256) void k_pv(
    const float* __restrict__ posW1, const float* __restrict__ posB2,
    float* __restrict__ ws)
{
    __shared__ float Wbuf[48*196];
    __shared__ float wsum[8*6*196];
    __shared__ float attns[8][96];
    __shared__ float Xl[8][48];
    ushort_t* ctrb = (ushort_t*)(ws + WS_CTRB);
    const int t = threadIdx.x;
    const int nb = blockIdx.x * 8;
    for (int e = t; e < 384; e += 256) {
        int w = e/48, k = e%48;
        Xl[w][k] = ws[WS_KNN + (size_t)(nb+w)*48 + k];
    }
    for (int e = t; e < 768; e += 256) {
        int w = e/96, r = e%96;
        attns[w][r] = ws[WS_ATTN + (size_t)(nb+w)*96 + r];
    }
    for (int e = t; e < 2304; e += 256) {
        int kk = e/48, cq = e%48;
        *(float4*)&Wbuf[kk*196 + cq*4] = *(const float4*)(posW1 + (size_t)(96+kk)*DD + cq*4);
    }
    __syncthreads();
    {
        const int cg = t & 7, rg5 = (t >> 3) & 3, w = t >> 5;
        const int j0 = rg5*4, c0 = cg*24;
        float cx0[3], cx1[3], cx2[3], cx3[3];
        #pragma unroll
        for (int d = 0; d < 3; ++d) {
            cx0[d] = Xl[w][(j0+0)*3 + d];
            cx1[d] = Xl[w][(j0+1)*3 + d];
            cx2[d] = Xl[w][(j0+2)*3 + d];
            cx3[d] = Xl[w][(j0+3)*3 + d];
        }
        float acc0[24], acc1[24], acc2[24], acc3[24];
        #pragma unroll
        for (int m = 0; m < 24; ++m) { acc0[m]=0.f; acc1[m]=0.f; acc2[m]=0.f; acc3[m]=0.f; }
        for (int k3 = 0; k3 < 16; ++k3) {
            #pragma unroll
            for (int d = 0; d < 3; ++d) {
                int k = k3*3 + d;
                float xk = Xl[w][k];
                float av0 = xk - cx0[d], av1 = xk - cx1[d];
                float av2 = xk - cx2[d], av3 = xk - cx3[d];
                #pragma unroll
                for (int m = 0; m < 24; ++m) {
                    float wv = Wbuf[k*196 + c0 + m];
                    acc0[m] += av0*wv; acc1[m] += av1*wv;
                    acc2[m] += av2*wv; acc3[m] += av3*wv;
                }
            }
        }
        #pragma unroll
        for (int m = 0; m < 24; ++m) {
            int c = c0 + m;
            float as = ws[WS_AB + 2*DD + c];
            float bb = ws[WS_AB + 576 + 2*DD + c];
            acc0[m] = fmaxf(acc0[m]*as + bb, 0.f);
            acc1[m] = fmaxf(acc1[m]*as + bb, 0.f);
            acc2[m] = fmaxf(acc2[m]*as + bb, 0.f);
            acc3[m] = fmaxf(acc3[m]*as + bb, 0.f);
        }
        #pragma unroll
        for (int h = 0; h < 6; ++h) {
            float a0 = attns[w][h*16 + j0 + 0];
            float a1 = attns[w][h*16 + j0 + 1];
            float a2 = attns[w][h*16 + j0 + 2];
            float a3 = attns[w][h*16 + j0 + 3];
            #pragma unroll
            for (int m = 0; m < 24; ++m) {
                float pm = a0*acc0[m] + a1*acc1[m] + a2*acc2[m] + a3*acc3[m];
                pm += __shfl_xor(pm, 8, 32);
                pm += __shfl_xor(pm, 16, 32);
                if (rg5 == 0) wsum[(w*6 + h)*196 + c0 + m] = pm;
            }
        }
    }
    __syncthreads();
    if (t < DD) {
        const int h = t >> 5;
        float pvacc[8];
        #pragma unroll
        for (int w = 0; w < 8; ++w) pvacc[w] = 0.f;
        const float* wrow = ws + WS_W2T + (size_t)t*DD;
        for (int k4 = 0; k4 < 48; ++k4) {
            float4 wv = *(const float4*)(wrow + k4*4);
            #pragma unroll
            for (int w = 0; w < 8; ++w) {
                float4 av = *(const float4*)&wsum[(w*6 + h)*196 + k4*4];
                pvacc[w] += av.x*wv.x + av.y*wv.y + av.z*wv.z + av.w*wv.w;
            }
        }
        float b2 = posB2[2*DD + t];
        #pragma unroll
        for (int w = 0; w < 8; ++w) {
            ctrb[(size_t)(nb+w)*DD + t] =
                f2bf(ws[WS_X1 + (size_t)(nb+w)*DD + t] + pvacc[w] + b2);
        }
    }
}

extern "C" void kernel_launch(void* const* d_in, const int* in_sizes, int n_in,
                              void* d_out, int out_size, void* d_ws, size_t ws_size,
                              hipStream_t stream)
{
    const float* p     = (const float*)d_in[0];
    const float* x     = (const float*)d_in[1];
    const int*   knn   = (const int*)  d_in[2];
    const float* Wqkv  = (const float*)d_in[3];
    const float* Wproj = (const float*)d_in[4];
    const float* bproj = (const float*)d_in[5];
    const float* propW = (const float*)d_in[6];
    const float* propB = (const float*)d_in[7];
    const float* gAW   = (const float*)d_in[8];
    const float* gAb   = (const float*)d_in[9];
    const float* gBW   = (const float*)d_in[10];
    const float* gBb   = (const float*)d_in[11];
    const float* gCW   = (const float*)d_in[12];
    const float* gCb   = (const float*)d_in[13];
    const float* posW1 = (const float*)d_in[14];
    const float* posB1 = (const float*)d_in[15];
    const float* gamma = (const float*)d_in[16];
    const float* beta  = (const float*)d_in[17];
    const float* posW2 = (const float*)d_in[18];
    const float* posB2 = (const float*)d_in[19];
    const float* kn    = (const float*)d_in[20];
    const float* deW1  = (const float*)d_in[21];
    const float* deB1  = (const float*)d_in[22];
    const float* deW2  = (const float*)d_in[23];
    const float* deB2  = (const float*)d_in[24];
    const float* kpW   = (const float*)d_in[25];
    const float* kpB   = (const float*)d_in[26];
    const float* fusW  = (const float*)d_in[27];
    const float* fusB  = (const float*)d_in[28];
    float* ws   = (float*)d_ws;
    float* outp = (float*)d_out;

    hipLaunchKernelGGL(k_init, dim3(10), dim3(256), 0, stream, ws);
    hipLaunchKernelGGL(k_w2t, dim3(144), dim3(256), 0, stream, posW2, ws);
    hipLaunchKernelGGL(k_prep, dim3(864), dim3(256), 0, stream, propW, Wqkv, fusW, Wproj, ws);
    hipLaunchKernelGGL(k_castx, dim3(NP*DD/256), dim3(256), 0, stream, x, ws);
    hipLaunchKernelGGL(k1_glue, dim3(NP/16), dim3(256), 0, stream, p, knn, ws);
    hipLaunchKernelGGL(k2_fold, dim3(3), dim3(256), 0, stream,
                       posW1, posB1, gamma, beta, gCW, gCb, ws);
    hipLaunchKernelGGL(k_prop_mfma, dim3(MTOT/64), dim3(256), 0, stream,
                       x, knn, propW, propB, ws);
    hipLaunchKernelGGL(k3a, dim3(NP/16), dim3(256), 0, stream,
                       p, kn, deW1, deB1, deW2, deB2, kpW, kpB, gAW, gAb, gBW, gBb, ws);
    // X2B = bf16(UB @ fusW + fusB)
    hipLaunchKernelGGL(gemm_mfma, dim3(NP/64, 3), dim3(256), 0, stream,
                       (const ushort_t*)(ws + WS_UB), (const ushort_t*)(ws + WS_FUSWT),
                       fusB, (float*)nullptr, (ushort_t*)(ws + WS_X2B), DD);
    // QKV = X2B @ Wqkv (fp32 out)
    hipLaunchKernelGGL(gemm_mfma, dim3(NP/64, 9), dim3(256), 0, stream,
                       (const ushort_t*)(ws + WS_X2B), (const ushort_t*)(ws + WS_QKVT),
                       (const float*)nullptr, ws + WS_QKV, (ushort_t*)nullptr, 576);
    hipLaunchKernelGGL(k_dqdk, dim3(NP/4), dim3(256), 0, stream, knn, posW1, posW2, ws);
    hipLaunchKernelGGL(k_score, dim3(NP), dim3(256), 0, stream, knn, ws);
    hipLaunchKernelGGL(k_pv, dim3(NP/8), dim3(256), 0, stream, posW1, posB2, ws);
    // OUT = CTRB @ Wproj + bproj (fp32 out)
    hipLaunchKernelGGL(gemm_mfma, dim3(NP/64, 3), dim3(256), 0, stream,
                       (const ushort_t*)(ws + WS_CTRB), (const ushort_t*)(ws + WS_PROJWT),
                       bproj, outp, (ushort_t*)nullptr, DD);
}

// Round 7
// 972.684 us; speedup vs baseline: 8.6367x; 1.1493x over previous
//
#include <hip/hip_runtime.h>
#include <math.h>

#define NP 16384
#define DD 192
#define NS 16
#define KSPN 16
#define MTOT (NP*NS)

typedef unsigned short ushort_t;
typedef __attribute__((ext_vector_type(8))) short short8;
typedef __attribute__((ext_vector_type(4))) float f32x4;

__device__ __forceinline__ ushort_t f2bf(float f) {
    union { float f; unsigned int u; } v; v.f = f;
    return (ushort_t)((v.u + 0x7FFFu + ((v.u >> 16) & 1u)) >> 16);
}

// ws float offsets
#define WS_KNN   0                         // NP*48   knn_xyz
#define WS_PR    (WS_KNN + NP*48)          // MTOT*3  p_r per window row
#define WS_GEO9  (WS_PR + MTOT*3)          // NP*9
#define WS_GDIS  (WS_GEO9 + NP*9)          // NP
#define WS_STATS (WS_GDIS + NP)            // [0]=dsum [1]=dmax(bits) [2..50)=possum [50..2354)=M2
#define WS_VOLV  (WS_STATS + 2354)         // 192
#define WS_AB    (WS_VOLV + DD)            // a[3][192] | bb[3][192] = 1152
#define WS_X1    (WS_AB + 1152)            // NP*192 post-propagate; later CTR1 (attn@v)
#define WS_U     (WS_X1 + NP*DD)           // NP*192: CTRB (bf16) after k_pv
#define WS_X2    (WS_U + NP*DD)            // NP*192: X2B (bf16, written by fus gemm)
#define WS_QKV   (WS_X2 + NP*DD)           // NP*576
#define WS_SC    (WS_QKV + NP*576)         // NP*192  SC[n][i(2)][h(6)][j(16)]; early: XB overlay
#define WS_ATTN  (WS_SC + NP*DD)           // NP*96   attn; early: UB (bf16) overlay
#define WS_W2T   (WS_ATTN + NP*96)         // 192*192 transposed posW2[2] fp32
#define WS_PROPWT (WS_W2T + 36864)         // 192*192 bf16 = 18432 floats (transposed propW[:192])
#define WS_QKVT  (WS_PROPWT + 18432)       // 576*192 bf16 = 55296 floats
#define WS_FUSWT (WS_QKVT + 55296)         // 18432
#define WS_PROJWT (WS_FUSWT + 18432)       // 18432
#define WS_W1T   (WS_PROJWT + 18432)       // 3*192*64 bf16 = 18432 floats (posW1 transposed, K pad 64)
// overlays (bf16 arrays in dead-interval regions):
#define WS_XB    WS_SC                     // NP*192 bf16 (dead before k_dqdk writes SC)
#define WS_UB    WS_ATTN                   // NP*192 bf16 (dead before k_score writes ATTN)
#define WS_X2B   WS_X2
#define WS_CTRB  WS_U
// total ~25.5M floats ~102 MB

__global__ __launch_bounds__(256) void k_init(float* __restrict__ ws) {
    int t = blockIdx.x * 256 + threadIdx.x;
    if (t < 2354) ws[WS_STATS + t] = 0.f;
}

// ---- tiny: W2T[c][kk] = posW2[2][kk][c] (fp32, for k_pv) ----
__global__ __launch_bounds__(256) void k_w2t(const float* __restrict__ posW2,
                                             float* __restrict__ ws) {
    int e = blockIdx.x*256 + threadIdx.x;      // e = c*192 + kk
    int c = e / DD, kk = e - c*DD;
    ws[WS_W2T + e] = posW2[(size_t)(2*DD + kk)*DD + c];
}

// ---- prep: bf16 transposed weight copies (n-major, k-contiguous) ----
__global__ __launch_bounds__(256) void k_prep(
    const float* __restrict__ propW, const float* __restrict__ Wqkv,
    const float* __restrict__ fusW, const float* __restrict__ Wproj,
    const float* __restrict__ posW1,
    float* __restrict__ ws)
{
    int e = blockIdx.x*256 + threadIdx.x;
    ushort_t* pwt = (ushort_t*)(ws + WS_PROPWT);
    ushort_t* qkt = (ushort_t*)(ws + WS_QKVT);
    ushort_t* fwt = (ushort_t*)(ws + WS_FUSWT);
    ushort_t* pjt = (ushort_t*)(ws + WS_PROJWT);
    ushort_t* w1t = (ushort_t*)(ws + WS_W1T);
    if (e < 36864) {
        int n = e/192, k = e - n*192;
        pwt[e] = f2bf(propW[(size_t)k*192 + n]);
    } else if (e < 147456) {
        int r = e - 36864; int n = r/192, k = r - n*192;
        qkt[r] = f2bf(Wqkv[(size_t)k*576 + n]);
    } else if (e < 184320) {
        int r = e - 147456; int n = r/192, k = r - n*192;
        fwt[r] = f2bf(fusW[(size_t)k*192 + n]);
    } else if (e < 221184) {
        int r = e - 184320; int n = r/192, k = r - n*192;
        pjt[r] = f2bf(Wproj[(size_t)k*192 + n]);
    } else if (e < 258048) {
        int r = e - 221184;
        int i = r / 12288, rem = r - i*12288;
        int n = rem / 64, k = rem - n*64;
        w1t[r] = (k < 48) ? f2bf(posW1[(size_t)(i*48 + k)*DD + n]) : (ushort_t)0;
    }
}

// ---- cast x -> bf16 ----
__global__ __launch_bounds__(256) void k_castx(const float* __restrict__ x,
                                               float* __restrict__ ws) {
    int e = blockIdx.x*256 + threadIdx.x;
    ((ushort_t*)(ws + WS_XB))[e] = f2bf(x[e]);
}

// ---- K1: geometry glue + stats ----
__global__ __launch_bounds__(256) void k1_glue(
    const float* __restrict__ p, const int* __restrict__ knn,
    float* __restrict__ ws)
{
    __shared__ float Xl[48];
    __shared__ float pos[NS][49];
    __shared__ float distl[NS];
    __shared__ int idx[NS];
    __shared__ float pn[3];
    const int t = threadIdx.x;
    float m2acc[9];
    #pragma unroll
    for (int q = 0; q < 9; ++q) m2acc[q] = 0.f;
    float psacc = 0.f, dsum_loc = 0.f, dmax_loc = 0.f;

    for (int it = 0; it < 16; ++it) {
        const int n = blockIdx.x * 16 + it;
        __syncthreads();
        if (t < NS) idx[t] = knn[n*NS + t];
        if (t < 3)  pn[t] = p[n*3 + t];
        __syncthreads();
        if (t < 48) { float v = p[idx[t/3]*3 + (t % 3)]; Xl[t] = v; ws[WS_KNN + n*48 + t] = v; }
        __syncthreads();
        if (t < 48) {
            int j = t/3, c = t % 3;
            ws[WS_PR + (n*NS + j)*3 + c] = Xl[t] - pn[c];
        }
        if (t < NS) {
            float dx = Xl[t*3]-pn[0], dy = Xl[t*3+1]-pn[1], dz = Xl[t*3+2]-pn[2];
            distl[t] = sqrtf(dx*dx + dy*dy + dz*dz + 1e-12f);
        }
        for (int e = t; e < NS*48; e += 256) {
            int r = e/48, k = e - r*48;
            pos[r][k] = Xl[k] - Xl[r*3 + (k % 3)];
        }
        __syncthreads();
        if (t == 0) {
            float dm = 0.f, ds = 0.f;
            for (int j = 0; j < NS; ++j) { dm = fmaxf(dm, distl[j]); ds += distl[j]; }
            ws[WS_GDIS + n] = dm;
            dsum_loc += ds; dmax_loc = fmaxf(dmax_loc, dm);
        }
        if (t < 3) {
            float mx = 0.f;
            for (int j = 0; j < NS; ++j) mx += Xl[j*3 + t];
            mx *= (1.f/16.f);
            ws[WS_GEO9 + n*9 + t]     = mx - pn[t];
            ws[WS_GEO9 + n*9 + 3 + t] = mx;
            ws[WS_GEO9 + n*9 + 6 + t] = pn[t];
        }
        {
            int e = t;
            #pragma unroll
            for (int q = 0; q < 9; ++q) {
                int a = e / 48, b = e - a*48;
                float s = 0.f;
                for (int j = 0; j < NS; ++j) s += pos[j][a] * pos[j][b];
                m2acc[q] += s;
                e += 256;
            }
        }
        if (t < 48) { float s = 0.f; for (int j = 0; j < NS; ++j) s += pos[j][t]; psacc += s; }
    }
    {
        int e = t;
        #pragma unroll
        for (int q = 0; q < 9; ++q) { atomicAdd(&ws[WS_STATS + 50 + e], m2acc[q]); e += 256; }
    }
    if (t < 48) atomicAdd(&ws[WS_STATS + 2 + t], psacc);
    if (t == 0) {
        atomicAdd(&ws[WS_STATS + 0], dsum_loc);
        atomicMax((int*)(ws + WS_STATS + 1), __float_as_int(dmax_loc));  // dist>=0
    }
}

// ---- K2: vol vector + BN fold (var via M2) -> a/bb ----
__global__ __launch_bounds__(256) void k2_fold(
    const float* __restrict__ posW1, const float* __restrict__ posB1,
    const float* __restrict__ gamma, const float* __restrict__ beta,
    const float* __restrict__ gCW, const float* __restrict__ gCb,
    float* __restrict__ ws)
{
    __shared__ float M2n[48][48];
    __shared__ float pmean[48];
    __shared__ float Wc[48][193];
    const int t = threadIdx.x;
    const int i = blockIdx.x;
    for (int e = t; e < 2304; e += 256) ((float*)M2n)[e] = ws[WS_STATS + 50 + e] * (1.f/(float)MTOT);
    if (t < 48) pmean[t] = ws[WS_STATS + 2 + t] * (1.f/(float)MTOT);
    if (t < DD) {
        for (int k = 0; k < 48; ++k) Wc[k][t] = posW1[(size_t)(i*48 + k)*DD + t];
    }
    __syncthreads();
    if (i == 0 && t < DD) {
        float dsum = ws[WS_STATS + 0];
        float dmax = __int_as_float(((const int*)(ws + WS_STATS))[1]);
        float vol = (dsum * (1.f/(float)MTOT)) / (dmax + 1e-8f);
        ws[WS_VOLV + t] = vol * gCW[t] + gCb[t];
    }
    if (t < DD) {
        float mu0 = 0.f;
        #pragma unroll 8
        for (int k = 0; k < 48; ++k) mu0 += pmean[k] * Wc[k][t];
        float e2 = 0.f;
        for (int a2 = 0; a2 < 48; ++a2) {
            float inner = 0.f;
            #pragma unroll 8
            for (int b2 = 0; b2 < 48; ++b2) inner += M2n[a2][b2] * Wc[b2][t];
            e2 += Wc[a2][t] * inner;
        }
        float var = fmaxf(e2 - mu0*mu0, 0.f);
        float as = rsqrtf(var + 1e-5f) * gamma[i*DD + t];
        ws[WS_AB + i*DD + t]       = as;
        ws[WS_AB + 576 + i*DD + t] = beta[i*DD + t] - mu0 * as;   // h'=relu(acc*as+bb)
    }
}

// ---- K_prop MFMA: gathered bf16 GEMM + fp32 p_r tail + relu + window mean ----
__global__ __launch_bounds__(256) void k_prop_mfma(
    const float* __restrict__ x, const int* __restrict__ knn,
    const float* __restrict__ propW, const float* __restrict__ propB,
    float* __restrict__ ws)
{
    __shared__ ushort_t As[64*40];     // A tile, stride 40 bf16 (80 B)
    __shared__ ushort_t Bs[192*40];    // Bt tile
    __shared__ float prs[64*3];
    __shared__ float W3[3*192];
    __shared__ int idx64[64];
    const int t = threadIdx.x;
    const int mbase = blockIdx.x * 64;
    const ushort_t* xb = (const ushort_t*)(ws + WS_XB);
    const ushort_t* pwt = (const ushort_t*)(ws + WS_PROPWT);
    if (t < 64) idx64[t] = knn[mbase + t];
    for (int e = t; e < 576; e += 256) W3[e] = propW[(size_t)(192 + e/192)*DD + (e % 192)];
    for (int e = t; e < 192; e += 256) prs[e] = ws[WS_PR + (size_t)mbase*3 + e];
    const int wave = t >> 6, lane = t & 63, m = lane & 15, quad = lane >> 4;
    f32x4 acc[12];
    #pragma unroll
    for (int nt = 0; nt < 12; ++nt) acc[nt] = (f32x4){0.f,0.f,0.f,0.f};
    for (int ks = 0; ks < 6; ++ks) {
        const int k0 = ks*32;
        __syncthreads();
        {   int r = t >> 2, seg = t & 3;
            *(uint4*)&As[r*40 + seg*8] = *(const uint4*)(xb + (size_t)idx64[r]*192 + k0 + seg*8);
        }
        for (int e = t; e < 768; e += 256) {
            int n = e >> 2, seg = e & 3;
            *(uint4*)&Bs[n*40 + seg*8] = *(const uint4*)(pwt + (size_t)n*192 + k0 + seg*8);
        }
        __syncthreads();
        short8 a = *(const short8*)&As[(wave*16 + m)*40 + quad*8];
        #pragma unroll
        for (int nt = 0; nt < 12; ++nt) {
            short8 b = *(const short8*)&Bs[(nt*16 + m)*40 + quad*8];
            acc[nt] = __builtin_amdgcn_mfma_f32_16x16x32_bf16(a, b, acc[nt], 0, 0, 0);
        }
    }
    const int n = blockIdx.x*4 + wave;   // global point
    #pragma unroll
    for (int nt = 0; nt < 12; ++nt) {
        int col = nt*16 + m;
        float bv = propB[col];
        float w0 = W3[col], w1 = W3[192 + col], w2 = W3[384 + col];
        float s = 0.f;
        #pragma unroll
        for (int reg = 0; reg < 4; ++reg) {
            int j = wave*16 + quad*4 + reg;
            float v = acc[nt][reg] + prs[j*3+0]*w0 + prs[j*3+1]*w1 + prs[j*3+2]*w2 + bv;
            s += fmaxf(v, 0.f);
        }
        s += __shfl_xor(s, 16);
        s += __shfl_xor(s, 32);
        if (quad == 0)
            ws[WS_X1 + (size_t)n*DD + col] = x[(size_t)n*DD + col] + s * (1.f/16.f);
    }
}

// ---- generic bf16 MFMA GEMM: C[M x N] = A[M x 192] @ Bt^T (+bias) ----
__global__ __launch_bounds__(256) void gemm_mfma(
    const ushort_t* __restrict__ A, const ushort_t* __restrict__ Bt,
    const float* __restrict__ bias, float* __restrict__ Cf,
    ushort_t* __restrict__ Cb, int N)
{
    __shared__ ushort_t As[64*40];
    __shared__ ushort_t Bs[64*40];
    const int t = threadIdx.x;
    const int wave = t >> 6, lane = t & 63, m = lane & 15, quad = lane >> 4;
    const int rowBase = blockIdx.x * 64, colBase = blockIdx.y * 64;
    f32x4 acc[4];
    #pragma unroll
    for (int nt = 0; nt < 4; ++nt) acc[nt] = (f32x4){0.f,0.f,0.f,0.f};
    for (int ks = 0; ks < 6; ++ks) {
        __syncthreads();
        {   int r = t >> 2, seg = t & 3;
            *(uint4*)&As[r*40 + seg*8] = *(const uint4*)(A + (size_t)(rowBase + r)*192 + ks*32 + seg*8);
            *(uint4*)&Bs[r*40 + seg*8] = *(const uint4*)(Bt + (size_t)(colBase + r)*192 + ks*32 + seg*8);
        }
        __syncthreads();
        short8 a = *(const short8*)&As[(wave*16 + m)*40 + quad*8];
        #pragma unroll
        for (int nt = 0; nt < 4; ++nt) {
            short8 b = *(const short8*)&Bs[(nt*16 + m)*40 + quad*8];
            acc[nt] = __builtin_amdgcn_mfma_f32_16x16x32_bf16(a, b, acc[nt], 0, 0, 0);
        }
    }
    #pragma unroll
    for (int nt = 0; nt < 4; ++nt) {
        int col = colBase + nt*16 + m;
        float bv = bias ? bias[col] : 0.f;
        #pragma unroll
        for (int reg = 0; reg < 4; ++reg) {
            int row = rowBase + wave*16 + quad*4 + reg;
            float v = acc[nt][reg] + bv;
            if (Cf) Cf[(size_t)row*N + col] = v;
            else    Cb[(size_t)row*N + col] = f2bf(v);
        }
    }
}

// ---- K3a: keypoint attention + U assembly (writes bf16 UB) ----
__global__ __launch_bounds__(256) void k3a(
    const float* __restrict__ p, const float* __restrict__ kn,
    const float* __restrict__ deW1, const float* __restrict__ deB1,
    const float* __restrict__ deW2, const float* __restrict__ deB2,
    const float* __restrict__ kpW, const float* __restrict__ kpB,
    const float* __restrict__ gAW, const float* __restrict__ gAb,
    const float* __restrict__ gBW, const float* __restrict__ gBb,
    float* __restrict__ ws)
{
    __shared__ float Wd[48][196];
    __shared__ float innr[KSPN][49];
    __shared__ float df[KSPN][193];
    __shared__ float kd[KSPN];
    __shared__ float scl[KSPN];
    ushort_t* ub = (ushort_t*)(ws + WS_UB);
    const int t = threadIdx.x;
    for (int e = t; e < 48*48; e += 256) {
        int w = e / 48, cq = e - w*48;
        *(float4*)&Wd[w][cq*4] = *(const float4*)(deW2 + (size_t)w*DD + cq*4);
    }
    const int kap = t >> 4, u = t & 15, c0 = u*12;
    for (int it = 0; it < 16; ++it) {
        const int n = blockIdx.x*16 + it;
        __syncthreads();
        if (t < KSPN) {
            float dx = p[n*3]-kn[t*3], dy = p[n*3+1]-kn[t*3+1], dz = p[n*3+2]-kn[t*3+2];
            kd[t] = sqrtf(dx*dx + dy*dy + dz*dz + 1e-12f);
        }
        __syncthreads();
        for (int e = t; e < KSPN*48; e += 256) {
            int r = e / 48, j = e - r*48;
            innr[r][j] = fmaxf(kd[r]*deW1[j] + deB1[j], 0.f);
        }
        __syncthreads();
        float a12[12];
        #pragma unroll
        for (int m = 0; m < 12; ++m) a12[m] = deB2[c0 + m];
        for (int w = 0; w < 48; ++w) {
            float av = innr[kap][w];
            #pragma unroll
            for (int m = 0; m < 12; ++m) a12[m] += av * Wd[w][c0 + m];
        }
        float ksc = 0.f;
        #pragma unroll
        for (int m = 0; m < 12; ++m) { df[kap][c0 + m] = a12[m]; ksc += a12[m]*kpW[c0 + m]; }
        #pragma unroll
        for (int off = 1; off < 16; off <<= 1) ksc += __shfl_xor(ksc, off, 16);
        if (u == 0) scl[kap] = ksc + kpB[0];
        __syncthreads();
        if (t < KSPN) {
            float v = scl[t], mx = v;
            #pragma unroll
            for (int off = 1; off < 16; off <<= 1) mx = fmaxf(mx, __shfl_xor(mx, off, 16));
            float e = expf(v - mx);
            float sm = e;
            #pragma unroll
            for (int off = 1; off < 16; off <<= 1) sm += __shfl_xor(sm, off, 16);
            scl[t] = e / sm;
        }
        __syncthreads();
        if (t < DD) {
            float dfeat = 0.f;
            #pragma unroll
            for (int k2 = 0; k2 < KSPN; ++k2) dfeat += scl[k2]*df[k2][t];
            float uval = ws[WS_X1 + (size_t)n*DD + t] + gAb[t] + gBb[t] + ws[WS_VOLV + t] + dfeat;
            uval += ws[WS_GDIS + n] * gBW[t];
            #pragma unroll
            for (int kk = 0; kk < 9; ++kk) uval += ws[WS_GEO9 + n*9 + kk] * gAW[kk*DD + t];
            ub[(size_t)n*DD + t] = f2bf(uval);
        }
    }
}

// ---- K_dqdk v4: 8 windows/block, both i. MFMA H-phase (pos bf16 tile x W1T
//      global B-frags) with fused rqs contraction; rq phase on VALU. ----
__global__ __launch_bounds__(256) void k_dqdk(
    const int* __restrict__ knn,
    const float* __restrict__ posW2,
    float* __restrict__ ws)
{
    __shared__ ushort_t posb[128*72];   // bf16 pos rows, K padded to 64, stride 72
    __shared__ float qk[8*192];         // q0 (i=0) / k0 (i=1)
    __shared__ float rqs[8*6*192];      // [w][h][kk]
    __shared__ float Xl[8][48];
    __shared__ int idx0[8];
    const int t = threadIdx.x;
    const int nb = blockIdx.x * 8;
    if (t < 8) idx0[t] = knn[(nb + t)*NS];
    for (int e = t; e < 384; e += 256) {
        int w = e / 48, k = e % 48;
        Xl[w][k] = ws[WS_KNN + (size_t)(nb + w)*48 + k];
    }
    __syncthreads();
    for (int e = t; e < 128*64; e += 256) {   // build bf16 pos tile
        int j = e >> 6, k = e & 63;
        int w = j >> 4, jl = j & 15;
        float v = (k < 48) ? (Xl[w][k] - Xl[w][jl*3 + (k % 3)]) : 0.f;
        posb[j*72 + k] = f2bf(v);
    }
    const int wave = t >> 6, lane = t & 63, m = lane & 15, quad = lane >> 4;
    const ushort_t* w1t = (const ushort_t*)(ws + WS_W1T);
    for (int i = 0; i < 2; ++i) {
        __syncthreads();      // prior-i consumers of qk/rqs done; posb built (i=0)
        for (int e = t; e < 8*192; e += 256) {
            int w = e / 192, c = e % 192;
            qk[w*192 + c] = ws[WS_QKV + (size_t)idx0[w]*576 + i*192 + c];
        }
        __syncthreads();
        if (t < 192) {        // rq: W2 row t (global) x qk broadcast
            const float* Wrow = posW2 + (size_t)i*DD*DD + (size_t)t*DD;
            for (int h = 0; h < 6; ++h) {
                float4 wr[8];
                #pragma unroll
                for (int q = 0; q < 8; ++q) wr[q] = *(const float4*)(Wrow + h*32 + q*4);
                float a[8];
                #pragma unroll
                for (int w = 0; w < 8; ++w) a[w] = 0.f;
                #pragma unroll
                for (int q = 0; q < 8; ++q) {
                    #pragma unroll
                    for (int d = 0; d < 4; ++d) {
                        float wv = (&wr[q].x)[d];
                        int c = h*32 + q*4 + d;
                        #pragma unroll
                        for (int w = 0; w < 8; ++w) a[w] += wv * qk[w*192 + c];
                    }
                }
                #pragma unroll
                for (int w = 0; w < 8; ++w) rqs[(w*6 + h)*192 + t] = a[w];
            }
        }
        __syncthreads();
        // MFMA H + fused contraction. Wave handles windows 2*wave, 2*wave+1.
        short8 afr[2][2];
        #pragma unroll
        for (int mt = 0; mt < 2; ++mt)
            #pragma unroll
            for (int ks = 0; ks < 2; ++ks)
                afr[mt][ks] = *(const short8*)&posb[((wave*2 + mt)*16 + m)*72 + ks*32 + quad*8];
        float s[48];          // [mt(2)][reg(4)][h(6)]
        #pragma unroll
        for (int e = 0; e < 48; ++e) s[e] = 0.f;
        for (int nt = 0; nt < 12; ++nt) {
            f32x4 acc0 = (f32x4){0.f,0.f,0.f,0.f};
            f32x4 acc1 = (f32x4){0.f,0.f,0.f,0.f};
            #pragma unroll
            for (int ks = 0; ks < 2; ++ks) {
                short8 b = *(const short8*)(w1t + ((size_t)(i*192 + nt*16 + m)*64 + ks*32 + quad*8));
                acc0 = __builtin_amdgcn_mfma_f32_16x16x32_bf16(afr[0][ks], b, acc0, 0, 0, 0);
                acc1 = __builtin_amdgcn_mfma_f32_16x16x32_bf16(afr[1][ks], b, acc1, 0, 0, 0);
            }
            int kk = nt*16 + m;
            float as = ws[WS_AB + i*DD + kk];
            float bb = ws[WS_AB + 576 + i*DD + kk];
            float h0[4], h1[4];
            #pragma unroll
            for (int reg = 0; reg < 4; ++reg) {
                h0[reg] = fmaxf(acc0[reg]*as + bb, 0.f);
                h1[reg] = fmaxf(acc1[reg]*as + bb, 0.f);
            }
            #pragma unroll
            for (int h = 0; h < 6; ++h) {
                float r0 = rqs[((wave*2 + 0)*6 + h)*192 + kk];
                float r1 = rqs[((wave*2 + 1)*6 + h)*192 + kk];
                #pragma unroll
                for (int reg = 0; reg < 4; ++reg) {
                    s[reg*6 + h]      += h0[reg]*r0;
                    s[24 + reg*6 + h] += h1[reg]*r1;
                }
            }
        }
        #pragma unroll
        for (int e = 0; e < 48; ++e) {   // reduce over m lanes (width 16)
            float v = s[e];
            v += __shfl_xor(v, 1, 16); v += __shfl_xor(v, 2, 16);
            v += __shfl_xor(v, 4, 16); v += __shfl_xor(v, 8, 16);
            s[e] = v;
        }
        if (m == 0) {
            #pragma unroll
            for (int mt = 0; mt < 2; ++mt)
                #pragma unroll
                for (int reg = 0; reg < 4; ++reg) {
                    int w = wave*2 + mt, j = quad*4 + reg;
                    #pragma unroll
                    for (int h = 0; h < 6; ++h)
                        ws[WS_SC + (size_t)(nb + w)*192 + i*96 + h*16 + j] = s[mt*24 + reg*6 + h];
                }
        }
    }
}

// ---- K_score: q0.k_j dots + softmax + CTR1 = attn@v; stores attn ----
__global__ __launch_bounds__(256) void k_score(
    const int* __restrict__ knn, float* __restrict__ ws)
{
    __shared__ float Kw[NS][196];
    __shared__ float Vw[NS][196];
    __shared__ float q0s[192];
    __shared__ float dqks[6][16];
    __shared__ float attns[6][16];
    __shared__ int idx[NS];
    const int n = blockIdx.x;
    const int t = threadIdx.x;
    if (t < NS) idx[t] = knn[n*NS + t];
    __syncthreads();
    for (int e = t; e < NS*48; e += 256) {
        int r = e/48, cq = e%48;
        *(float4*)&Kw[r][cq*4] = *(const float4*)(ws + WS_QKV + (size_t)idx[r]*576 + 192 + cq*4);
        *(float4*)&Vw[r][cq*4] = *(const float4*)(ws + WS_QKV + (size_t)idx[r]*576 + 384 + cq*4);
    }
    if (t < DD) q0s[t] = ws[WS_QKV + (size_t)idx[0]*576 + t];
    __syncthreads();
    {
        const int j = t >> 4, u = t & 15;
        #pragma unroll
        for (int h = 0; h < 6; ++h) {
            int c = h*32 + u*2;
            float v = q0s[c]*Kw[j][c] + q0s[c+1]*Kw[j][c+1];
            #pragma unroll
            for (int off = 1; off < 16; off <<= 1) v += __shfl_xor(v, off, 16);
            if (u == 0) dqks[h][j] = v;
        }
    }
    __syncthreads();
    if (t < 96) {
        const float scale = 0.17677669529663687f;  // 32^-0.5
        const int h = t >> 4, jj = t & 15;
        float z = (dqks[h][jj]
                 + ws[WS_SC + (size_t)n*192 + h*16 + jj]
                 + ws[WS_SC + (size_t)n*192 + 96 + h*16 + jj]) * scale;
        float mx = z;
        #pragma unroll
        for (int off = 1; off < 16; off <<= 1) mx = fmaxf(mx, __shfl_xor(mx, off, 16));
        float e = expf(z - mx);
        float sm = e;
        #pragma unroll
        for (int off = 1; off < 16; off <<= 1) sm += __shfl_xor(sm, off, 16);
        float a = e / sm;
        attns[h][jj] = a;
        ws[WS_ATTN + (size_t)n*96 + h*16 + jj] = a;
    }
    __syncthreads();
    if (t < DD) {
        const int h = t >> 5;
        float s = 0.f;
        #pragma unroll
        for (int jj = 0; jj < NS; ++jj) s += attns[h][jj] * Vw[jj][t];
        ws[WS_X1 + (size_t)n*DD + t] = s;
    }
}

// ---- K_pv v3: 8 windows/block. MFMA H2 (pos bf16 x W1T[2]) with fused
//      attn-weighted j-reduction -> wsum; pv via fp32 W2T rows. ----
__global__ __launch_bounds__(256) void k_pv(
    const float* __restrict__ posB2, float* __restrict__ ws)
{
    __shared__ ushort_t posb[128*72];
    __shared__ float wsum[8*6*192];
    __shared__ float attns[8][96];
    __shared__ float Xl[8][48];
    ushort_t* ctrb = (ushort_t*)(ws + WS_CTRB);
    const int t = threadIdx.x;
    const int nb = blockIdx.x * 8;
    for (int e = t; e < 384; e += 256) {
        int w = e/48, k = e%48;
        Xl[w][k] = ws[WS_KNN + (size_t)(nb+w)*48 + k];
    }
    for (int e = t; e < 768; e += 256) {
        int w = e/96, r = e%96;
        attns[w][r] = ws[WS_ATTN + (size_t)(nb+w)*96 + r];
    }
    __syncthreads();
    for (int e = t; e < 128*64; e += 256) {
        int j = e >> 6, k = e & 63;
        int w = j >> 4, jl = j & 15;
        float v = (k < 48) ? (Xl[w][k] - Xl[w][jl*3 + (k % 3)]) : 0.f;
        posb[j*72 + k] = f2bf(v);
    }
    __syncthreads();
    {
        const int wave = t >> 6, lane = t & 63, m = lane & 15, quad = lane >> 4;
        const ushort_t* w1t = (const ushort_t*)(ws + WS_W1T);
        const int w0 = wave*2, w1 = wave*2 + 1;
        short8 afr[2][2];
        #pragma unroll
        for (int mt = 0; mt < 2; ++mt)
            #pragma unroll
            for (int ks = 0; ks < 2; ++ks)
                afr[mt][ks] = *(const short8*)&posb[((wave*2 + mt)*16 + m)*72 + ks*32 + quad*8];
        for (int nt = 0; nt < 12; ++nt) {
            f32x4 acc0 = (f32x4){0.f,0.f,0.f,0.f};
            f32x4 acc1 = (f32x4){0.f,0.f,0.f,0.f};
            #pragma unroll
            for (int ks = 0; ks < 2; ++ks) {
                short8 b = *(const short8*)(w1t + ((size_t)(2*192 + nt*16 + m)*64 + ks*32 + quad*8));
                acc0 = __builtin_amdgcn_mfma_f32_16x16x32_bf16(afr[0][ks], b, acc0, 0, 0, 0);
                acc1 = __builtin_amdgcn_mfma_f32_16x16x32_bf16(afr[1][ks], b, acc1, 0, 0, 0);
            }
            int kk = nt*16 + m;
            float as = ws[WS_AB + 2*DD + kk];
            float bb = ws[WS_AB + 576 + 2*DD + kk];
            float h0[4], h1[4];
            #pragma unroll
            for (int reg = 0; reg < 4; ++reg) {
                h0[reg] = fmaxf(acc0[reg]*as + bb, 0.f);
                h1[reg] = fmaxf(acc1[reg]*as + bb, 0.f);
            }
            #pragma unroll
            for (int h = 0; h < 6; ++h) {
                float p0 = 0.f, p1 = 0.f;
                #pragma unroll
                for (int reg = 0; reg < 4; ++reg) {
                    int j = quad*4 + reg;
                    p0 += attns[w0][h*16 + j] * h0[reg];
                    p1 += attns[w1][h*16 + j] * h1[reg];
                }
                p0 += __shfl_xor(p0, 16); p0 += __shfl_xor(p0, 32);
                p1 += __shfl_xor(p1, 16); p1 += __shfl_xor(p1, 32);
                if (quad == 0) {
                    wsum[(w0*6 + h)*192 + kk] = p0;
                    wsum[(w1*6 + h)*192 + kk] = p1;
                }
            }
        }
    }
    __syncthreads();
    if (t < DD) {
        const int h = t >> 5;
        float pvacc[8];
        #pragma unroll
        for (int w = 0; w < 8; ++w) pvacc[w] = 0.f;
        const float* wrow = ws + WS_W2T + (size_t)t*DD;
        for (int k4 = 0; k4 < 48; ++k4) {
            float4 wv = *(const float4*)(wrow + k4*4);
            #pragma unroll
            for (int w = 0; w < 8; ++w) {
                float4 av = *(const float4*)&wsum[(w*6 + h)*192 + k4*4];
                pvacc[w] += av.x*wv.x + av.y*wv.y + av.z*wv.z + av.w*wv.w;
            }
        }
        float b2 = posB2[2*DD + t];
        #pragma unroll
        for (int w = 0; w < 8; ++w) {
            ctrb[(size_t)(nb+w)*DD + t] =
                f2bf(ws[WS_X1 + (size_t)(nb+w)*DD + t] + pvacc[w] + b2);
        }
    }
}

extern "C" void kernel_launch(void* const* d_in, const int* in_sizes, int n_in,
                              void* d_out, int out_size, void* d_ws, size_t ws_size,
                              hipStream_t stream)
{
    const float* p     = (const float*)d_in[0];
    const float* x     = (const float*)d_in[1];
    const int*   knn   = (const int*)  d_in[2];
    const float* Wqkv  = (const float*)d_in[3];
    const float* Wproj = (const float*)d_in[4];
    const float* bproj = (const float*)d_in[5];
    const float* propW = (const float*)d_in[6];
    const float* propB = (const float*)d_in[7];
    const float* gAW   = (const float*)d_in[8];
    const float* gAb   = (const float*)d_in[9];
    const float* gBW   = (const float*)d_in[10];
    const float* gBb   = (const float*)d_in[11];
    const float* gCW   = (const float*)d_in[12];
    const float* gCb   = (const float*)d_in[13];
    const float* posW1 = (const float*)d_in[14];
    const float* posB1 = (const float*)d_in[15];
    const float* gamma = (const float*)d_in[16];
    const float* beta  = (const float*)d_in[17];
    const float* posW2 = (const float*)d_in[18];
    const float* posB2 = (const float*)d_in[19];
    const float* kn    = (const float*)d_in[20];
    const float* deW1  = (const float*)d_in[21];
    const float* deB1  = (const float*)d_in[22];
    const float* deW2  = (const float*)d_in[23];
    const float* deB2  = (const float*)d_in[24];
    const float* kpW   = (const float*)d_in[25];
    const float* kpB   = (const float*)d_in[26];
    const float* fusW  = (const float*)d_in[27];
    const float* fusB  = (const float*)d_in[28];
    float* ws   = (float*)d_ws;
    float* outp = (float*)d_out;

    hipLaunchKernelGGL(k_init, dim3(10), dim3(256), 0, stream, ws);
    hipLaunchKernelGGL(k_w2t, dim3(144), dim3(256), 0, stream, posW2, ws);
    hipLaunchKernelGGL(k_prep, dim3(1008), dim3(256), 0, stream,
                       propW, Wqkv, fusW, Wproj, posW1, ws);
    hipLaunchKernelGGL(k_castx, dim3(NP*DD/256), dim3(256), 0, stream, x, ws);
    hipLaunchKernelGGL(k1_glue, dim3(NP/16), dim3(256), 0, stream, p, knn, ws);
    hipLaunchKernelGGL(k2_fold, dim3(3), dim3(256), 0, stream,
                       posW1, posB1, gamma, beta, gCW, gCb, ws);
    hipLaunchKernelGGL(k_prop_mfma, dim3(MTOT/64), dim3(256), 0, stream,
                       x, knn, propW, propB, ws);
    hipLaunchKernelGGL(k3a, dim3(NP/16), dim3(256), 0, stream,
                       p, kn, deW1, deB1, deW2, deB2, kpW, kpB, gAW, gAb, gBW, gBb, ws);
    // X2B = bf16(UB @ fusW + fusB)
    hipLaunchKernelGGL(gemm_mfma, dim3(NP/64, 3), dim3(256), 0, stream,
                       (const ushort_t*)(ws + WS_UB), (const ushort_t*)(ws + WS_FUSWT),
                       fusB, (float*)nullptr, (ushort_t*)(ws + WS_X2B), DD);
    // QKV = X2B @ Wqkv (fp32 out)
    hipLaunchKernelGGL(gemm_mfma, dim3(NP/64, 9), dim3(256), 0, stream,
                       (const ushort_t*)(ws + WS_X2B), (const ushort_t*)(ws + WS_QKVT),
                       (const float*)nullptr, ws + WS_QKV, (ushort_t*)nullptr, 576);
    hipLaunchKernelGGL(k_dqdk, dim3(NP/8), dim3(256), 0, stream, knn, posW2, ws);
    hipLaunchKernelGGL(k_score, dim3(NP), dim3(256), 0, stream, knn, ws);
    hipLaunchKernelGGL(k_pv, dim3(NP/8), dim3(256), 0, stream, posB2, ws);
    // OUT = CTRB @ Wproj + bproj (fp32 out)
    hipLaunchKernelGGL(gemm_mfma, dim3(NP/64, 3), dim3(256), 0, stream,
                       (const ushort_t*)(ws + WS_CTRB), (const ushort_t*)(ws + WS_PROJWT),
                       bproj, outp, (ushort_t*)nullptr, DD);
}

// Round 8
// 802.461 us; speedup vs baseline: 10.4688x; 1.2121x over previous
//
#include <hip/hip_runtime.h>
#include <math.h>

#define NP 16384
#define DD 192
#define NS 16
#define KSPN 16
#define MTOT (NP*NS)

typedef unsigned short ushort_t;
typedef __attribute__((ext_vector_type(8))) short short8;
typedef __attribute__((ext_vector_type(4))) float f32x4;

__device__ __forceinline__ ushort_t f2bf(float f) {
    union { float f; unsigned int u; } v; v.f = f;
    return (ushort_t)((v.u + 0x7FFFu + ((v.u >> 16) & 1u)) >> 16);
}

// ws float offsets
#define WS_KNN   0                         // NP*48   knn_xyz
#define WS_PR    (WS_KNN + NP*48)          // MTOT*3  p_r per window row
#define WS_GEO9  (WS_PR + MTOT*3)          // NP*9
#define WS_GDIS  (WS_GEO9 + NP*9)          // NP
// STATS: [0]=dsum [1]=dmax(bits) [2..50)=sumX [50..2354)=A1 [2354..2498)=A2
//        [2498..2507)=A3 [2507..2510)=sumS
#define WS_STATS (WS_GDIS + NP)
#define WS_VOLV  (WS_STATS + 2512)         // 192
#define WS_AB    (WS_VOLV + DD)            // a[3][192] | bb[3][192] = 1152
#define WS_X1    (WS_AB + 1152)            // NP*192 post-propagate; later CTR1 (attn@v)
#define WS_U     (WS_X1 + NP*DD)           // NP*192: CTRB (bf16) after k_pv
#define WS_X2    (WS_U + NP*DD)            // NP*192: X2B (bf16, written by fus gemm)
#define WS_QKV   (WS_X2 + NP*DD)           // NP*576
#define WS_SC    (WS_QKV + NP*576)         // NP*192  SC[n][i(2)][h(6)][j(16)]; early: XB overlay
#define WS_ATTN  (WS_SC + NP*DD)           // NP*96   attn; early: UB (bf16) overlay
#define WS_W2T   (WS_ATTN + NP*96)         // 192*192 transposed posW2[2] fp32
#define WS_PROPWT (WS_W2T + 36864)         // 18432 floats (bf16 transposed propW[:192])
#define WS_QKVT  (WS_PROPWT + 18432)       // 55296
#define WS_FUSWT (WS_QKVT + 55296)         // 18432
#define WS_PROJWT (WS_FUSWT + 18432)       // 18432
#define WS_W1T   (WS_PROJWT + 18432)       // 3*192*64 bf16 = 18432 floats (K pad 64)
// overlays (bf16 arrays in dead-interval regions):
#define WS_XB    WS_SC
#define WS_UB    WS_ATTN
#define WS_X2B   WS_X2
#define WS_CTRB  WS_U

__global__ __launch_bounds__(256) void k_init(float* __restrict__ ws) {
    int t = blockIdx.x * 256 + threadIdx.x;
    if (t < 2512) ws[WS_STATS + t] = 0.f;
}

// ---- tiny: W2T[c][kk] = posW2[2][kk][c] (fp32, for k_pv) ----
__global__ __launch_bounds__(256) void k_w2t(const float* __restrict__ posW2,
                                             float* __restrict__ ws) {
    int e = blockIdx.x*256 + threadIdx.x;      // e = c*192 + kk
    int c = e / DD, kk = e - c*DD;
    ws[WS_W2T + e] = posW2[(size_t)(2*DD + kk)*DD + c];
}

// ---- prep: bf16 transposed weight copies (n-major, k-contiguous) ----
__global__ __launch_bounds__(256) void k_prep(
    const float* __restrict__ propW, const float* __restrict__ Wqkv,
    const float* __restrict__ fusW, const float* __restrict__ Wproj,
    const float* __restrict__ posW1,
    float* __restrict__ ws)
{
    int e = blockIdx.x*256 + threadIdx.x;
    ushort_t* pwt = (ushort_t*)(ws + WS_PROPWT);
    ushort_t* qkt = (ushort_t*)(ws + WS_QKVT);
    ushort_t* fwt = (ushort_t*)(ws + WS_FUSWT);
    ushort_t* pjt = (ushort_t*)(ws + WS_PROJWT);
    ushort_t* w1t = (ushort_t*)(ws + WS_W1T);
    if (e < 36864) {
        int n = e/192, k = e - n*192;
        pwt[e] = f2bf(propW[(size_t)k*192 + n]);
    } else if (e < 147456) {
        int r = e - 36864; int n = r/192, k = r - n*192;
        qkt[r] = f2bf(Wqkv[(size_t)k*576 + n]);
    } else if (e < 184320) {
        int r = e - 147456; int n = r/192, k = r - n*192;
        fwt[r] = f2bf(fusW[(size_t)k*192 + n]);
    } else if (e < 221184) {
        int r = e - 184320; int n = r/192, k = r - n*192;
        pjt[r] = f2bf(Wproj[(size_t)k*192 + n]);
    } else if (e < 258048) {
        int r = e - 221184;
        int i = r / 12288, rem = r - i*12288;
        int n = rem / 64, k = rem - n*64;
        w1t[r] = (k < 48) ? f2bf(posW1[(size_t)(i*48 + k)*DD + n]) : (ushort_t)0;
    }
}

// ---- cast x -> bf16 ----
__global__ __launch_bounds__(256) void k_castx(const float* __restrict__ x,
                                               float* __restrict__ ws) {
    int e = blockIdx.x*256 + threadIdx.x;
    ((ushort_t*)(ws + WS_XB))[e] = f2bf(x[e]);
}

// ---- K1a: per-(point,neighbor) geometry. One thread per (n, j). ----
__global__ __launch_bounds__(256) void k1a_geom(
    const float* __restrict__ p, const int* __restrict__ knn,
    float* __restrict__ ws)
{
    __shared__ float red[32];
    const int t = threadIdx.x;
    const int w = t >> 4, u = t & 15;
    const int n = blockIdx.x*16 + w;
    const int idx = knn[n*NS + u];
    const float X0 = p[idx*3+0], X1 = p[idx*3+1], X2 = p[idx*3+2];
    const float pn0 = p[n*3+0], pn1 = p[n*3+1], pn2 = p[n*3+2];
    ws[WS_KNN + (size_t)n*48 + u*3 + 0] = X0;
    ws[WS_KNN + (size_t)n*48 + u*3 + 1] = X1;
    ws[WS_KNN + (size_t)n*48 + u*3 + 2] = X2;
    const float dx = X0-pn0, dy = X1-pn1, dz = X2-pn2;
    ws[WS_PR + (size_t)(n*NS+u)*3 + 0] = dx;
    ws[WS_PR + (size_t)(n*NS+u)*3 + 1] = dy;
    ws[WS_PR + (size_t)(n*NS+u)*3 + 2] = dz;
    const float dist = sqrtf(dx*dx + dy*dy + dz*dz + 1e-12f);
    float dmx = dist, dsm = dist, S0 = X0, S1 = X1, S2 = X2;
    #pragma unroll
    for (int off = 1; off < 16; off <<= 1) {
        dmx = fmaxf(dmx, __shfl_xor(dmx, off, 16));
        dsm += __shfl_xor(dsm, off, 16);
        S0 += __shfl_xor(S0, off, 16);
        S1 += __shfl_xor(S1, off, 16);
        S2 += __shfl_xor(S2, off, 16);
    }
    if (u == 0) {
        ws[WS_GDIS + n] = dmx;
        float m0 = S0*(1.f/16.f), m1 = S1*(1.f/16.f), m2 = S2*(1.f/16.f);
        float* g = ws + WS_GEO9 + (size_t)n*9;
        g[0] = m0-pn0; g[1] = m1-pn1; g[2] = m2-pn2;
        g[3] = m0; g[4] = m1; g[5] = m2;
        g[6] = pn0; g[7] = pn1; g[8] = pn2;
        red[w] = dsm; red[16+w] = dmx;
    }
    __syncthreads();
    if (t == 0) {
        float ds = 0.f, dm = 0.f;
        #pragma unroll
        for (int i = 0; i < 16; ++i) { ds += red[i]; dm = fmaxf(dm, red[16+i]); }
        atomicAdd(&ws[WS_STATS + 0], ds);
        atomicMax((int*)(ws + WS_STATS + 1), __float_as_int(dm));  // dist>=0
    }
}

// ---- K1b: factored BN stats: A1=Sum XX^T, A2=Sum X S^T, A3=Sum T, sumX, sumS ----
__global__ __launch_bounds__(256) void k1b_stats(float* __restrict__ ws)
{
    __shared__ float Xs[128][48];
    __shared__ float Ss[128][3];
    __shared__ float a3p[9][16];
    const int t = threadIdx.x;
    const int c0 = blockIdx.x * 128;
    for (int e = t; e < 1536; e += 256) {
        int r = e/12, q = e%12;
        *(float4*)&Xs[r][q*4] = *(const float4*)(ws + WS_KNN + (size_t)(c0+r)*48 + q*4);
    }
    __syncthreads();
    if (t < 128) {
        float s0 = 0.f, s1 = 0.f, s2 = 0.f;
        #pragma unroll
        for (int j = 0; j < 16; ++j) { s0 += Xs[t][3*j]; s1 += Xs[t][3*j+1]; s2 += Xs[t][3*j+2]; }
        Ss[t][0] = s0; Ss[t][1] = s1; Ss[t][2] = s2;
    }
    __syncthreads();
    {   // A1: 9 entries per thread
        float acc[9];
        #pragma unroll
        for (int q = 0; q < 9; ++q) acc[q] = 0.f;
        for (int i = 0; i < 128; ++i) {
            int e = t;
            #pragma unroll
            for (int q = 0; q < 9; ++q) {
                int a = e/48, b = e%48;
                acc[q] += Xs[i][a] * Xs[i][b];
                e += 256;
            }
        }
        int e = t;
        #pragma unroll
        for (int q = 0; q < 9; ++q) { atomicAdd(&ws[WS_STATS + 50 + e], acc[q]); e += 256; }
    }
    if (t < 144) {   // A2[a][d]
        int a = t/3, d = t%3;
        float s = 0.f;
        for (int i = 0; i < 128; ++i) s += Xs[i][a] * Ss[i][d];
        atomicAdd(&ws[WS_STATS + 2354 + t], s);
    }
    if (t < 144) {   // A3 partials: q = t/16 entry, part = t%16 -> 8 points each
        int q = t >> 4, part = t & 15;
        int d = q/3, e2 = q%3;
        float s = 0.f;
        for (int i = part*8; i < part*8 + 8; ++i) {
            #pragma unroll
            for (int j = 0; j < 16; ++j) s += Xs[i][3*j+d] * Xs[i][3*j+e2];
        }
        a3p[q][part] = s;
    }
    if (t < 48) {    // sumX
        float s = 0.f;
        for (int i = 0; i < 128; ++i) s += Xs[i][t];
        atomicAdd(&ws[WS_STATS + 2 + t], s);
    }
    if (t < 3) {     // sumS
        float s = 0.f;
        for (int i = 0; i < 128; ++i) s += Ss[i][t];
        atomicAdd(&ws[WS_STATS + 2507 + t], s);
    }
    __syncthreads();
    if (t < 9) {
        float s = 0.f;
        #pragma unroll
        for (int i = 0; i < 16; ++i) s += a3p[t][i];
        atomicAdd(&ws[WS_STATS + 2498 + t], s);
    }
}

// ---- K2: vol vector + BN fold (M2 reconstructed from factored stats) ----
__global__ __launch_bounds__(256) void k2_fold(
    const float* __restrict__ posW1, const float* __restrict__ posB1,
    const float* __restrict__ gamma, const float* __restrict__ beta,
    const float* __restrict__ gCW, const float* __restrict__ gCb,
    float* __restrict__ ws)
{
    __shared__ float M2n[48][48];
    __shared__ float pmean[48];
    __shared__ float Wc[48][193];
    const int t = threadIdx.x;
    const int i = blockIdx.x;
    for (int e = t; e < 2304; e += 256) {
        int a = e/48, b = e%48, ad = a%3, bd = b%3;
        float v = 16.f*ws[WS_STATS + 50 + e]
                - ws[WS_STATS + 2354 + a*3 + bd]
                - ws[WS_STATS + 2354 + b*3 + ad]
                + ws[WS_STATS + 2498 + ad*3 + bd];
        M2n[a][b] = v * (1.f/(float)MTOT);
    }
    if (t < 48) pmean[t] = (16.f*ws[WS_STATS + 2 + t] - ws[WS_STATS + 2507 + t%3])
                           * (1.f/(float)MTOT);
    if (t < DD) {
        for (int k = 0; k < 48; ++k) Wc[k][t] = posW1[(size_t)(i*48 + k)*DD + t];
    }
    __syncthreads();
    if (i == 0 && t < DD) {
        float dsum = ws[WS_STATS + 0];
        float dmax = __int_as_float(((const int*)(ws + WS_STATS))[1]);
        float vol = (dsum * (1.f/(float)MTOT)) / (dmax + 1e-8f);
        ws[WS_VOLV + t] = vol * gCW[t] + gCb[t];
    }
    if (t < DD) {
        float mu0 = 0.f;
        #pragma unroll 8
        for (int k = 0; k < 48; ++k) mu0 += pmean[k] * Wc[k][t];
        float e2 = 0.f;
        for (int a2 = 0; a2 < 48; ++a2) {
            float inner = 0.f;
            #pragma unroll 8
            for (int b2 = 0; b2 < 48; ++b2) inner += M2n[a2][b2] * Wc[b2][t];
            e2 += Wc[a2][t] * inner;
        }
        float var = fmaxf(e2 - mu0*mu0, 0.f);
        float as = rsqrtf(var + 1e-5f) * gamma[i*DD + t];
        ws[WS_AB + i*DD + t]       = as;
        ws[WS_AB + 576 + i*DD + t] = beta[i*DD + t] - mu0 * as;   // h'=relu(acc*as+bb)
    }
}

// ---- K_prop MFMA: gathered bf16 GEMM + fp32 p_r tail + relu + window mean ----
__global__ __launch_bounds__(256) void k_prop_mfma(
    const float* __restrict__ x, const int* __restrict__ knn,
    const float* __restrict__ propW, const float* __restrict__ propB,
    float* __restrict__ ws)
{
    __shared__ ushort_t As[64*40];     // A tile, stride 40 bf16 (80 B)
    __shared__ ushort_t Bs[192*40];    // Bt tile
    __shared__ float prs[64*3];
    __shared__ float W3[3*192];
    __shared__ int idx64[64];
    const int t = threadIdx.x;
    const int mbase = blockIdx.x * 64;
    const ushort_t* xb = (const ushort_t*)(ws + WS_XB);
    const ushort_t* pwt = (const ushort_t*)(ws + WS_PROPWT);
    if (t < 64) idx64[t] = knn[mbase + t];
    for (int e = t; e < 576; e += 256) W3[e] = propW[(size_t)(192 + e/192)*DD + (e % 192)];
    for (int e = t; e < 192; e += 256) prs[e] = ws[WS_PR + (size_t)mbase*3 + e];
    const int wave = t >> 6, lane = t & 63, m = lane & 15, quad = lane >> 4;
    f32x4 acc[12];
    #pragma unroll
    for (int nt = 0; nt < 12; ++nt) acc[nt] = (f32x4){0.f,0.f,0.f,0.f};
    for (int ks = 0; ks < 6; ++ks) {
        const int k0 = ks*32;
        __syncthreads();
        {   int r = t >> 2, seg = t & 3;
            *(uint4*)&As[r*40 + seg*8] = *(const uint4*)(xb + (size_t)idx64[r]*192 + k0 + seg*8);
        }
        for (int e = t; e < 768; e += 256) {
            int n = e >> 2, seg = e & 3;
            *(uint4*)&Bs[n*40 + seg*8] = *(const uint4*)(pwt + (size_t)n*192 + k0 + seg*8);
        }
        __syncthreads();
        short8 a = *(const short8*)&As[(wave*16 + m)*40 + quad*8];
        #pragma unroll
        for (int nt = 0; nt < 12; ++nt) {
            short8 b = *(const short8*)&Bs[(nt*16 + m)*40 + quad*8];
            acc[nt] = __builtin_amdgcn_mfma_f32_16x16x32_bf16(a, b, acc[nt], 0, 0, 0);
        }
    }
    const int n = blockIdx.x*4 + wave;   // global point
    #pragma unroll
    for (int nt = 0; nt < 12; ++nt) {
        int col = nt*16 + m;
        float bv = propB[col];
        float w0 = W3[col], w1 = W3[192 + col], w2 = W3[384 + col];
        float s = 0.f;
        #pragma unroll
        for (int reg = 0; reg < 4; ++reg) {
            int j = wave*16 + quad*4 + reg;
            float v = acc[nt][reg] + prs[j*3+0]*w0 + prs[j*3+1]*w1 + prs[j*3+2]*w2 + bv;
            s += fmaxf(v, 0.f);
        }
        s += __shfl_xor(s, 16);
        s += __shfl_xor(s, 32);
        if (quad == 0)
            ws[WS_X1 + (size_t)n*DD + col] = x[(size_t)n*DD + col] + s * (1.f/16.f);
    }
}

// ---- generic bf16 MFMA GEMM: C[M x N] = A[M x 192] @ Bt^T (+bias) ----
__global__ __launch_bounds__(256) void gemm_mfma(
    const ushort_t* __restrict__ A, const ushort_t* __restrict__ Bt,
    const float* __restrict__ bias, float* __restrict__ Cf,
    ushort_t* __restrict__ Cb, int N)
{
    __shared__ ushort_t As[64*40];
    __shared__ ushort_t Bs[64*40];
    const int t = threadIdx.x;
    const int wave = t >> 6, lane = t & 63, m = lane & 15, quad = lane >> 4;
    const int rowBase = blockIdx.x * 64, colBase = blockIdx.y * 64;
    f32x4 acc[4];
    #pragma unroll
    for (int nt = 0; nt < 4; ++nt) acc[nt] = (f32x4){0.f,0.f,0.f,0.f};
    for (int ks = 0; ks < 6; ++ks) {
        __syncthreads();
        {   int r = t >> 2, seg = t & 3;
            *(uint4*)&As[r*40 + seg*8] = *(const uint4*)(A + (size_t)(rowBase + r)*192 + ks*32 + seg*8);
            *(uint4*)&Bs[r*40 + seg*8] = *(const uint4*)(Bt + (size_t)(colBase + r)*192 + ks*32 + seg*8);
        }
        __syncthreads();
        short8 a = *(const short8*)&As[(wave*16 + m)*40 + quad*8];
        #pragma unroll
        for (int nt = 0; nt < 4; ++nt) {
            short8 b = *(const short8*)&Bs[(nt*16 + m)*40 + quad*8];
            acc[nt] = __builtin_amdgcn_mfma_f32_16x16x32_bf16(a, b, acc[nt], 0, 0, 0);
        }
    }
    #pragma unroll
    for (int nt = 0; nt < 4; ++nt) {
        int col = colBase + nt*16 + m;
        float bv = bias ? bias[col] : 0.f;
        #pragma unroll
        for (int reg = 0; reg < 4; ++reg) {
            int row = rowBase + wave*16 + quad*4 + reg;
            float v = acc[nt][reg] + bv;
            if (Cf) Cf[(size_t)row*N + col] = v;
            else    Cb[(size_t)row*N + col] = f2bf(v);
        }
    }
}

// ---- K3a: keypoint attention + U assembly (writes bf16 UB) ----
__global__ __launch_bounds__(256) void k3a(
    const float* __restrict__ p, const float* __restrict__ kn,
    const float* __restrict__ deW1, const float* __restrict__ deB1,
    const float* __restrict__ deW2, const float* __restrict__ deB2,
    const float* __restrict__ kpW, const float* __restrict__ kpB,
    const float* __restrict__ gAW, const float* __restrict__ gAb,
    const float* __restrict__ gBW, const float* __restrict__ gBb,
    float* __restrict__ ws)
{
    __shared__ float Wd[48][196];
    __shared__ float innr[KSPN][49];
    __shared__ float df[KSPN][193];
    __shared__ float kd[KSPN];
    __shared__ float scl[KSPN];
    ushort_t* ub = (ushort_t*)(ws + WS_UB);
    const int t = threadIdx.x;
    for (int e = t; e < 48*48; e += 256) {
        int w = e / 48, cq = e - w*48;
        *(float4*)&Wd[w][cq*4] = *(const float4*)(deW2 + (size_t)w*DD + cq*4);
    }
    const int kap = t >> 4, u = t & 15, c0 = u*12;
    for (int it = 0; it < 16; ++it) {
        const int n = blockIdx.x*16 + it;
        __syncthreads();
        if (t < KSPN) {
            float dx = p[n*3]-kn[t*3], dy = p[n*3+1]-kn[t*3+1], dz = p[n*3+2]-kn[t*3+2];
            kd[t] = sqrtf(dx*dx + dy*dy + dz*dz + 1e-12f);
        }
        __syncthreads();
        for (int e = t; e < KSPN*48; e += 256) {
            int r = e / 48, j = e - r*48;
            innr[r][j] = fmaxf(kd[r]*deW1[j] + deB1[j], 0.f);
        }
        __syncthreads();
        float a12[12];
        #pragma unroll
        for (int m = 0; m < 12; ++m) a12[m] = deB2[c0 + m];
        for (int w = 0; w < 48; ++w) {
            float av = innr[kap][w];
            #pragma unroll
            for (int m = 0; m < 12; ++m) a12[m] += av * Wd[w][c0 + m];
        }
        float ksc = 0.f;
        #pragma unroll
        for (int m = 0; m < 12; ++m) { df[kap][c0 + m] = a12[m]; ksc += a12[m]*kpW[c0 + m]; }
        #pragma unroll
        for (int off = 1; off < 16; off <<= 1) ksc += __shfl_xor(ksc, off, 16);
        if (u == 0) scl[kap] = ksc + kpB[0];
        __syncthreads();
        if (t < KSPN) {
            float v = scl[t], mx = v;
            #pragma unroll
            for (int off = 1; off < 16; off <<= 1) mx = fmaxf(mx, __shfl_xor(mx, off, 16));
            float e = expf(v - mx);
            float sm = e;
            #pragma unroll
            for (int off = 1; off < 16; off <<= 1) sm += __shfl_xor(sm, off, 16);
            scl[t] = e / sm;
        }
        __syncthreads();
        if (t < DD) {
            float dfeat = 0.f;
            #pragma unroll
            for (int k2 = 0; k2 < KSPN; ++k2) dfeat += scl[k2]*df[k2][t];
            float uval = ws[WS_X1 + (size_t)n*DD + t] + gAb[t] + gBb[t] + ws[WS_VOLV + t] + dfeat;
            uval += ws[WS_GDIS + n] * gBW[t];
            #pragma unroll
            for (int kk = 0; kk < 9; ++kk) uval += ws[WS_GEO9 + n*9 + kk] * gAW[kk*DD + t];
            ub[(size_t)n*DD + t] = f2bf(uval);
        }
    }
}

// ---- K_dqdk v4: 8 windows/block, both i. MFMA H-phase with fused rqs contraction ----
__global__ __launch_bounds__(256) void k_dqdk(
    const int* __restrict__ knn,
    const float* __restrict__ posW2,
    float* __restrict__ ws)
{
    __shared__ ushort_t posb[128*72];   // bf16 pos rows, K padded to 64, stride 72
    __shared__ float qk[8*192];         // q0 (i=0) / k0 (i=1)
    __shared__ float rqs[8*6*192];      // [w][h][kk]
    __shared__ float Xl[8][48];
    __shared__ int idx0[8];
    const int t = threadIdx.x;
    const int nb = blockIdx.x * 8;
    if (t < 8) idx0[t] = knn[(nb + t)*NS];
    for (int e = t; e < 384; e += 256) {
        int w = e / 48, k = e % 48;
        Xl[w][k] = ws[WS_KNN + (size_t)(nb + w)*48 + k];
    }
    __syncthreads();
    for (int e = t; e < 128*64; e += 256) {   // build bf16 pos tile
        int j = e >> 6, k = e & 63;
        int w = j >> 4, jl = j & 15;
        float v = (k < 48) ? (Xl[w][k] - Xl[w][jl*3 + (k % 3)]) : 0.f;
        posb[j*72 + k] = f2bf(v);
    }
    const int wave = t >> 6, lane = t & 63, m = lane & 15, quad = lane >> 4;
    const ushort_t* w1t = (const ushort_t*)(ws + WS_W1T);
    for (int i = 0; i < 2; ++i) {
        __syncthreads();
        for (int e = t; e < 8*192; e += 256) {
            int w = e / 192, c = e % 192;
            qk[w*192 + c] = ws[WS_QKV + (size_t)idx0[w]*576 + i*192 + c];
        }
        __syncthreads();
        if (t < 192) {        // rq: W2 row t (global) x qk broadcast
            const float* Wrow = posW2 + (size_t)i*DD*DD + (size_t)t*DD;
            for (int h = 0; h < 6; ++h) {
                float4 wr[8];
                #pragma unroll
                for (int q = 0; q < 8; ++q) wr[q] = *(const float4*)(Wrow + h*32 + q*4);
                float a[8];
                #pragma unroll
                for (int w = 0; w < 8; ++w) a[w] = 0.f;
                #pragma unroll
                for (int q = 0; q < 8; ++q) {
                    #pragma unroll
                    for (int d = 0; d < 4; ++d) {
                        float wv = (&wr[q].x)[d];
                        int c = h*32 + q*4 + d;
                        #pragma unroll
                        for (int w = 0; w < 8; ++w) a[w] += wv * qk[w*192 + c];
                    }
                }
                #pragma unroll
                for (int w = 0; w < 8; ++w) rqs[(w*6 + h)*192 + t] = a[w];
            }
        }
        __syncthreads();
        short8 afr[2][2];
        #pragma unroll
        for (int mt = 0; mt < 2; ++mt)
            #pragma unroll
            for (int ks = 0; ks < 2; ++ks)
                afr[mt][ks] = *(const short8*)&posb[((wave*2 + mt)*16 + m)*72 + ks*32 + quad*8];
        float s[48];          // [mt(2)][reg(4)][h(6)]
        #pragma unroll
        for (int e = 0; e < 48; ++e) s[e] = 0.f;
        for (int nt = 0; nt < 12; ++nt) {
            f32x4 acc0 = (f32x4){0.f,0.f,0.f,0.f};
            f32x4 acc1 = (f32x4){0.f,0.f,0.f,0.f};
            #pragma unroll
            for (int ks = 0; ks < 2; ++ks) {
                short8 b = *(const short8*)(w1t + ((size_t)(i*192 + nt*16 + m)*64 + ks*32 + quad*8));
                acc0 = __builtin_amdgcn_mfma_f32_16x16x32_bf16(afr[0][ks], b, acc0, 0, 0, 0);
                acc1 = __builtin_amdgcn_mfma_f32_16x16x32_bf16(afr[1][ks], b, acc1, 0, 0, 0);
            }
            int kk = nt*16 + m;
            float as = ws[WS_AB + i*DD + kk];
            float bb = ws[WS_AB + 576 + i*DD + kk];
            float h0[4], h1[4];
            #pragma unroll
            for (int reg = 0; reg < 4; ++reg) {
                h0[reg] = fmaxf(acc0[reg]*as + bb, 0.f);
                h1[reg] = fmaxf(acc1[reg]*as + bb, 0.f);
            }
            #pragma unroll
            for (int h = 0; h < 6; ++h) {
                float r0 = rqs[((wave*2 + 0)*6 + h)*192 + kk];
                float r1 = rqs[((wave*2 + 1)*6 + h)*192 + kk];
                #pragma unroll
                for (int reg = 0; reg < 4; ++reg) {
                    s[reg*6 + h]      += h0[reg]*r0;
                    s[24 + reg*6 + h] += h1[reg]*r1;
                }
            }
        }
        #pragma unroll
        for (int e = 0; e < 48; ++e) {   // reduce over m lanes (width 16)
            float v = s[e];
            v += __shfl_xor(v, 1, 16); v += __shfl_xor(v, 2, 16);
            v += __shfl_xor(v, 4, 16); v += __shfl_xor(v, 8, 16);
            s[e] = v;
        }
        if (m == 0) {
            #pragma unroll
            for (int mt = 0; mt < 2; ++mt)
                #pragma unroll
                for (int reg = 0; reg < 4; ++reg) {
                    int w = wave*2 + mt, j = quad*4 + reg;
                    #pragma unroll
                    for (int h = 0; h < 6; ++h)
                        ws[WS_SC + (size_t)(nb + w)*192 + i*96 + h*16 + j] = s[mt*24 + reg*6 + h];
                }
        }
    }
}

// ---- K_score: q0.k_j dots + softmax + CTR1 = attn@v; stores attn ----
__global__ __launch_bounds__(256) void k_score(
    const int* __restrict__ knn, float* __restrict__ ws)
{
    __shared__ float Kw[NS][196];
    __shared__ float Vw[NS][196];
    __shared__ float q0s[192];
    __shared__ float dqks[6][16];
    __shared__ float attns[6][16];
    __shared__ int idx[NS];
    const int n = blockIdx.x;
    const int t = threadIdx.x;
    if (t < NS) idx[t] = knn[n*NS + t];
    __syncthreads();
    for (int e = t; e < NS*48; e += 256) {
        int r = e/48, cq = e%48;
        *(float4*)&Kw[r][cq*4] = *(const float4*)(ws + WS_QKV + (size_t)idx[r]*576 + 192 + cq*4);
        *(float4*)&Vw[r][cq*4] = *(const float4*)(ws + WS_QKV + (size_t)idx[r]*576 + 384 + cq*4);
    }
    if (t < DD) q0s[t] = ws[WS_QKV + (size_t)idx[0]*576 + t];
    __syncthreads();
    {
        const int j = t >> 4, u = t & 15;
        #pragma unroll
        for (int h = 0; h < 6; ++h) {
            int c = h*32 + u*2;
            float v = q0s[c]*Kw[j][c] + q0s[c+1]*Kw[j][c+1];
            #pragma unroll
            for (int off = 1; off < 16; off <<= 1) v += __shfl_xor(v, off, 16);
            if (u == 0) dqks[h][j] = v;
        }
    }
    __syncthreads();
    if (t < 96) {
        const float scale = 0.17677669529663687f;  // 32^-0.5
        const int h = t >> 4, jj = t & 15;
        float z = (dqks[h][jj]
                 + ws[WS_SC + (size_t)n*192 + h*16 + jj]
                 + ws[WS_SC + (size_t)n*192 + 96 + h*16 + jj]) * scale;
        float mx = z;
        #pragma unroll
        for (int off = 1; off < 16; off <<= 1) mx = fmaxf(mx, __shfl_xor(mx, off, 16));
        float e = expf(z - mx);
        float sm = e;
        #pragma unroll
        for (int off = 1; off < 16; off <<= 1) sm += __shfl_xor(sm, off, 16);
        float a = e / sm;
        attns[h][jj] = a;
        ws[WS_ATTN + (size_t)n*96 + h*16 + jj] = a;
    }
    __syncthreads();
    if (t < DD) {
        const int h = t >> 5;
        float s = 0.f;
        #pragma unroll
        for (int jj = 0; jj < NS; ++jj) s += attns[h][jj] * Vw[jj][t];
        ws[WS_X1 + (size_t)n*DD + t] = s;
    }
}

// ---- K_pv v3: MFMA H2 with fused attn-weighted j-reduction -> wsum; pv via W2T ----
__global__ __launch_bounds__(256) void k_pv(
    const float* __restrict__ posB2, float* __restrict__ ws)
{
    __shared__ ushort_t posb[128*72];
    __shared__ float wsum[8*6*192];
    __shared__ float attns[8][96];
    __shared__ float Xl[8][48];
    ushort_t* ctrb = (ushort_t*)(ws + WS_CTRB);
    const int t = threadIdx.x;
    const int nb = blockIdx.x * 8;
    for (int e = t; e < 384; e += 256) {
        int w = e/48, k = e%48;
        Xl[w][k] = ws[WS_KNN + (size_t)(nb+w)*48 + k];
    }
    for (int e = t; e < 768; e += 256) {
        int w = e/96, r = e%96;
        attns[w][r] = ws[WS_ATTN + (size_t)(nb+w)*96 + r];
    }
    __syncthreads();
    for (int e = t; e < 128*64; e += 256) {
        int j = e >> 6, k = e & 63;
        int w = j >> 4, jl = j & 15;
        float v = (k < 48) ? (Xl[w][k] - Xl[w][jl*3 + (k % 3)]) : 0.f;
        posb[j*72 + k] = f2bf(v);
    }
    __syncthreads();
    {
        const int wave = t >> 6, lane = t & 63, m = lane & 15, quad = lane >> 4;
        const ushort_t* w1t = (const ushort_t*)(ws + WS_W1T);
        const int w0 = wave*2, w1 = wave*2 + 1;
        short8 afr[2][2];
        #pragma unroll
        for (int mt = 0; mt < 2; ++mt)
            #pragma unroll
            for (int ks = 0; ks < 2; ++ks)
                afr[mt][ks] = *(const short8*)&posb[((wave*2 + mt)*16 + m)*72 + ks*32 + quad*8];
        for (int nt = 0; nt < 12; ++nt) {
            f32x4 acc0 = (f32x4){0.f,0.f,0.f,0.f};
            f32x4 acc1 = (f32x4){0.f,0.f,0.f,0.f};
            #pragma unroll
            for (int ks = 0; ks < 2; ++ks) {
                short8 b = *(const short8*)(w1t + ((size_t)(2*192 + nt*16 + m)*64 + ks*32 + quad*8));
                acc0 = __builtin_amdgcn_mfma_f32_16x16x32_bf16(afr[0][ks], b, acc0, 0, 0, 0);
                acc1 = __builtin_amdgcn_mfma_f32_16x16x32_bf16(afr[1][ks], b, acc1, 0, 0, 0);
            }
            int kk = nt*16 + m;
            float as = ws[WS_AB + 2*DD + kk];
            float bb = ws[WS_AB + 576 + 2*DD + kk];
            float h0[4], h1[4];
            #pragma unroll
            for (int reg = 0; reg < 4; ++reg) {
                h0[reg] = fmaxf(acc0[reg]*as + bb, 0.f);
                h1[reg] = fmaxf(acc1[reg]*as + bb, 0.f);
            }
            #pragma unroll
            for (int h = 0; h < 6; ++h) {
                float p0 = 0.f, p1 = 0.f;
                #pragma unroll
                for (int reg = 0; reg < 4; ++reg) {
                    int j = quad*4 + reg;
                    p0 += attns[w0][h*16 + j] * h0[reg];
                    p1 += attns[w1][h*16 + j] * h1[reg];
                }
                p0 += __shfl_xor(p0, 16); p0 += __shfl_xor(p0, 32);
                p1 += __shfl_xor(p1, 16); p1 += __shfl_xor(p1, 32);
                if (quad == 0) {
                    wsum[(w0*6 + h)*192 + kk] = p0;
                    wsum[(w1*6 + h)*192 + kk] = p1;
                }
            }
        }
    }
    __syncthreads();
    if (t < DD) {
        const int h = t >> 5;
        float pvacc[8];
        #pragma unroll
        for (int w = 0; w < 8; ++w) pvacc[w] = 0.f;
        const float* wrow = ws + WS_W2T + (size_t)t*DD;
        for (int k4 = 0; k4 < 48; ++k4) {
            float4 wv = *(const float4*)(wrow + k4*4);
            #pragma unroll
            for (int w = 0; w < 8; ++w) {
                float4 av = *(const float4*)&wsum[(w*6 + h)*192 + k4*4];
                pvacc[w] += av.x*wv.x + av.y*wv.y + av.z*wv.z + av.w*wv.w;
            }
        }
        float b2 = posB2[2*DD + t];
        #pragma unroll
        for (int w = 0; w < 8; ++w) {
            ctrb[(size_t)(nb+w)*DD + t] =
                f2bf(ws[WS_X1 + (size_t)(nb+w)*DD + t] + pvacc[w] + b2);
        }
    }
}

extern "C" void kernel_launch(void* const* d_in, const int* in_sizes, int n_in,
                              void* d_out, int out_size, void* d_ws, size_t ws_size,
                              hipStream_t stream)
{
    const float* p     = (const float*)d_in[0];
    const float* x     = (const float*)d_in[1];
    const int*   knn   = (const int*)  d_in[2];
    const float* Wqkv  = (const float*)d_in[3];
    const float* Wproj = (const float*)d_in[4];
    const float* bproj = (const float*)d_in[5];
    const float* propW = (const float*)d_in[6];
    const float* propB = (const float*)d_in[7];
    const float* gAW   = (const float*)d_in[8];
    const float* gAb   = (const float*)d_in[9];
    const float* gBW   = (const float*)d_in[10];
    const float* gBb   = (const float*)d_in[11];
    const float* gCW   = (const float*)d_in[12];
    const float* gCb   = (const float*)d_in[13];
    const float* posW1 = (const float*)d_in[14];
    const float* posB1 = (const float*)d_in[15];
    const float* gamma = (const float*)d_in[16];
    const float* beta  = (const float*)d_in[17];
    const float* posW2 = (const float*)d_in[18];
    const float* posB2 = (const float*)d_in[19];
    const float* kn    = (const float*)d_in[20];
    const float* deW1  = (const float*)d_in[21];
    const float* deB1  = (const float*)d_in[22];
    const float* deW2  = (const float*)d_in[23];
    const float* deB2  = (const float*)d_in[24];
    const float* kpW   = (const float*)d_in[25];
    const float* kpB   = (const float*)d_in[26];
    const float* fusW  = (const float*)d_in[27];
    const float* fusB  = (const float*)d_in[28];
    float* ws   = (float*)d_ws;
    float* outp = (float*)d_out;

    hipLaunchKernelGGL(k_init, dim3(10), dim3(256), 0, stream, ws);
    hipLaunchKernelGGL(k_w2t, dim3(144), dim3(256), 0, stream, posW2, ws);
    hipLaunchKernelGGL(k_prep, dim3(1008), dim3(256), 0, stream,
                       propW, Wqkv, fusW, Wproj, posW1, ws);
    hipLaunchKernelGGL(k_castx, dim3(NP*DD/256), dim3(256), 0, stream, x, ws);
    hipLaunchKernelGGL(k1a_geom, dim3(NP/16), dim3(256), 0, stream, p, knn, ws);
    hipLaunchKernelGGL(k1b_stats, dim3(NP/128), dim3(256), 0, stream, ws);
    hipLaunchKernelGGL(k2_fold, dim3(3), dim3(256), 0, stream,
                       posW1, posB1, gamma, beta, gCW, gCb, ws);
    hipLaunchKernelGGL(k_prop_mfma, dim3(MTOT/64), dim3(256), 0, stream,
                       x, knn, propW, propB, ws);
    hipLaunchKernelGGL(k3a, dim3(NP/16), dim3(256), 0, stream,
                       p, kn, deW1, deB1, deW2, deB2, kpW, kpB, gAW, gAb, gBW, gBb, ws);
    // X2B = bf16(UB @ fusW + fusB)
    hipLaunchKernelGGL(gemm_mfma, dim3(NP/64, 3), dim3(256), 0, stream,
                       (const ushort_t*)(ws + WS_UB), (const ushort_t*)(ws + WS_FUSWT),
                       fusB, (float*)nullptr, (ushort_t*)(ws + WS_X2B), DD);
    // QKV = X2B @ Wqkv (fp32 out)
    hipLaunchKernelGGL(gemm_mfma, dim3(NP/64, 9), dim3(256), 0, stream,
                       (const ushort_t*)(ws + WS_X2B), (const ushort_t*)(ws + WS_QKVT),
                       (const float*)nullptr, ws + WS_QKV, (ushort_t*)nullptr, 576);
    hipLaunchKernelGGL(k_dqdk, dim3(NP/8), dim3(256), 0, stream, knn, posW2, ws);
    hipLaunchKernelGGL(k_score, dim3(NP), dim3(256), 0, stream, knn, ws);
    hipLaunchKernelGGL(k_pv, dim3(NP/8), dim3(256), 0, stream, posB2, ws);
    // OUT = CTRB @ Wproj + bproj (fp32 out)
    hipLaunchKernelGGL(gemm_mfma, dim3(NP/64, 3), dim3(256), 0, stream,
                       (const ushort_t*)(ws + WS_CTRB), (const ushort_t*)(ws + WS_PROJWT),
                       bproj, outp, (ushort_t*)nullptr, DD);
}

// Round 9
// 768.294 us; speedup vs baseline: 10.9344x; 1.0445x over previous
//
#include <hip/hip_runtime.h>
#include <math.h>

#define NP 16384
#define DD 192
#define NS 16
#define KSPN 16
#define MTOT (NP*NS)

typedef unsigned short ushort_t;
typedef __attribute__((ext_vector_type(8))) short short8;
typedef __attribute__((ext_vector_type(4))) float f32x4;

__device__ __forceinline__ ushort_t f2bf(float f) {
    union { float f; unsigned int u; } v; v.f = f;
    return (ushort_t)((v.u + 0x7FFFu + ((v.u >> 16) & 1u)) >> 16);
}

// ws float offsets
#define WS_KNN   0                         // NP*48   knn_xyz
#define WS_PR    (WS_KNN + NP*48)          // MTOT*3  p_r per window row
#define WS_GEO9  (WS_PR + MTOT*3)          // NP*9
#define WS_GDIS  (WS_GEO9 + NP*9)          // NP
// STATS: [0]=dsum [1]=dmax(bits) [2..50)=sumX [50..2354)=A1 [2354..2498)=A2
//        [2498..2507)=A3 [2507..2510)=sumS
#define WS_STATS (WS_GDIS + NP)
#define WS_VOLV  (WS_STATS + 2512)         // 192
#define WS_AB    (WS_VOLV + DD)            // a[3][192] | bb[3][192] = 1152
#define WS_X1    (WS_AB + 1152)            // NP*192 post-propagate (consumed by k3a)
#define WS_U     (WS_X1 + NP*DD)           // NP*192: CTRB (bf16) after fused attn
#define WS_X2    (WS_U + NP*DD)            // NP*192: X2B (bf16, written by fus gemm)
#define WS_QKV   (WS_X2 + NP*DD)           // NP*576
#define WS_SC    (WS_QKV + NP*576)         // region: XB overlay (bf16 x)
#define WS_ATTN  (WS_SC + NP*DD)           // region: UB overlay (bf16 U)
#define WS_W2T   (WS_ATTN + NP*96)         // 192*192 transposed posW2[2] fp32
#define WS_PROPWT (WS_W2T + 36864)         // 18432 floats (bf16 transposed propW[:192])
#define WS_QKVT  (WS_PROPWT + 18432)       // 55296
#define WS_FUSWT (WS_QKVT + 55296)         // 18432
#define WS_PROJWT (WS_FUSWT + 18432)       // 18432
#define WS_W1T   (WS_PROJWT + 18432)       // 3*192*64 bf16 = 18432 floats (K pad 64)
// overlays (bf16 arrays in dead-interval regions):
#define WS_XB    WS_SC
#define WS_UB    WS_ATTN
#define WS_X2B   WS_X2
#define WS_CTRB  WS_U

__global__ __launch_bounds__(256) void k_init(float* __restrict__ ws) {
    int t = blockIdx.x * 256 + threadIdx.x;
    if (t < 2512) ws[WS_STATS + t] = 0.f;
}

// ---- tiny: W2T[c][kk] = posW2[2][kk][c] (fp32) ----
__global__ __launch_bounds__(256) void k_w2t(const float* __restrict__ posW2,
                                             float* __restrict__ ws) {
    int e = blockIdx.x*256 + threadIdx.x;      // e = c*192 + kk
    int c = e / DD, kk = e - c*DD;
    ws[WS_W2T + e] = posW2[(size_t)(2*DD + kk)*DD + c];
}

// ---- prep: bf16 transposed weight copies (n-major, k-contiguous) ----
__global__ __launch_bounds__(256) void k_prep(
    const float* __restrict__ propW, const float* __restrict__ Wqkv,
    const float* __restrict__ fusW, const float* __restrict__ Wproj,
    const float* __restrict__ posW1,
    float* __restrict__ ws)
{
    int e = blockIdx.x*256 + threadIdx.x;
    ushort_t* pwt = (ushort_t*)(ws + WS_PROPWT);
    ushort_t* qkt = (ushort_t*)(ws + WS_QKVT);
    ushort_t* fwt = (ushort_t*)(ws + WS_FUSWT);
    ushort_t* pjt = (ushort_t*)(ws + WS_PROJWT);
    ushort_t* w1t = (ushort_t*)(ws + WS_W1T);
    if (e < 36864) {
        int n = e/192, k = e - n*192;
        pwt[e] = f2bf(propW[(size_t)k*192 + n]);
    } else if (e < 147456) {
        int r = e - 36864; int n = r/192, k = r - n*192;
        qkt[r] = f2bf(Wqkv[(size_t)k*576 + n]);
    } else if (e < 184320) {
        int r = e - 147456; int n = r/192, k = r - n*192;
        fwt[r] = f2bf(fusW[(size_t)k*192 + n]);
    } else if (e < 221184) {
        int r = e - 184320; int n = r/192, k = r - n*192;
        pjt[r] = f2bf(Wproj[(size_t)k*192 + n]);
    } else if (e < 258048) {
        int r = e - 221184;
        int i = r / 12288, rem = r - i*12288;
        int n = rem / 64, k = rem - n*64;
        w1t[r] = (k < 48) ? f2bf(posW1[(size_t)(i*48 + k)*DD + n]) : (ushort_t)0;
    }
}

// ---- cast x -> bf16 ----
__global__ __launch_bounds__(256) void k_castx(const float* __restrict__ x,
                                               float* __restrict__ ws) {
    int e = blockIdx.x*256 + threadIdx.x;
    ((ushort_t*)(ws + WS_XB))[e] = f2bf(x[e]);
}

// ---- K1a: per-(point,neighbor) geometry ----
__global__ __launch_bounds__(256) void k1a_geom(
    const float* __restrict__ p, const int* __restrict__ knn,
    float* __restrict__ ws)
{
    __shared__ float red[32];
    const int t = threadIdx.x;
    const int w = t >> 4, u = t & 15;
    const int n = blockIdx.x*16 + w;
    const int idx = knn[n*NS + u];
    const float X0 = p[idx*3+0], X1 = p[idx*3+1], X2 = p[idx*3+2];
    const float pn0 = p[n*3+0], pn1 = p[n*3+1], pn2 = p[n*3+2];
    ws[WS_KNN + (size_t)n*48 + u*3 + 0] = X0;
    ws[WS_KNN + (size_t)n*48 + u*3 + 1] = X1;
    ws[WS_KNN + (size_t)n*48 + u*3 + 2] = X2;
    const float dx = X0-pn0, dy = X1-pn1, dz = X2-pn2;
    ws[WS_PR + (size_t)(n*NS+u)*3 + 0] = dx;
    ws[WS_PR + (size_t)(n*NS+u)*3 + 1] = dy;
    ws[WS_PR + (size_t)(n*NS+u)*3 + 2] = dz;
    const float dist = sqrtf(dx*dx + dy*dy + dz*dz + 1e-12f);
    float dmx = dist, dsm = dist, S0 = X0, S1 = X1, S2 = X2;
    #pragma unroll
    for (int off = 1; off < 16; off <<= 1) {
        dmx = fmaxf(dmx, __shfl_xor(dmx, off, 16));
        dsm += __shfl_xor(dsm, off, 16);
        S0 += __shfl_xor(S0, off, 16);
        S1 += __shfl_xor(S1, off, 16);
        S2 += __shfl_xor(S2, off, 16);
    }
    if (u == 0) {
        ws[WS_GDIS + n] = dmx;
        float m0 = S0*(1.f/16.f), m1 = S1*(1.f/16.f), m2 = S2*(1.f/16.f);
        float* g = ws + WS_GEO9 + (size_t)n*9;
        g[0] = m0-pn0; g[1] = m1-pn1; g[2] = m2-pn2;
        g[3] = m0; g[4] = m1; g[5] = m2;
        g[6] = pn0; g[7] = pn1; g[8] = pn2;
        red[w] = dsm; red[16+w] = dmx;
    }
    __syncthreads();
    if (t == 0) {
        float ds = 0.f, dm = 0.f;
        #pragma unroll
        for (int i = 0; i < 16; ++i) { ds += red[i]; dm = fmaxf(dm, red[16+i]); }
        atomicAdd(&ws[WS_STATS + 0], ds);
        atomicMax((int*)(ws + WS_STATS + 1), __float_as_int(dm));  // dist>=0
    }
}

// ---- K1b: factored BN stats ----
__global__ __launch_bounds__(256) void k1b_stats(float* __restrict__ ws)
{
    __shared__ float Xs[128][48];
    __shared__ float Ss[128][3];
    __shared__ float a3p[9][16];
    const int t = threadIdx.x;
    const int c0 = blockIdx.x * 128;
    for (int e = t; e < 1536; e += 256) {
        int r = e/12, q = e%12;
        *(float4*)&Xs[r][q*4] = *(const float4*)(ws + WS_KNN + (size_t)(c0+r)*48 + q*4);
    }
    __syncthreads();
    if (t < 128) {
        float s0 = 0.f, s1 = 0.f, s2 = 0.f;
        #pragma unroll
        for (int j = 0; j < 16; ++j) { s0 += Xs[t][3*j]; s1 += Xs[t][3*j+1]; s2 += Xs[t][3*j+2]; }
        Ss[t][0] = s0; Ss[t][1] = s1; Ss[t][2] = s2;
    }
    __syncthreads();
    {
        float acc[9];
        #pragma unroll
        for (int q = 0; q < 9; ++q) acc[q] = 0.f;
        for (int i = 0; i < 128; ++i) {
            int e = t;
            #pragma unroll
            for (int q = 0; q < 9; ++q) {
                int a = e/48, b = e%48;
                acc[q] += Xs[i][a] * Xs[i][b];
                e += 256;
            }
        }
        int e = t;
        #pragma unroll
        for (int q = 0; q < 9; ++q) { atomicAdd(&ws[WS_STATS + 50 + e], acc[q]); e += 256; }
    }
    if (t < 144) {
        int a = t/3, d = t%3;
        float s = 0.f;
        for (int i = 0; i < 128; ++i) s += Xs[i][a] * Ss[i][d];
        atomicAdd(&ws[WS_STATS + 2354 + t], s);
    }
    if (t < 144) {
        int q = t >> 4, part = t & 15;
        int d = q/3, e2 = q%3;
        float s = 0.f;
        for (int i = part*8; i < part*8 + 8; ++i) {
            #pragma unroll
            for (int j = 0; j < 16; ++j) s += Xs[i][3*j+d] * Xs[i][3*j+e2];
        }
        a3p[q][part] = s;
    }
    if (t < 48) {
        float s = 0.f;
        for (int i = 0; i < 128; ++i) s += Xs[i][t];
        atomicAdd(&ws[WS_STATS + 2 + t], s);
    }
    if (t < 3) {
        float s = 0.f;
        for (int i = 0; i < 128; ++i) s += Ss[i][t];
        atomicAdd(&ws[WS_STATS + 2507 + t], s);
    }
    __syncthreads();
    if (t < 9) {
        float s = 0.f;
        #pragma unroll
        for (int i = 0; i < 16; ++i) s += a3p[t][i];
        atomicAdd(&ws[WS_STATS + 2498 + t], s);
    }
}

// ---- K2: vol vector + BN fold (M2 reconstructed from factored stats) ----
__global__ __launch_bounds__(256) void k2_fold(
    const float* __restrict__ posW1, const float* __restrict__ posB1,
    const float* __restrict__ gamma, const float* __restrict__ beta,
    const float* __restrict__ gCW, const float* __restrict__ gCb,
    float* __restrict__ ws)
{
    __shared__ float M2n[48][48];
    __shared__ float pmean[48];
    __shared__ float Wc[48][193];
    const int t = threadIdx.x;
    const int i = blockIdx.x;
    for (int e = t; e < 2304; e += 256) {
        int a = e/48, b = e%48, ad = a%3, bd = b%3;
        float v = 16.f*ws[WS_STATS + 50 + e]
                - ws[WS_STATS + 2354 + a*3 + bd]
                - ws[WS_STATS + 2354 + b*3 + ad]
                + ws[WS_STATS + 2498 + ad*3 + bd];
        M2n[a][b] = v * (1.f/(float)MTOT);
    }
    if (t < 48) pmean[t] = (16.f*ws[WS_STATS + 2 + t] - ws[WS_STATS + 2507 + t%3])
                           * (1.f/(float)MTOT);
    if (t < DD) {
        for (int k = 0; k < 48; ++k) Wc[k][t] = posW1[(size_t)(i*48 + k)*DD + t];
    }
    __syncthreads();
    if (i == 0 && t < DD) {
        float dsum = ws[WS_STATS + 0];
        float dmax = __int_as_float(((const int*)(ws + WS_STATS))[1]);
        float vol = (dsum * (1.f/(float)MTOT)) / (dmax + 1e-8f);
        ws[WS_VOLV + t] = vol * gCW[t] + gCb[t];
    }
    if (t < DD) {
        float mu0 = 0.f;
        #pragma unroll 8
        for (int k = 0; k < 48; ++k) mu0 += pmean[k] * Wc[k][t];
        float e2 = 0.f;
        for (int a2 = 0; a2 < 48; ++a2) {
            float inner = 0.f;
            #pragma unroll 8
            for (int b2 = 0; b2 < 48; ++b2) inner += M2n[a2][b2] * Wc[b2][t];
            e2 += Wc[a2][t] * inner;
        }
        float var = fmaxf(e2 - mu0*mu0, 0.f);
        float as = rsqrtf(var + 1e-5f) * gamma[i*DD + t];
        ws[WS_AB + i*DD + t]       = as;
        ws[WS_AB + 576 + i*DD + t] = beta[i*DD + t] - mu0 * as;   // h'=relu(acc*as+bb)
    }
}

// ---- K_prop MFMA ----
__global__ __launch_bounds__(256) void k_prop_mfma(
    const float* __restrict__ x, const int* __restrict__ knn,
    const float* __restrict__ propW, const float* __restrict__ propB,
    float* __restrict__ ws)
{
    __shared__ ushort_t As[64*40];
    __shared__ ushort_t Bs[192*40];
    __shared__ float prs[64*3];
    __shared__ float W3[3*192];
    __shared__ int idx64[64];
    const int t = threadIdx.x;
    const int mbase = blockIdx.x * 64;
    const ushort_t* xb = (const ushort_t*)(ws + WS_XB);
    const ushort_t* pwt = (const ushort_t*)(ws + WS_PROPWT);
    if (t < 64) idx64[t] = knn[mbase + t];
    for (int e = t; e < 576; e += 256) W3[e] = propW[(size_t)(192 + e/192)*DD + (e % 192)];
    for (int e = t; e < 192; e += 256) prs[e] = ws[WS_PR + (size_t)mbase*3 + e];
    const int wave = t >> 6, lane = t & 63, m = lane & 15, quad = lane >> 4;
    f32x4 acc[12];
    #pragma unroll
    for (int nt = 0; nt < 12; ++nt) acc[nt] = (f32x4){0.f,0.f,0.f,0.f};
    for (int ks = 0; ks < 6; ++ks) {
        const int k0 = ks*32;
        __syncthreads();
        {   int r = t >> 2, seg = t & 3;
            *(uint4*)&As[r*40 + seg*8] = *(const uint4*)(xb + (size_t)idx64[r]*192 + k0 + seg*8);
        }
        for (int e = t; e < 768; e += 256) {
            int n = e >> 2, seg = e & 3;
            *(uint4*)&Bs[n*40 + seg*8] = *(const uint4*)(pwt + (size_t)n*192 + k0 + seg*8);
        }
        __syncthreads();
        short8 a = *(const short8*)&As[(wave*16 + m)*40 + quad*8];
        #pragma unroll
        for (int nt = 0; nt < 12; ++nt) {
            short8 b = *(const short8*)&Bs[(nt*16 + m)*40 + quad*8];
            acc[nt] = __builtin_amdgcn_mfma_f32_16x16x32_bf16(a, b, acc[nt], 0, 0, 0);
        }
    }
    const int n = blockIdx.x*4 + wave;
    #pragma unroll
    for (int nt = 0; nt < 12; ++nt) {
        int col = nt*16 + m;
        float bv = propB[col];
        float w0 = W3[col], w1 = W3[192 + col], w2 = W3[384 + col];
        float s = 0.f;
        #pragma unroll
        for (int reg = 0; reg < 4; ++reg) {
            int j = wave*16 + quad*4 + reg;
            float v = acc[nt][reg] + prs[j*3+0]*w0 + prs[j*3+1]*w1 + prs[j*3+2]*w2 + bv;
            s += fmaxf(v, 0.f);
        }
        s += __shfl_xor(s, 16);
        s += __shfl_xor(s, 32);
        if (quad == 0)
            ws[WS_X1 + (size_t)n*DD + col] = x[(size_t)n*DD + col] + s * (1.f/16.f);
    }
}

// ---- generic bf16 MFMA GEMM ----
__global__ __launch_bounds__(256) void gemm_mfma(
    const ushort_t* __restrict__ A, const ushort_t* __restrict__ Bt,
    const float* __restrict__ bias, float* __restrict__ Cf,
    ushort_t* __restrict__ Cb, int N)
{
    __shared__ ushort_t As[64*40];
    __shared__ ushort_t Bs[64*40];
    const int t = threadIdx.x;
    const int wave = t >> 6, lane = t & 63, m = lane & 15, quad = lane >> 4;
    const int rowBase = blockIdx.x * 64, colBase = blockIdx.y * 64;
    f32x4 acc[4];
    #pragma unroll
    for (int nt = 0; nt < 4; ++nt) acc[nt] = (f32x4){0.f,0.f,0.f,0.f};
    for (int ks = 0; ks < 6; ++ks) {
        __syncthreads();
        {   int r = t >> 2, seg = t & 3;
            *(uint4*)&As[r*40 + seg*8] = *(const uint4*)(A + (size_t)(rowBase + r)*192 + ks*32 + seg*8);
            *(uint4*)&Bs[r*40 + seg*8] = *(const uint4*)(Bt + (size_t)(colBase + r)*192 + ks*32 + seg*8);
        }
        __syncthreads();
        short8 a = *(const short8*)&As[(wave*16 + m)*40 + quad*8];
        #pragma unroll
        for (int nt = 0; nt < 4; ++nt) {
            short8 b = *(const short8*)&Bs[(nt*16 + m)*40 + quad*8];
            acc[nt] = __builtin_amdgcn_mfma_f32_16x16x32_bf16(a, b, acc[nt], 0, 0, 0);
        }
    }
    #pragma unroll
    for (int nt = 0; nt < 4; ++nt) {
        int col = colBase + nt*16 + m;
        float bv = bias ? bias[col] : 0.f;
        #pragma unroll
        for (int reg = 0; reg < 4; ++reg) {
            int row = rowBase + wave*16 + quad*4 + reg;
            float v = acc[nt][reg] + bv;
            if (Cf) Cf[(size_t)row*N + col] = v;
            else    Cb[(size_t)row*N + col] = f2bf(v);
        }
    }
}

// ---- K3a: keypoint attention + U assembly (writes bf16 UB) ----
__global__ __launch_bounds__(256) void k3a(
    const float* __restrict__ p, const float* __restrict__ kn,
    const float* __restrict__ deW1, const float* __restrict__ deB1,
    const float* __restrict__ deW2, const float* __restrict__ deB2,
    const float* __restrict__ kpW, const float* __restrict__ kpB,
    const float* __restrict__ gAW, const float* __restrict__ gAb,
    const float* __restrict__ gBW, const float* __restrict__ gBb,
    float* __restrict__ ws)
{
    __shared__ float Wd[48][196];
    __shared__ float innr[KSPN][49];
    __shared__ float df[KSPN][193];
    __shared__ float kd[KSPN];
    __shared__ float scl[KSPN];
    ushort_t* ub = (ushort_t*)(ws + WS_UB);
    const int t = threadIdx.x;
    for (int e = t; e < 48*48; e += 256) {
        int w = e / 48, cq = e - w*48;
        *(float4*)&Wd[w][cq*4] = *(const float4*)(deW2 + (size_t)w*DD + cq*4);
    }
    const int kap = t >> 4, u = t & 15, c0 = u*12;
    for (int it = 0; it < 16; ++it) {
        const int n = blockIdx.x*16 + it;
        __syncthreads();
        if (t < KSPN) {
            float dx = p[n*3]-kn[t*3], dy = p[n*3+1]-kn[t*3+1], dz = p[n*3+2]-kn[t*3+2];
            kd[t] = sqrtf(dx*dx + dy*dy + dz*dz + 1e-12f);
        }
        __syncthreads();
        for (int e = t; e < KSPN*48; e += 256) {
            int r = e / 48, j = e - r*48;
            innr[r][j] = fmaxf(kd[r]*deW1[j] + deB1[j], 0.f);
        }
        __syncthreads();
        float a12[12];
        #pragma unroll
        for (int m = 0; m < 12; ++m) a12[m] = deB2[c0 + m];
        for (int w = 0; w < 48; ++w) {
            float av = innr[kap][w];
            #pragma unroll
            for (int m = 0; m < 12; ++m) a12[m] += av * Wd[w][c0 + m];
        }
        float ksc = 0.f;
        #pragma unroll
        for (int m = 0; m < 12; ++m) { df[kap][c0 + m] = a12[m]; ksc += a12[m]*kpW[c0 + m]; }
        #pragma unroll
        for (int off = 1; off < 16; off <<= 1) ksc += __shfl_xor(ksc, off, 16);
        if (u == 0) scl[kap] = ksc + kpB[0];
        __syncthreads();
        if (t < KSPN) {
            float v = scl[t], mx = v;
            #pragma unroll
            for (int off = 1; off < 16; off <<= 1) mx = fmaxf(mx, __shfl_xor(mx, off, 16));
            float e = expf(v - mx);
            float sm = e;
            #pragma unroll
            for (int off = 1; off < 16; off <<= 1) sm += __shfl_xor(sm, off, 16);
            scl[t] = e / sm;
        }
        __syncthreads();
        if (t < DD) {
            float dfeat = 0.f;
            #pragma unroll
            for (int k2 = 0; k2 < KSPN; ++k2) dfeat += scl[k2]*df[k2][t];
            float uval = ws[WS_X1 + (size_t)n*DD + t] + gAb[t] + gBb[t] + ws[WS_VOLV + t] + dfeat;
            uval += ws[WS_GDIS + n] * gBW[t];
            #pragma unroll
            for (int kk = 0; kk < 9; ++kk) uval += ws[WS_GEO9 + n*9 + kk] * gAW[kk*DD + t];
            ub[(size_t)n*DD + t] = f2bf(uval);
        }
    }
}

// ---- K_attn_fused: dqdk + scores + softmax + attn@v + pv + CTR, 8 windows/block ----
__global__ __launch_bounds__(256) void k_attn_fused(
    const int* __restrict__ knn,
    const float* __restrict__ posW2, const float* __restrict__ posB2,
    float* __restrict__ ws)
{
    __shared__ ushort_t posb[128*72];   // bf16 pos rows, K pad 64, stride 72
    __shared__ float rqs[8*6*192];      // rq per i; later wsum
    __shared__ float qk[8*192];         // q0 (i=0) / k0 (i=1), reloaded per i
    __shared__ float scb[8*192];        // sc[w][i(2)][h(6)][j(16)]
    __shared__ float dqk[8*96];         // dqk[w][h][j]
    __shared__ float attns[8*96];
    __shared__ float Xl[8][48];
    __shared__ int idxs[128];
    const int t = threadIdx.x;
    const int nb = blockIdx.x * 8;
    ushort_t* ctrb = (ushort_t*)(ws + WS_CTRB);
    if (t < 128) idxs[t] = knn[(nb + (t >> 4))*NS + (t & 15)];
    for (int e = t; e < 384; e += 256) {
        int w = e/48, k = e%48;
        Xl[w][k] = ws[WS_KNN + (size_t)(nb+w)*48 + k];
    }
    __syncthreads();
    for (int e = t; e < 128*64; e += 256) {   // build bf16 pos tile
        int j = e >> 6, k = e & 63;
        int w = j >> 4, jl = j & 15;
        float v = (k < 48) ? (Xl[w][k] - Xl[w][jl*3 + (k % 3)]) : 0.f;
        posb[j*72 + k] = f2bf(v);
    }
    const int wave = t >> 6, lane = t & 63, m = lane & 15, quad = lane >> 4;
    const ushort_t* w1t = (const ushort_t*)(ws + WS_W1T);
    // ---- i = 0,1: rq + MFMA H + fused contraction -> scb ----
    for (int i = 0; i < 2; ++i) {
        __syncthreads();   // posb built (i=0) / prior rqs,qk readers done (i=1)
        for (int e = t; e < 8*192; e += 256) {
            int w = e/192, c = e%192;
            qk[e] = ws[WS_QKV + (size_t)idxs[w*16]*576 + i*192 + c];
        }
        __syncthreads();
        if (t < 192) {     // rq: W2 row t (global) x qk broadcast
            const float* Wrow = posW2 + (size_t)i*DD*DD + (size_t)t*DD;
            for (int h = 0; h < 6; ++h) {
                float4 wr[8];
                #pragma unroll
                for (int q = 0; q < 8; ++q) wr[q] = *(const float4*)(Wrow + h*32 + q*4);
                float a[8];
                #pragma unroll
                for (int w = 0; w < 8; ++w) a[w] = 0.f;
                #pragma unroll
                for (int q = 0; q < 8; ++q) {
                    #pragma unroll
                    for (int d = 0; d < 4; ++d) {
                        float wv = (&wr[q].x)[d];
                        int c = h*32 + q*4 + d;
                        #pragma unroll
                        for (int w = 0; w < 8; ++w) a[w] += wv * qk[w*192 + c];
                    }
                }
                #pragma unroll
                for (int w = 0; w < 8; ++w) rqs[(w*6 + h)*192 + t] = a[w];
            }
        }
        __syncthreads();
        short8 afr[2][2];
        #pragma unroll
        for (int mt = 0; mt < 2; ++mt)
            #pragma unroll
            for (int ks = 0; ks < 2; ++ks)
                afr[mt][ks] = *(const short8*)&posb[((wave*2 + mt)*16 + m)*72 + ks*32 + quad*8];
        float s[48];       // [mt(2)][reg(4)][h(6)]
        #pragma unroll
        for (int e = 0; e < 48; ++e) s[e] = 0.f;
        for (int nt = 0; nt < 12; ++nt) {
            f32x4 acc0 = (f32x4){0.f,0.f,0.f,0.f};
            f32x4 acc1 = (f32x4){0.f,0.f,0.f,0.f};
            #pragma unroll
            for (int ks = 0; ks < 2; ++ks) {
                short8 b = *(const short8*)(w1t + ((size_t)(i*192 + nt*16 + m)*64 + ks*32 + quad*8));
                acc0 = __builtin_amdgcn_mfma_f32_16x16x32_bf16(afr[0][ks], b, acc0, 0, 0, 0);
                acc1 = __builtin_amdgcn_mfma_f32_16x16x32_bf16(afr[1][ks], b, acc1, 0, 0, 0);
            }
            int kk = nt*16 + m;
            float as = ws[WS_AB + i*DD + kk];
            float bb = ws[WS_AB + 576 + i*DD + kk];
            float h0[4], h1[4];
            #pragma unroll
            for (int reg = 0; reg < 4; ++reg) {
                h0[reg] = fmaxf(acc0[reg]*as + bb, 0.f);
                h1[reg] = fmaxf(acc1[reg]*as + bb, 0.f);
            }
            #pragma unroll
            for (int h = 0; h < 6; ++h) {
                float r0 = rqs[((wave*2 + 0)*6 + h)*192 + kk];
                float r1 = rqs[((wave*2 + 1)*6 + h)*192 + kk];
                #pragma unroll
                for (int reg = 0; reg < 4; ++reg) {
                    s[reg*6 + h]      += h0[reg]*r0;
                    s[24 + reg*6 + h] += h1[reg]*r1;
                }
            }
        }
        #pragma unroll
        for (int e = 0; e < 48; ++e) {
            float v = s[e];
            v += __shfl_xor(v, 1, 16); v += __shfl_xor(v, 2, 16);
            v += __shfl_xor(v, 4, 16); v += __shfl_xor(v, 8, 16);
            s[e] = v;
        }
        if (m == 0) {
            #pragma unroll
            for (int mt = 0; mt < 2; ++mt)
                #pragma unroll
                for (int reg = 0; reg < 4; ++reg) {
                    int w = wave*2 + mt, j = quad*4 + reg;
                    #pragma unroll
                    for (int h = 0; h < 6; ++h)
                        scb[w*192 + i*96 + h*16 + j] = s[mt*24 + reg*6 + h];
                }
        }
    }
    // ---- dqk dots: thread -> (w, j, half); 3 full head dots each ----
    {
        const int w = t >> 5, r = t & 31, j = r >> 1, half = r & 1;
        const float* krow = ws + WS_QKV + (size_t)idxs[w*16 + j]*576 + 192 + half*96;
        const float* qrow = ws + WS_QKV + (size_t)idxs[w*16]*576 + half*96;
        float hd[3] = {0.f, 0.f, 0.f};
        #pragma unroll
        for (int q = 0; q < 24; ++q) {
            float4 kv = *(const float4*)(krow + q*4);
            float4 qv = *(const float4*)(qrow + q*4);
            hd[q >> 3] += kv.x*qv.x + kv.y*qv.y + kv.z*qv.z + kv.w*qv.w;
        }
        dqk[w*96 + (half*3+0)*16 + j] = hd[0];
        dqk[w*96 + (half*3+1)*16 + j] = hd[1];
        dqk[w*96 + (half*3+2)*16 + j] = hd[2];
    }
    __syncthreads();   // dqk+scb ready; also all rqs reads (i=1) done
    // ---- softmax over j per (w,h): 768 entries in 3 chunks ----
    {
        const float scale = 0.17677669529663687f;  // 32^-0.5
        #pragma unroll
        for (int c = 0; c < 3; ++c) {
            int e = c*256 + t;
            int row = e >> 4, j = e & 15, w = row / 6, h = row % 6;
            float z = (dqk[e] + scb[w*192 + h*16 + j] + scb[w*192 + 96 + h*16 + j]) * scale;
            float mx = z;
            #pragma unroll
            for (int off = 1; off < 16; off <<= 1) mx = fmaxf(mx, __shfl_xor(mx, off, 16));
            float ex = expf(z - mx);
            float sm = ex;
            #pragma unroll
            for (int off = 1; off < 16; off <<= 1) sm += __shfl_xor(sm, off, 16);
            attns[w*96 + h*16 + j] = ex / sm;
        }
    }
    __syncthreads();   // attns ready
    // ---- phase E: ctr1[w] = (attn @ v)[c=t] in registers ----
    float ctr1[8];
    if (t < DD) {
        const int h = t >> 5;
        #pragma unroll
        for (int w = 0; w < 8; ++w) {
            float sv = 0.f;
            #pragma unroll
            for (int j = 0; j < NS; ++j)
                sv += attns[w*96 + h*16 + j] * ws[WS_QKV + (size_t)idxs[w*16 + j]*576 + 384 + t];
            ctr1[w] = sv;
        }
    }
    // ---- phase F: H2 MFMA + attn-weighted reduce -> wsum (rqs region) ----
    {
        float* wsum = rqs;
        const int w0 = wave*2, w1 = wave*2 + 1;
        short8 afr[2][2];
        #pragma unroll
        for (int mt = 0; mt < 2; ++mt)
            #pragma unroll
            for (int ks = 0; ks < 2; ++ks)
                afr[mt][ks] = *(const short8*)&posb[((wave*2 + mt)*16 + m)*72 + ks*32 + quad*8];
        for (int nt = 0; nt < 12; ++nt) {
            f32x4 acc0 = (f32x4){0.f,0.f,0.f,0.f};
            f32x4 acc1 = (f32x4){0.f,0.f,0.f,0.f};
            #pragma unroll
            for (int ks = 0; ks < 2; ++ks) {
                short8 b = *(const short8*)(w1t + ((size_t)(2*192 + nt*16 + m)*64 + ks*32 + quad*8));
                acc0 = __builtin_amdgcn_mfma_f32_16x16x32_bf16(afr[0][ks], b, acc0, 0, 0, 0);
                acc1 = __builtin_amdgcn_mfma_f32_16x16x32_bf16(afr[1][ks], b, acc1, 0, 0, 0);
            }
            int kk = nt*16 + m;
            float as = ws[WS_AB + 2*DD + kk];
            float bb = ws[WS_AB + 576 + 2*DD + kk];
            float h0[4], h1[4];
            #pragma unroll
            for (int reg = 0; reg < 4; ++reg) {
                h0[reg] = fmaxf(acc0[reg]*as + bb, 0.f);
                h1[reg] = fmaxf(acc1[reg]*as + bb, 0.f);
            }
            #pragma unroll
            for (int h = 0; h < 6; ++h) {
                float p0 = 0.f, p1 = 0.f;
                #pragma unroll
                for (int reg = 0; reg < 4; ++reg) {
                    int j = quad*4 + reg;
                    p0 += attns[w0*96 + h*16 + j] * h0[reg];
                    p1 += attns[w1*96 + h*16 + j] * h1[reg];
                }
                p0 += __shfl_xor(p0, 16); p0 += __shfl_xor(p0, 32);
                p1 += __shfl_xor(p1, 16); p1 += __shfl_xor(p1, 32);
                if (quad == 0) {
                    wsum[(w0*6 + h)*192 + kk] = p0;
                    wsum[(w1*6 + h)*192 + kk] = p1;
                }
            }
        }
    }
    __syncthreads();   // wsum ready
    // ---- pv = wsum @ W2_2 via W2T rows; CTR = ctr1 + pv + b2 ----
    if (t < DD) {
        const float* wsum = rqs;
        const int h = t >> 5;
        float pvacc[8];
        #pragma unroll
        for (int w = 0; w < 8; ++w) pvacc[w] = 0.f;
        const float* wrow = ws + WS_W2T + (size_t)t*DD;
        for (int k4 = 0; k4 < 48; ++k4) {
            float4 wv = *(const float4*)(wrow + k4*4);
            #pragma unroll
            for (int w = 0; w < 8; ++w) {
                const float* av = &wsum[(w*6 + h)*192 + k4*4];
                pvacc[w] += av[0]*wv.x + av[1]*wv.y + av[2]*wv.z + av[3]*wv.w;
            }
        }
        float b2 = posB2[2*DD + t];
        #pragma unroll
        for (int w = 0; w < 8; ++w)
            ctrb[(size_t)(nb+w)*DD + t] = f2bf(ctr1[w] + pvacc[w] + b2);
    }
}

extern "C" void kernel_launch(void* const* d_in, const int* in_sizes, int n_in,
                              void* d_out, int out_size, void* d_ws, size_t ws_size,
                              hipStream_t stream)
{
    const float* p     = (const float*)d_in[0];
    const float* x     = (const float*)d_in[1];
    const int*   knn   = (const int*)  d_in[2];
    const float* Wqkv  = (const float*)d_in[3];
    const float* Wproj = (const float*)d_in[4];
    const float* bproj = (const float*)d_in[5];
    const float* propW = (const float*)d_in[6];
    const float* propB = (const float*)d_in[7];
    const float* gAW   = (const float*)d_in[8];
    const float* gAb   = (const float*)d_in[9];
    const float* gBW   = (const float*)d_in[10];
    const float* gBb   = (const float*)d_in[11];
    const float* gCW   = (const float*)d_in[12];
    const float* gCb   = (const float*)d_in[13];
    const float* posW1 = (const float*)d_in[14];
    const float* posB1 = (const float*)d_in[15];
    const float* gamma = (const float*)d_in[16];
    const float* beta  = (const float*)d_in[17];
    const float* posW2 = (const float*)d_in[18];
    const float* posB2 = (const float*)d_in[19];
    const float* kn    = (const float*)d_in[20];
    const float* deW1  = (const float*)d_in[21];
    const float* deB1  = (const float*)d_in[22];
    const float* deW2  = (const float*)d_in[23];
    const float* deB2  = (const float*)d_in[24];
    const float* kpW   = (const float*)d_in[25];
    const float* kpB   = (const float*)d_in[26];
    const float* fusW  = (const float*)d_in[27];
    const float* fusB  = (const float*)d_in[28];
    float* ws   = (float*)d_ws;
    float* outp = (float*)d_out;

    hipLaunchKernelGGL(k_init, dim3(10), dim3(256), 0, stream, ws);
    hipLaunchKernelGGL(k_w2t, dim3(144), dim3(256), 0, stream, posW2, ws);
    hipLaunchKernelGGL(k_prep, dim3(1008), dim3(256), 0, stream,
                       propW, Wqkv, fusW, Wproj, posW1, ws);
    hipLaunchKernelGGL(k_castx, dim3(NP*DD/256), dim3(256), 0, stream, x, ws);
    hipLaunchKernelGGL(k1a_geom, dim3(NP/16), dim3(256), 0, stream, p, knn, ws);
    hipLaunchKernelGGL(k1b_stats, dim3(NP/128), dim3(256), 0, stream, ws);
    hipLaunchKernelGGL(k2_fold, dim3(3), dim3(256), 0, stream,
                       posW1, posB1, gamma, beta, gCW, gCb, ws);
    hipLaunchKernelGGL(k_prop_mfma, dim3(MTOT/64), dim3(256), 0, stream,
                       x, knn, propW, propB, ws);
    hipLaunchKernelGGL(k3a, dim3(NP/16), dim3(256), 0, stream,
                       p, kn, deW1, deB1, deW2, deB2, kpW, kpB, gAW, gAb, gBW, gBb, ws);
    // X2B = bf16(UB @ fusW + fusB)
    hipLaunchKernelGGL(gemm_mfma, dim3(NP/64, 3), dim3(256), 0, stream,
                       (const ushort_t*)(ws + WS_UB), (const ushort_t*)(ws + WS_FUSWT),
                       fusB, (float*)nullptr, (ushort_t*)(ws + WS_X2B), DD);
    // QKV = X2B @ Wqkv (fp32 out)
    hipLaunchKernelGGL(gemm_mfma, dim3(NP/64, 9), dim3(256), 0, stream,
                       (const ushort_t*)(ws + WS_X2B), (const ushort_t*)(ws + WS_QKVT),
                       (const float*)nullptr, ws + WS_QKV, (ushort_t*)nullptr, 576);
    hipLaunchKernelGGL(k_attn_fused, dim3(NP/8), dim3(256), 0, stream,
                       knn, posW2, posB2, ws);
    // OUT = CTRB @ Wproj + bproj (fp32 out)
    hipLaunchKernelGGL(gemm_mfma, dim3(NP/64, 3), dim3(256), 0, stream,
                       (const ushort_t*)(ws + WS_CTRB), (const ushort_t*)(ws + WS_PROJWT),
                       bproj, outp, (ushort_t*)nullptr, DD);
}

// Round 10
// 663.896 us; speedup vs baseline: 12.6538x; 1.1573x over previous
//
#include <hip/hip_runtime.h>
#include <math.h>

#define NP 16384
#define DD 192
#define NS 16
#define KSPN 16
#define MTOT (NP*NS)

typedef unsigned short ushort_t;
typedef __attribute__((ext_vector_type(8))) short short8;
typedef __attribute__((ext_vector_type(4))) float f32x4;

__device__ __forceinline__ ushort_t f2bf(float f) {
    union { float f; unsigned int u; } v; v.f = f;
    return (ushort_t)((v.u + 0x7FFFu + ((v.u >> 16) & 1u)) >> 16);
}
__device__ __forceinline__ float bf2f(ushort_t u) {
    return __uint_as_float(((unsigned int)u) << 16);
}

// ws float offsets
#define WS_KNN   0                         // NP*48   knn_xyz
#define WS_PR    (WS_KNN + NP*48)          // MTOT*3  p_r per window row
#define WS_GEO9  (WS_PR + MTOT*3)          // NP*9
#define WS_GDIS  (WS_GEO9 + NP*9)          // NP
// STATS: [0]=dsum [1]=dmax(bits) [2..50)=sumX [50..2354)=A1 [2354..2498)=A2
//        [2498..2507)=A3 [2507..2510)=sumS
#define WS_STATS (WS_GDIS + NP)
#define WS_VOLV  (WS_STATS + 2512)         // 192
#define WS_AB    (WS_VOLV + DD)            // a[3][192] | bb[3][192] = 1152
#define WS_X1    (WS_AB + 1152)            // NP*192 post-propagate (consumed by k3a)
#define WS_U     (WS_X1 + NP*DD)           // NP*192: CTRB (bf16) after fused attn
#define WS_X2    (WS_U + NP*DD)            // NP*192: X2B (bf16, written by fus gemm)
#define WS_QKV   (WS_X2 + NP*DD)           // NP*576 bf16 (uses half the region)
#define WS_SC    (WS_QKV + NP*576)         // region: XB overlay (bf16 x)
#define WS_ATTN  (WS_SC + NP*DD)           // region: UB overlay (bf16 U)
#define WS_W2T   (WS_ATTN + NP*96)         // 192*192 transposed posW2[2] fp32
#define WS_PROPWT (WS_W2T + 36864)         // 18432 floats (bf16 transposed propW[:192])
#define WS_QKVT  (WS_PROPWT + 18432)       // 55296
#define WS_FUSWT (WS_QKVT + 55296)         // 18432
#define WS_PROJWT (WS_FUSWT + 18432)       // 18432
#define WS_W1T   (WS_PROJWT + 18432)       // 3*192*64 bf16 = 18432 floats (K pad 64)
#define WS_DEW2T (WS_W1T + 18432)          // 192*64 bf16 = 6144 floats (deW2 transposed, K pad 64)
// overlays (bf16 arrays in dead-interval regions):
#define WS_XB    WS_SC
#define WS_UB    WS_ATTN
#define WS_X2B   WS_X2
#define WS_CTRB  WS_U

__global__ __launch_bounds__(256) void k_init(float* __restrict__ ws) {
    int t = blockIdx.x * 256 + threadIdx.x;
    if (t < 2512) ws[WS_STATS + t] = 0.f;
}

// ---- tiny: W2T[c][kk] = posW2[2][kk][c] (fp32) ----
__global__ __launch_bounds__(256) void k_w2t(const float* __restrict__ posW2,
                                             float* __restrict__ ws) {
    int e = blockIdx.x*256 + threadIdx.x;      // e = c*192 + kk
    int c = e / DD, kk = e - c*DD;
    ws[WS_W2T + e] = posW2[(size_t)(2*DD + kk)*DD + c];
}

// ---- prep: bf16 transposed weight copies (n-major, k-contiguous) ----
__global__ __launch_bounds__(256) void k_prep(
    const float* __restrict__ propW, const float* __restrict__ Wqkv,
    const float* __restrict__ fusW, const float* __restrict__ Wproj,
    const float* __restrict__ posW1, const float* __restrict__ deW2,
    float* __restrict__ ws)
{
    int e = blockIdx.x*256 + threadIdx.x;
    ushort_t* pwt = (ushort_t*)(ws + WS_PROPWT);
    ushort_t* qkt = (ushort_t*)(ws + WS_QKVT);
    ushort_t* fwt = (ushort_t*)(ws + WS_FUSWT);
    ushort_t* pjt = (ushort_t*)(ws + WS_PROJWT);
    ushort_t* w1t = (ushort_t*)(ws + WS_W1T);
    ushort_t* dwt = (ushort_t*)(ws + WS_DEW2T);
    if (e < 36864) {
        int n = e/192, k = e - n*192;
        pwt[e] = f2bf(propW[(size_t)k*192 + n]);
    } else if (e < 147456) {
        int r = e - 36864; int n = r/192, k = r - n*192;
        qkt[r] = f2bf(Wqkv[(size_t)k*576 + n]);
    } else if (e < 184320) {
        int r = e - 147456; int n = r/192, k = r - n*192;
        fwt[r] = f2bf(fusW[(size_t)k*192 + n]);
    } else if (e < 221184) {
        int r = e - 184320; int n = r/192, k = r - n*192;
        pjt[r] = f2bf(Wproj[(size_t)k*192 + n]);
    } else if (e < 258048) {
        int r = e - 221184;
        int i = r / 12288, rem = r - i*12288;
        int n = rem / 64, k = rem - n*64;
        w1t[r] = (k < 48) ? f2bf(posW1[(size_t)(i*48 + k)*DD + n]) : (ushort_t)0;
    } else if (e < 270336) {
        int r = e - 258048;
        int n = r / 64, k = r - n*64;
        dwt[r] = (k < 48) ? f2bf(deW2[(size_t)k*DD + n]) : (ushort_t)0;
    }
}

// ---- cast x -> bf16 ----
__global__ __launch_bounds__(256) void k_castx(const float* __restrict__ x,
                                               float* __restrict__ ws) {
    int e = blockIdx.x*256 + threadIdx.x;
    ((ushort_t*)(ws + WS_XB))[e] = f2bf(x[e]);
}

// ---- K1a: per-(point,neighbor) geometry ----
__global__ __launch_bounds__(256) void k1a_geom(
    const float* __restrict__ p, const int* __restrict__ knn,
    float* __restrict__ ws)
{
    __shared__ float red[32];
    const int t = threadIdx.x;
    const int w = t >> 4, u = t & 15;
    const int n = blockIdx.x*16 + w;
    const int idx = knn[n*NS + u];
    const float X0 = p[idx*3+0], X1 = p[idx*3+1], X2 = p[idx*3+2];
    const float pn0 = p[n*3+0], pn1 = p[n*3+1], pn2 = p[n*3+2];
    ws[WS_KNN + (size_t)n*48 + u*3 + 0] = X0;
    ws[WS_KNN + (size_t)n*48 + u*3 + 1] = X1;
    ws[WS_KNN + (size_t)n*48 + u*3 + 2] = X2;
    const float dx = X0-pn0, dy = X1-pn1, dz = X2-pn2;
    ws[WS_PR + (size_t)(n*NS+u)*3 + 0] = dx;
    ws[WS_PR + (size_t)(n*NS+u)*3 + 1] = dy;
    ws[WS_PR + (size_t)(n*NS+u)*3 + 2] = dz;
    const float dist = sqrtf(dx*dx + dy*dy + dz*dz + 1e-12f);
    float dmx = dist, dsm = dist, S0 = X0, S1 = X1, S2 = X2;
    #pragma unroll
    for (int off = 1; off < 16; off <<= 1) {
        dmx = fmaxf(dmx, __shfl_xor(dmx, off, 16));
        dsm += __shfl_xor(dsm, off, 16);
        S0 += __shfl_xor(S0, off, 16);
        S1 += __shfl_xor(S1, off, 16);
        S2 += __shfl_xor(S2, off, 16);
    }
    if (u == 0) {
        ws[WS_GDIS + n] = dmx;
        float m0 = S0*(1.f/16.f), m1 = S1*(1.f/16.f), m2 = S2*(1.f/16.f);
        float* g = ws + WS_GEO9 + (size_t)n*9;
        g[0] = m0-pn0; g[1] = m1-pn1; g[2] = m2-pn2;
        g[3] = m0; g[4] = m1; g[5] = m2;
        g[6] = pn0; g[7] = pn1; g[8] = pn2;
        red[w] = dsm; red[16+w] = dmx;
    }
    __syncthreads();
    if (t == 0) {
        float ds = 0.f, dm = 0.f;
        #pragma unroll
        for (int i = 0; i < 16; ++i) { ds += red[i]; dm = fmaxf(dm, red[16+i]); }
        atomicAdd(&ws[WS_STATS + 0], ds);
        atomicMax((int*)(ws + WS_STATS + 1), __float_as_int(dm));  // dist>=0
    }
}

// ---- K1b: factored BN stats ----
__global__ __launch_bounds__(256) void k1b_stats(float* __restrict__ ws)
{
    __shared__ float Xs[128][48];
    __shared__ float Ss[128][3];
    __shared__ float a3p[9][16];
    const int t = threadIdx.x;
    const int c0 = blockIdx.x * 128;
    for (int e = t; e < 1536; e += 256) {
        int r = e/12, q = e%12;
        *(float4*)&Xs[r][q*4] = *(const float4*)(ws + WS_KNN + (size_t)(c0+r)*48 + q*4);
    }
    __syncthreads();
    if (t < 128) {
        float s0 = 0.f, s1 = 0.f, s2 = 0.f;
        #pragma unroll
        for (int j = 0; j < 16; ++j) { s0 += Xs[t][3*j]; s1 += Xs[t][3*j+1]; s2 += Xs[t][3*j+2]; }
        Ss[t][0] = s0; Ss[t][1] = s1; Ss[t][2] = s2;
    }
    __syncthreads();
    {
        float acc[9];
        #pragma unroll
        for (int q = 0; q < 9; ++q) acc[q] = 0.f;
        for (int i = 0; i < 128; ++i) {
            int e = t;
            #pragma unroll
            for (int q = 0; q < 9; ++q) {
                int a = e/48, b = e%48;
                acc[q] += Xs[i][a] * Xs[i][b];
                e += 256;
            }
        }
        int e = t;
        #pragma unroll
        for (int q = 0; q < 9; ++q) { atomicAdd(&ws[WS_STATS + 50 + e], acc[q]); e += 256; }
    }
    if (t < 144) {
        int a = t/3, d = t%3;
        float s = 0.f;
        for (int i = 0; i < 128; ++i) s += Xs[i][a] * Ss[i][d];
        atomicAdd(&ws[WS_STATS + 2354 + t], s);
    }
    if (t < 144) {
        int q = t >> 4, part = t & 15;
        int d = q/3, e2 = q%3;
        float s = 0.f;
        for (int i = part*8; i < part*8 + 8; ++i) {
            #pragma unroll
            for (int j = 0; j < 16; ++j) s += Xs[i][3*j+d] * Xs[i][3*j+e2];
        }
        a3p[q][part] = s;
    }
    if (t < 48) {
        float s = 0.f;
        for (int i = 0; i < 128; ++i) s += Xs[i][t];
        atomicAdd(&ws[WS_STATS + 2 + t], s);
    }
    if (t < 3) {
        float s = 0.f;
        for (int i = 0; i < 128; ++i) s += Ss[i][t];
        atomicAdd(&ws[WS_STATS + 2507 + t], s);
    }
    __syncthreads();
    if (t < 9) {
        float s = 0.f;
        #pragma unroll
        for (int i = 0; i < 16; ++i) s += a3p[t][i];
        atomicAdd(&ws[WS_STATS + 2498 + t], s);
    }
}

// ---- K2: vol vector + BN fold (M2 reconstructed from factored stats) ----
__global__ __launch_bounds__(256) void k2_fold(
    const float* __restrict__ posW1, const float* __restrict__ posB1,
    const float* __restrict__ gamma, const float* __restrict__ beta,
    const float* __restrict__ gCW, const float* __restrict__ gCb,
    float* __restrict__ ws)
{
    __shared__ float M2n[48][48];
    __shared__ float pmean[48];
    __shared__ float Wc[48][193];
    const int t = threadIdx.x;
    const int i = blockIdx.x;
    for (int e = t; e < 2304; e += 256) {
        int a = e/48, b = e%48, ad = a%3, bd = b%3;
        float v = 16.f*ws[WS_STATS + 50 + e]
                - ws[WS_STATS + 2354 + a*3 + bd]
                - ws[WS_STATS + 2354 + b*3 + ad]
                + ws[WS_STATS + 2498 + ad*3 + bd];
        M2n[a][b] = v * (1.f/(float)MTOT);
    }
    if (t < 48) pmean[t] = (16.f*ws[WS_STATS + 2 + t] - ws[WS_STATS + 2507 + t%3])
                           * (1.f/(float)MTOT);
    if (t < DD) {
        for (int k = 0; k < 48; ++k) Wc[k][t] = posW1[(size_t)(i*48 + k)*DD + t];
    }
    __syncthreads();
    if (i == 0 && t < DD) {
        float dsum = ws[WS_STATS + 0];
        float dmax = __int_as_float(((const int*)(ws + WS_STATS))[1]);
        float vol = (dsum * (1.f/(float)MTOT)) / (dmax + 1e-8f);
        ws[WS_VOLV + t] = vol * gCW[t] + gCb[t];
    }
    if (t < DD) {
        float mu0 = 0.f;
        #pragma unroll 8
        for (int k = 0; k < 48; ++k) mu0 += pmean[k] * Wc[k][t];
        float e2 = 0.f;
        for (int a2 = 0; a2 < 48; ++a2) {
            float inner = 0.f;
            #pragma unroll 8
            for (int b2 = 0; b2 < 48; ++b2) inner += M2n[a2][b2] * Wc[b2][t];
            e2 += Wc[a2][t] * inner;
        }
        float var = fmaxf(e2 - mu0*mu0, 0.f);
        float as = rsqrtf(var + 1e-5f) * gamma[i*DD + t];
        ws[WS_AB + i*DD + t]       = as;
        ws[WS_AB + 576 + i*DD + t] = beta[i*DD + t] - mu0 * as;   // h'=relu(acc*as+bb)
    }
}

// ---- K_prop MFMA ----
__global__ __launch_bounds__(256) void k_prop_mfma(
    const float* __restrict__ x, const int* __restrict__ knn,
    const float* __restrict__ propW, const float* __restrict__ propB,
    float* __restrict__ ws)
{
    __shared__ ushort_t As[64*40];
    __shared__ ushort_t Bs[192*40];
    __shared__ float prs[64*3];
    __shared__ float W3[3*192];
    __shared__ int idx64[64];
    const int t = threadIdx.x;
    const int mbase = blockIdx.x * 64;
    const ushort_t* xb = (const ushort_t*)(ws + WS_XB);
    const ushort_t* pwt = (const ushort_t*)(ws + WS_PROPWT);
    if (t < 64) idx64[t] = knn[mbase + t];
    for (int e = t; e < 576; e += 256) W3[e] = propW[(size_t)(192 + e/192)*DD + (e % 192)];
    for (int e = t; e < 192; e += 256) prs[e] = ws[WS_PR + (size_t)mbase*3 + e];
    const int wave = t >> 6, lane = t & 63, m = lane & 15, quad = lane >> 4;
    f32x4 acc[12];
    #pragma unroll
    for (int nt = 0; nt < 12; ++nt) acc[nt] = (f32x4){0.f,0.f,0.f,0.f};
    for (int ks = 0; ks < 6; ++ks) {
        const int k0 = ks*32;
        __syncthreads();
        {   int r = t >> 2, seg = t & 3;
            *(uint4*)&As[r*40 + seg*8] = *(const uint4*)(xb + (size_t)idx64[r]*192 + k0 + seg*8);
        }
        for (int e = t; e < 768; e += 256) {
            int n = e >> 2, seg = e & 3;
            *(uint4*)&Bs[n*40 + seg*8] = *(const uint4*)(pwt + (size_t)n*192 + k0 + seg*8);
        }
        __syncthreads();
        short8 a = *(const short8*)&As[(wave*16 + m)*40 + quad*8];
        #pragma unroll
        for (int nt = 0; nt < 12; ++nt) {
            short8 b = *(const short8*)&Bs[(nt*16 + m)*40 + quad*8];
            acc[nt] = __builtin_amdgcn_mfma_f32_16x16x32_bf16(a, b, acc[nt], 0, 0, 0);
        }
    }
    const int n = blockIdx.x*4 + wave;
    #pragma unroll
    for (int nt = 0; nt < 12; ++nt) {
        int col = nt*16 + m;
        float bv = propB[col];
        float w0 = W3[col], w1 = W3[192 + col], w2 = W3[384 + col];
        float s = 0.f;
        #pragma unroll
        for (int reg = 0; reg < 4; ++reg) {
            int j = wave*16 + quad*4 + reg;
            float v = acc[nt][reg] + prs[j*3+0]*w0 + prs[j*3+1]*w1 + prs[j*3+2]*w2 + bv;
            s += fmaxf(v, 0.f);
        }
        s += __shfl_xor(s, 16);
        s += __shfl_xor(s, 32);
        if (quad == 0)
            ws[WS_X1 + (size_t)n*DD + col] = x[(size_t)n*DD + col] + s * (1.f/16.f);
    }
}

// ---- generic bf16 MFMA GEMM ----
__global__ __launch_bounds__(256) void gemm_mfma(
    const ushort_t* __restrict__ A, const ushort_t* __restrict__ Bt,
    const float* __restrict__ bias, float* __restrict__ Cf,
    ushort_t* __restrict__ Cb, int N)
{
    __shared__ ushort_t As[64*40];
    __shared__ ushort_t Bs[64*40];
    const int t = threadIdx.x;
    const int wave = t >> 6, lane = t & 63, m = lane & 15, quad = lane >> 4;
    const int rowBase = blockIdx.x * 64, colBase = blockIdx.y * 64;
    f32x4 acc[4];
    #pragma unroll
    for (int nt = 0; nt < 4; ++nt) acc[nt] = (f32x4){0.f,0.f,0.f,0.f};
    for (int ks = 0; ks < 6; ++ks) {
        __syncthreads();
        {   int r = t >> 2, seg = t & 3;
            *(uint4*)&As[r*40 + seg*8] = *(const uint4*)(A + (size_t)(rowBase + r)*192 + ks*32 + seg*8);
            *(uint4*)&Bs[r*40 + seg*8] = *(const uint4*)(Bt + (size_t)(colBase + r)*192 + ks*32 + seg*8);
        }
        __syncthreads();
        short8 a = *(const short8*)&As[(wave*16 + m)*40 + quad*8];
        #pragma unroll
        for (int nt = 0; nt < 4; ++nt) {
            short8 b = *(const short8*)&Bs[(nt*16 + m)*40 + quad*8];
            acc[nt] = __builtin_amdgcn_mfma_f32_16x16x32_bf16(a, b, acc[nt], 0, 0, 0);
        }
    }
    #pragma unroll
    for (int nt = 0; nt < 4; ++nt) {
        int col = colBase + nt*16 + m;
        float bv = bias ? bias[col] : 0.f;
        #pragma unroll
        for (int reg = 0; reg < 4; ++reg) {
            int row = rowBase + wave*16 + quad*4 + reg;
            float v = acc[nt][reg] + bv;
            if (Cf) Cf[(size_t)row*N + col] = v;
            else    Cb[(size_t)row*N + col] = f2bf(v);
        }
    }
}

// ---- K3a v2: keypoint attention via MFMA (8 points/block) + U assembly ----
__global__ __launch_bounds__(256) void k3a(
    const float* __restrict__ p, const float* __restrict__ kn,
    const float* __restrict__ deW1, const float* __restrict__ deB1,
    const float* __restrict__ deB2, const float* __restrict__ kpW,
    const float* __restrict__ gAW, const float* __restrict__ gAb,
    const float* __restrict__ gBW, const float* __restrict__ gBb,
    float* __restrict__ ws)
{
    __shared__ ushort_t fb[128*72];     // f rows bf16, K pad 64, stride 72
    __shared__ float kds[8][16];
    __shared__ float w1s[48], b1s[48];
    __shared__ float dfeat[8][192];
    ushort_t* ub = (ushort_t*)(ws + WS_UB);
    const int t = threadIdx.x;
    const int nb = blockIdx.x * 8;
    if (t < 48) { w1s[t] = deW1[t]; b1s[t] = deB1[t]; }
    if (t < 128) {
        int w = t >> 4, kp = t & 15;
        float dx = p[(nb+w)*3+0]-kn[kp*3+0];
        float dy = p[(nb+w)*3+1]-kn[kp*3+1];
        float dz = p[(nb+w)*3+2]-kn[kp*3+2];
        kds[w][kp] = sqrtf(dx*dx + dy*dy + dz*dz + 1e-12f);
    }
    __syncthreads();
    for (int e = t; e < 128*64; e += 256) {   // f = relu(kd*w1+b1), bf16 A tile
        int j = e >> 6, k = e & 63;
        float v = (k < 48) ? fmaxf(kds[j>>4][j&15]*w1s[k] + b1s[k], 0.f) : 0.f;
        fb[j*72 + k] = f2bf(v);
    }
    __syncthreads();
    const int wave = t >> 6, lane = t & 63, m = lane & 15, quad = lane >> 4;
    const ushort_t* dwt = (const ushort_t*)(ws + WS_DEW2T);
    short8 afr[2][2];
    #pragma unroll
    for (int mt = 0; mt < 2; ++mt)
        #pragma unroll
        for (int ks = 0; ks < 2; ++ks)
            afr[mt][ks] = *(const short8*)&fb[((wave*2 + mt)*16 + m)*72 + ks*32 + quad*8];
    float df[2][12][4];
    float sc[2][4];
    #pragma unroll
    for (int mt = 0; mt < 2; ++mt)
        #pragma unroll
        for (int reg = 0; reg < 4; ++reg) sc[mt][reg] = 0.f;
    for (int nt = 0; nt < 12; ++nt) {
        f32x4 acc0 = (f32x4){0.f,0.f,0.f,0.f};
        f32x4 acc1 = (f32x4){0.f,0.f,0.f,0.f};
        #pragma unroll
        for (int ks = 0; ks < 2; ++ks) {
            short8 b = *(const short8*)(dwt + ((size_t)(nt*16 + m)*64 + ks*32 + quad*8));
            acc0 = __builtin_amdgcn_mfma_f32_16x16x32_bf16(afr[0][ks], b, acc0, 0, 0, 0);
            acc1 = __builtin_amdgcn_mfma_f32_16x16x32_bf16(afr[1][ks], b, acc1, 0, 0, 0);
        }
        int col = nt*16 + m;
        float b2 = deB2[col], kw = kpW[col];
        #pragma unroll
        for (int reg = 0; reg < 4; ++reg) {
            float d0 = acc0[reg] + b2, d1 = acc1[reg] + b2;
            df[0][nt][reg] = d0; df[1][nt][reg] = d1;
            sc[0][reg] += d0*kw; sc[1][reg] += d1*kw;
        }
    }
    #pragma unroll
    for (int mt = 0; mt < 2; ++mt)     // reduce score over m lanes (width 16)
        #pragma unroll
        for (int reg = 0; reg < 4; ++reg) {
            float v = sc[mt][reg];
            v += __shfl_xor(v, 1, 16); v += __shfl_xor(v, 2, 16);
            v += __shfl_xor(v, 4, 16); v += __shfl_xor(v, 8, 16);
            sc[mt][reg] = v;
        }
    float wgt[2][4];
    #pragma unroll
    for (int mt = 0; mt < 2; ++mt) {   // softmax over kp = quad*4+reg (kpB const: dropped)
        float mx = fmaxf(fmaxf(sc[mt][0], sc[mt][1]), fmaxf(sc[mt][2], sc[mt][3]));
        mx = fmaxf(mx, __shfl_xor(mx, 16));
        mx = fmaxf(mx, __shfl_xor(mx, 32));
        float sm = 0.f;
        #pragma unroll
        for (int reg = 0; reg < 4; ++reg) { wgt[mt][reg] = expf(sc[mt][reg] - mx); sm += wgt[mt][reg]; }
        sm += __shfl_xor(sm, 16);
        sm += __shfl_xor(sm, 32);
        float inv = 1.f / sm;
        #pragma unroll
        for (int reg = 0; reg < 4; ++reg) wgt[mt][reg] *= inv;
    }
    for (int nt = 0; nt < 12; ++nt) {  // dfeat = attn-weighted kp-reduction
        int col = nt*16 + m;
        #pragma unroll
        for (int mt = 0; mt < 2; ++mt) {
            float s = 0.f;
            #pragma unroll
            for (int reg = 0; reg < 4; ++reg) s += wgt[mt][reg] * df[mt][nt][reg];
            s += __shfl_xor(s, 16);
            s += __shfl_xor(s, 32);
            if (quad == 0) dfeat[wave*2 + mt][col] = s;
        }
    }
    __syncthreads();
    if (t < DD) {                      // U assembly -> bf16 UB
        for (int w = 0; w < 8; ++w) {
            int n = nb + w;
            float uval = ws[WS_X1 + (size_t)n*DD + t] + gAb[t] + gBb[t]
                       + ws[WS_VOLV + t] + dfeat[w][t];
            uval += ws[WS_GDIS + n] * gBW[t];
            #pragma unroll
            for (int kk = 0; kk < 9; ++kk) uval += ws[WS_GEO9 + (size_t)n*9 + kk] * gAW[kk*DD + t];
            ub[(size_t)n*DD + t] = f2bf(uval);
        }
    }
}

// ---- K_attn_fused: dqdk + scores + softmax + attn@v + pv + CTR; bf16 QKV ----
__global__ __launch_bounds__(256) void k_attn_fused(
    const int* __restrict__ knn,
    const float* __restrict__ posW2, const float* __restrict__ posB2,
    float* __restrict__ ws)
{
    __shared__ ushort_t posb[128*72];   // bf16 pos rows, K pad 64, stride 72
    __shared__ float rqs[8*6*192];      // rq per i; later wsum
    __shared__ float qk[8*192];         // q0 (i=0) / k0 (i=1), reloaded per i
    __shared__ float scb[8*192];        // sc[w][i(2)][h(6)][j(16)]
    __shared__ float dqk[8*96];         // dqk[w][h][j]
    __shared__ float attns[8*96];
    __shared__ float Xl[8][48];
    __shared__ int idxs[128];
    const int t = threadIdx.x;
    const int nb = blockIdx.x * 8;
    ushort_t* ctrb = (ushort_t*)(ws + WS_CTRB);
    const ushort_t* qkvb = (const ushort_t*)(ws + WS_QKV);
    if (t < 128) idxs[t] = knn[(nb + (t >> 4))*NS + (t & 15)];
    for (int e = t; e < 384; e += 256) {
        int w = e/48, k = e%48;
        Xl[w][k] = ws[WS_KNN + (size_t)(nb+w)*48 + k];
    }
    __syncthreads();
    for (int e = t; e < 128*64; e += 256) {   // build bf16 pos tile
        int j = e >> 6, k = e & 63;
        int w = j >> 4, jl = j & 15;
        float v = (k < 48) ? (Xl[w][k] - Xl[w][jl*3 + (k % 3)]) : 0.f;
        posb[j*72 + k] = f2bf(v);
    }
    const int wave = t >> 6, lane = t & 63, m = lane & 15, quad = lane >> 4;
    const ushort_t* w1t = (const ushort_t*)(ws + WS_W1T);
    // ---- i = 0,1: rq + MFMA H + fused contraction -> scb ----
    for (int i = 0; i < 2; ++i) {
        __syncthreads();   // posb built (i=0) / prior rqs,qk readers done (i=1)
        for (int e = t; e < 8*192; e += 256) {
            int w = e/192, c = e%192;
            qk[e] = bf2f(qkvb[(size_t)idxs[w*16]*576 + i*192 + c]);
        }
        __syncthreads();
        if (t < 192) {     // rq: W2 row t (global) x qk broadcast
            const float* Wrow = posW2 + (size_t)i*DD*DD + (size_t)t*DD;
            for (int h = 0; h < 6; ++h) {
                float4 wr[8];
                #pragma unroll
                for (int q = 0; q < 8; ++q) wr[q] = *(const float4*)(Wrow + h*32 + q*4);
                float a[8];
                #pragma unroll
                for (int w = 0; w < 8; ++w) a[w] = 0.f;
                #pragma unroll
                for (int q = 0; q < 8; ++q) {
                    #pragma unroll
                    for (int d = 0; d < 4; ++d) {
                        float wv = (&wr[q].x)[d];
                        int c = h*32 + q*4 + d;
                        #pragma unroll
                        for (int w = 0; w < 8; ++w) a[w] += wv * qk[w*192 + c];
                    }
                }
                #pragma unroll
                for (int w = 0; w < 8; ++w) rqs[(w*6 + h)*192 + t] = a[w];
            }
        }
        __syncthreads();
        short8 afr[2][2];
        #pragma unroll
        for (int mt = 0; mt < 2; ++mt)
            #pragma unroll
            for (int ks = 0; ks < 2; ++ks)
                afr[mt][ks] = *(const short8*)&posb[((wave*2 + mt)*16 + m)*72 + ks*32 + quad*8];
        float s[48];       // [mt(2)][reg(4)][h(6)]
        #pragma unroll
        for (int e = 0; e < 48; ++e) s[e] = 0.f;
        for (int nt = 0; nt < 12; ++nt) {
            f32x4 acc0 = (f32x4){0.f,0.f,0.f,0.f};
            f32x4 acc1 = (f32x4){0.f,0.f,0.f,0.f};
            #pragma unroll
            for (int ks = 0; ks < 2; ++ks) {
                short8 b = *(const short8*)(w1t + ((size_t)(i*192 + nt*16 + m)*64 + ks*32 + quad*8));
                acc0 = __builtin_amdgcn_mfma_f32_16x16x32_bf16(afr[0][ks], b, acc0, 0, 0, 0);
                acc1 = __builtin_amdgcn_mfma_f32_16x16x32_bf16(afr[1][ks], b, acc1, 0, 0, 0);
            }
            int kk = nt*16 + m;
            float as = ws[WS_AB + i*DD + kk];
            float bb = ws[WS_AB + 576 + i*DD + kk];
            float h0[4], h1[4];
            #pragma unroll
            for (int reg = 0; reg < 4; ++reg) {
                h0[reg] = fmaxf(acc0[reg]*as + bb, 0.f);
                h1[reg] = fmaxf(acc1[reg]*as + bb, 0.f);
            }
            #pragma unroll
            for (int h = 0; h < 6; ++h) {
                float r0 = rqs[((wave*2 + 0)*6 + h)*192 + kk];
                float r1 = rqs[((wave*2 + 1)*6 + h)*192 + kk];
                #pragma unroll
                for (int reg = 0; reg < 4; ++reg) {
                    s[reg*6 + h]      += h0[reg]*r0;
                    s[24 + reg*6 + h] += h1[reg]*r1;
                }
            }
        }
        #pragma unroll
        for (int e = 0; e < 48; ++e) {
            float v = s[e];
            v += __shfl_xor(v, 1, 16); v += __shfl_xor(v, 2, 16);
            v += __shfl_xor(v, 4, 16); v += __shfl_xor(v, 8, 16);
            s[e] = v;
        }
        if (m == 0) {
            #pragma unroll
            for (int mt = 0; mt < 2; ++mt)
                #pragma unroll
                for (int reg = 0; reg < 4; ++reg) {
                    int w = wave*2 + mt, j = quad*4 + reg;
                    #pragma unroll
                    for (int h = 0; h < 6; ++h)
                        scb[w*192 + i*96 + h*16 + j] = s[mt*24 + reg*6 + h];
                }
        }
    }
    // ---- dqk dots: thread -> (w, j, half); bf16 rows ----
    {
        const int w = t >> 5, r = t & 31, j = r >> 1, half = r & 1;
        const ushort_t* krow = qkvb + (size_t)idxs[w*16 + j]*576 + 192 + half*96;
        const ushort_t* qrow = qkvb + (size_t)idxs[w*16]*576 + half*96;
        float hd[3] = {0.f, 0.f, 0.f};
        #pragma unroll
        for (int q = 0; q < 12; ++q) {
            uint4 kv = *(const uint4*)(krow + q*8);
            uint4 qv = *(const uint4*)(qrow + q*8);
            float sv = 0.f;
            #pragma unroll
            for (int d = 0; d < 4; ++d) {
                unsigned int ku = (&kv.x)[d], qu = (&qv.x)[d];
                sv += __uint_as_float(ku << 16) * __uint_as_float(qu << 16);
                sv += __uint_as_float(ku & 0xffff0000u) * __uint_as_float(qu & 0xffff0000u);
            }
            hd[q >> 2] += sv;
        }
        dqk[w*96 + (half*3+0)*16 + j] = hd[0];
        dqk[w*96 + (half*3+1)*16 + j] = hd[1];
        dqk[w*96 + (half*3+2)*16 + j] = hd[2];
    }
    __syncthreads();   // dqk+scb ready; also all rqs reads (i=1) done
    // ---- softmax over j per (w,h) ----
    {
        const float scale = 0.17677669529663687f;  // 32^-0.5
        #pragma unroll
        for (int c = 0; c < 3; ++c) {
            int e = c*256 + t;
            int row = e >> 4, j = e & 15, w = row / 6, h = row % 6;
            float z = (dqk[e] + scb[w*192 + h*16 + j] + scb[w*192 + 96 + h*16 + j]) * scale;
            float mx = z;
            #pragma unroll
            for (int off = 1; off < 16; off <<= 1) mx = fmaxf(mx, __shfl_xor(mx, off, 16));
            float ex = expf(z - mx);
            float sm = ex;
            #pragma unroll
            for (int off = 1; off < 16; off <<= 1) sm += __shfl_xor(sm, off, 16);
            attns[w*96 + h*16 + j] = ex / sm;
        }
    }
    __syncthreads();   // attns ready
    // ---- ctr1 = attn @ v (bf16 V rows) ----
    float ctr1[8];
    if (t < DD) {
        const int h = t >> 5;
        #pragma unroll
        for (int w = 0; w < 8; ++w) {
            float sv = 0.f;
            #pragma unroll
            for (int j = 0; j < NS; ++j)
                sv += attns[w*96 + h*16 + j] * bf2f(qkvb[(size_t)idxs[w*16 + j]*576 + 384 + t]);
            ctr1[w] = sv;
        }
    }
    // ---- H2 MFMA + attn-weighted reduce -> wsum (rqs region) ----
    {
        float* wsum = rqs;
        const int w0 = wave*2, w1 = wave*2 + 1;
        short8 afr[2][2];
        #pragma unroll
        for (int mt = 0; mt < 2; ++mt)
            #pragma unroll
            for (int ks = 0; ks < 2; ++ks)
                afr[mt][ks] = *(const short8*)&posb[((wave*2 + mt)*16 + m)*72 + ks*32 + quad*8];
        for (int nt = 0; nt < 12; ++nt) {
            f32x4 acc0 = (f32x4){0.f,0.f,0.f,0.f};
            f32x4 acc1 = (f32x4){0.f,0.f,0.f,0.f};
            #pragma unroll
            for (int ks = 0; ks < 2; ++ks) {
                short8 b = *(const short8*)(w1t + ((size_t)(2*192 + nt*16 + m)*64 + ks*32 + quad*8));
                acc0 = __builtin_amdgcn_mfma_f32_16x16x32_bf16(afr[0][ks], b, acc0, 0, 0, 0);
                acc1 = __builtin_amdgcn_mfma_f32_16x16x32_bf16(afr[1][ks], b, acc1, 0, 0, 0);
            }
            int kk = nt*16 + m;
            float as = ws[WS_AB + 2*DD + kk];
            float bb = ws[WS_AB + 576 + 2*DD + kk];
            float h0[4], h1[4];
            #pragma unroll
            for (int reg = 0; reg < 4; ++reg) {
                h0[reg] = fmaxf(acc0[reg]*as + bb, 0.f);
                h1[reg] = fmaxf(acc1[reg]*as + bb, 0.f);
            }
            #pragma unroll
            for (int h = 0; h < 6; ++h) {
                float p0 = 0.f, p1 = 0.f;
                #pragma unroll
                for (int reg = 0; reg < 4; ++reg) {
                    int j = quad*4 + reg;
                    p0 += attns[w0*96 + h*16 + j] * h0[reg];
                    p1 += attns[w1*96 + h*16 + j] * h1[reg];
                }
                p0 += __shfl_xor(p0, 16); p0 += __shfl_xor(p0, 32);
                p1 += __shfl_xor(p1, 16); p1 += __shfl_xor(p1, 32);
                if (quad == 0) {
                    wsum[(w0*6 + h)*192 + kk] = p0;
                    wsum[(w1*6 + h)*192 + kk] = p1;
                }
            }
        }
    }
    __syncthreads();   // wsum ready
    // ---- pv = wsum @ W2_2 via W2T rows; CTR = ctr1 + pv + b2 ----
    if (t < DD) {
        const float* wsum = rqs;
        const int h = t >> 5;
        float pvacc[8];
        #pragma unroll
        for (int w = 0; w < 8; ++w) pvacc[w] = 0.f;
        const float* wrow = ws + WS_W2T + (size_t)t*DD;
        for (int k4 = 0; k4 < 48; ++k4) {
            float4 wv = *(const float4*)(wrow + k4*4);
            #pragma unroll
            for (int w = 0; w < 8; ++w) {
                const float* av = &wsum[(w*6 + h)*192 + k4*4];
                pvacc[w] += av[0]*wv.x + av[1]*wv.y + av[2]*wv.z + av[3]*wv.w;
            }
        }
        float b2 = posB2[2*DD + t];
        #pragma unroll
        for (int w = 0; w < 8; ++w)
            ctrb[(size_t)(nb+w)*DD + t] = f2bf(ctr1[w] + pvacc[w] + b2);
    }
}

extern "C" void kernel_launch(void* const* d_in, const int* in_sizes, int n_in,
                              void* d_out, int out_size, void* d_ws, size_t ws_size,
                              hipStream_t stream)
{
    const float* p     = (const float*)d_in[0];
    const float* x     = (const float*)d_in[1];
    const int*   knn   = (const int*)  d_in[2];
    const float* Wqkv  = (const float*)d_in[3];
    const float* Wproj = (const float*)d_in[4];
    const float* bproj = (const float*)d_in[5];
    const float* propW = (const float*)d_in[6];
    const float* propB = (const float*)d_in[7];
    const float* gAW   = (const float*)d_in[8];
    const float* gAb   = (const float*)d_in[9];
    const float* gBW   = (const float*)d_in[10];
    const float* gBb   = (const float*)d_in[11];
    const float* gCW   = (const float*)d_in[12];
    const float* gCb   = (const float*)d_in[13];
    const float* posW1 = (const float*)d_in[14];
    const float* posB1 = (const float*)d_in[15];
    const float* gamma = (const float*)d_in[16];
    const float* beta  = (const float*)d_in[17];
    const float* posW2 = (const float*)d_in[18];
    const float* posB2 = (const float*)d_in[19];
    const float* kn    = (const float*)d_in[20];
    const float* deW1  = (const float*)d_in[21];
    const float* deB1  = (const float*)d_in[22];
    const float* deW2  = (const float*)d_in[23];
    const float* deB2  = (const float*)d_in[24];
    const float* kpW   = (const float*)d_in[25];
    const float* kpB   = (const float*)d_in[26];
    const float* fusW  = (const float*)d_in[27];
    const float* fusB  = (const float*)d_in[28];
    float* ws   = (float*)d_ws;
    float* outp = (float*)d_out;
    (void)kpB;  // constant shift inside softmax: invariant, dropped

    hipLaunchKernelGGL(k_init, dim3(10), dim3(256), 0, stream, ws);
    hipLaunchKernelGGL(k_w2t, dim3(144), dim3(256), 0, stream, posW2, ws);
    hipLaunchKernelGGL(k_prep, dim3(1056), dim3(256), 0, stream,
                       propW, Wqkv, fusW, Wproj, posW1, deW2, ws);
    hipLaunchKernelGGL(k_castx, dim3(NP*DD/256), dim3(256), 0, stream, x, ws);
    hipLaunchKernelGGL(k1a_geom, dim3(NP/16), dim3(256), 0, stream, p, knn, ws);
    hipLaunchKernelGGL(k1b_stats, dim3(NP/128), dim3(256), 0, stream, ws);
    hipLaunchKernelGGL(k2_fold, dim3(3), dim3(256), 0, stream,
                       posW1, posB1, gamma, beta, gCW, gCb, ws);
    hipLaunchKernelGGL(k_prop_mfma, dim3(MTOT/64), dim3(256), 0, stream,
                       x, knn, propW, propB, ws);
    hipLaunchKernelGGL(k3a, dim3(NP/8), dim3(256), 0, stream,
                       p, kn, deW1, deB1, deB2, kpW, gAW, gAb, gBW, gBb, ws);
    // X2B = bf16(UB @ fusW + fusB)
    hipLaunchKernelGGL(gemm_mfma, dim3(NP/64, 3), dim3(256), 0, stream,
                       (const ushort_t*)(ws + WS_UB), (const ushort_t*)(ws + WS_FUSWT),
                       fusB, (float*)nullptr, (ushort_t*)(ws + WS_X2B), DD);
    // QKV = bf16(X2B @ Wqkv)
    hipLaunchKernelGGL(gemm_mfma, dim3(NP/64, 9), dim3(256), 0, stream,
                       (const ushort_t*)(ws + WS_X2B), (const ushort_t*)(ws + WS_QKVT),
                       (const float*)nullptr, (float*)nullptr,
                       (ushort_t*)(ws + WS_QKV), 576);
    hipLaunchKernelGGL(k_attn_fused, dim3(NP/8), dim3(256), 0, stream,
                       knn, posW2, posB2, ws);
    // OUT = CTRB @ Wproj + bproj (fp32 out)
    hipLaunchKernelGGL(gemm_mfma, dim3(NP/64, 3), dim3(256), 0, stream,
                       (const ushort_t*)(ws + WS_CTRB), (const ushort_t*)(ws + WS_PROJWT),
                       bproj, outp, (ushort_t*)nullptr, DD);
}